// Round 1
// baseline (956.227 us; speedup 1.0000x reference)
//
#include <hip/hip_runtime.h>
#include <math.h>

// Problem constants
#define NB 4
#define HB 256
#define WB 256
#define CB 8
#define NPIX (NB*HB*WB)   // 262144
#define W2B 129           // rfft bins along W

__device__ __forceinline__ float gelu_f(float x){
    float x3 = x*x*x;
    float t = tanhf(0.7978845608028654f*(x + 0.044715f*x3));
    return 0.5f*x*(1.0f+t);
}

__device__ __forceinline__ void ldcp(float* dst, const float* __restrict__ src, int n, int t){
    for (int i = t; i < n; i += 256) dst[i] = src[i];
}

// 3-layer MLP (2 -> 16 -> 16 -> 64), weights packed in LDS at sw:
// [0:32) w1, [32:48) b1, [48:304) w2, [304:320) b2, [320:1344) w3, [1344:1408) b3
__device__ __forceinline__ void mlp_store(const float* sw, float a, float b,
                                          float* __restrict__ dst, float scale){
    float h1[16], h2[16];
#pragma unroll
    for (int o = 0; o < 16; ++o)
        h1[o] = gelu_f(a*sw[o] + b*sw[16+o] + sw[32+o]);
#pragma unroll
    for (int o = 0; o < 16; ++o){
        float acc = sw[304+o];
#pragma unroll
        for (int i = 0; i < 16; ++i) acc += h1[i]*sw[48+i*16+o];
        h2[o] = gelu_f(acc);
    }
#pragma unroll
    for (int o = 0; o < 64; ++o){
        float acc = sw[1344+o];
#pragma unroll
        for (int i = 0; i < 16; ++i) acc += h2[i]*sw[320+i*64+o];
        dst[o] = acc*scale;
    }
}

// ---- gamma/delta matrices from k: one thread per pixel ------------------
__global__ __launch_bounds__(256) void mlp_gd_kernel(
    const float* __restrict__ kin,
    const float* gw1,const float* gb1,const float* gw2,const float* gb2,const float* gw3,const float* gb3,
    const float* dw1,const float* db1,const float* dw2,const float* db2,const float* dw3,const float* db3,
    float* __restrict__ gmat, float* __restrict__ dmat)
{
    __shared__ float sw[2816];
    int t = threadIdx.x;
    ldcp(sw+0,   gw1,  32, t); ldcp(sw+32,  gb1, 16, t);
    ldcp(sw+48,  gw2, 256, t); ldcp(sw+304, gb2, 16, t);
    ldcp(sw+320, gw3,1024, t); ldcp(sw+1344,gb3, 64, t);
    ldcp(sw+1408+0,   dw1,  32, t); ldcp(sw+1408+32,  db1, 16, t);
    ldcp(sw+1408+48,  dw2, 256, t); ldcp(sw+1408+304, db2, 16, t);
    ldcp(sw+1408+320, dw3,1024, t); ldcp(sw+1408+1344,db3, 64, t);
    __syncthreads();
    int pix = blockIdx.x*256 + t;
    float a = kin[(size_t)pix*2+0], b = kin[(size_t)pix*2+1];
    mlp_store(sw,      a, b, gmat + (size_t)pix*64, 1.0f/64.0f);
    mlp_store(sw+1408, a, b, dmat + (size_t)pix*64, 1.0f/64.0f);
}

// ---- spectral filter: filt[h][w2][j][k] from K=(kx[w2], ky[h]) ----------
__global__ __launch_bounds__(256) void filt_kernel(
    const float* fw1,const float* fb1,const float* fw2,const float* fb2,const float* fw3,const float* fb3,
    const float* iw1,const float* ib1,const float* iw2,const float* ib2,const float* iw3,const float* ib3,
    float* __restrict__ fre, float* __restrict__ fim)
{
    __shared__ float sw[2816];
    int t = threadIdx.x;
    ldcp(sw+0,   fw1,  32, t); ldcp(sw+32,  fb1, 16, t);
    ldcp(sw+48,  fw2, 256, t); ldcp(sw+304, fb2, 16, t);
    ldcp(sw+320, fw3,1024, t); ldcp(sw+1344,fb3, 64, t);
    ldcp(sw+1408+0,   iw1,  32, t); ldcp(sw+1408+32,  ib1, 16, t);
    ldcp(sw+1408+48,  iw2, 256, t); ldcp(sw+1408+304, ib2, 16, t);
    ldcp(sw+1408+320, iw3,1024, t); ldcp(sw+1408+1344,ib3, 64, t);
    __syncthreads();
    int p = blockIdx.x*256 + t;      // 129 blocks * 256 = 33024 points exactly
    int i = p / 129, j = p % 129;
    float x = (float)j;                          // kx = rfftfreq*H = w2
    float y = (float)(i < 128 ? i : i - 256);    // ky = fftfreq*W signed
    mlp_store(sw,      x, y, fre + (size_t)p*64, 1.0f/64.0f);
    mlp_store(sw+1408, x, y, fim + (size_t)p*64, 1.0f/64.0f);
}

// ---- per-pixel einsums ---------------------------------------------------
__global__ __launch_bounds__(256) void pre_kernel(
    const float* __restrict__ u, const float* __restrict__ gmat,
    const float* __restrict__ dmat, float* __restrict__ loc, float* __restrict__ du)
{
    int gid = blockIdx.x*256 + threadIdx.x;  // over NPIX*8
    int pix = gid >> 3, kk = gid & 7;
    const float* up = u + (size_t)pix*8;
    const float* gp = gmat + (size_t)pix*64 + kk;
    const float* dp = dmat + (size_t)pix*64 + kk;
    float sg = 0.f, sd = 0.f;
#pragma unroll
    for (int j = 0; j < 8; ++j){ float uj = up[j]; sg += uj*gp[j*8]; sd += uj*dp[j*8]; }
    loc[gid] = 2.0f*up[kk] - sg;
    du[gid]  = sd;
}

__global__ __launch_bounds__(256) void upd_kernel(
    const float* __restrict__ loc, const float* __restrict__ gu,
    const float* __restrict__ gmat, float* __restrict__ unew)
{
    int gid = blockIdx.x*256 + threadIdx.x;
    int pix = gid >> 3, kk = gid & 7;
    const float* up = gu + (size_t)pix*8;
    const float* gp = gmat + (size_t)pix*64 + kk;
    float s = 0.f;
#pragma unroll
    for (int j = 0; j < 8; ++j) s += up[j]*gp[j*8];
    unew[gid] = loc[gid] + s;
}

__global__ __launch_bounds__(256) void post_kernel(
    const float* __restrict__ u, const float* __restrict__ bias, float* __restrict__ out)
{
    int gid = blockIdx.x*256 + threadIdx.x;
    out[gid] = gelu_f(u[gid] + bias[gid & 7]);
}

// ---- 256-point FFT via 16x16 Cooley-Tukey, 256 threads, data in LDS -----
// Natural order in, natural order out. tw tables hold exp(-2*pi*i*m/256).
__device__ __forceinline__ void fft256_lds(float* re, float* im,
                                           const float* twc, const float* tws,
                                           int t, bool inv)
{
    int n2 = t >> 4, k1 = t & 15;
    float ar = 0.f, ai = 0.f;
#pragma unroll
    for (int n1 = 0; n1 < 16; ++n1){
        int m = (n1*k1*16) & 255;
        float c = twc[m], s = tws[m]; if (inv) s = -s;
        float xr = re[16*n1 + n2], xi = im[16*n1 + n2];
        ar += xr*c - xi*s;
        ai += xr*s + xi*c;
    }
    int m2 = (n2*k1) & 255;
    float c2 = twc[m2], s2 = tws[m2]; if (inv) s2 = -s2;
    float br = ar*c2 - ai*s2, bi = ar*s2 + ai*c2;
    __syncthreads();
    re[t] = br; im[t] = bi;                 // B[n2][k1] at n2*16+k1 == t
    __syncthreads();
    int k1b = t & 15, k2 = t >> 4;
    float xr2 = 0.f, xi2 = 0.f;
#pragma unroll
    for (int n2b = 0; n2b < 16; ++n2b){
        int m3 = (n2b*k2*16) & 255;
        float c3 = twc[m3], s3 = tws[m3]; if (inv) s3 = -s3;
        float br2 = re[n2b*16 + k1b], bi2 = im[n2b*16 + k1b];
        xr2 += br2*c3 - bi2*s3;
        xi2 += br2*s3 + bi2*c3;
    }
    __syncthreads();
    re[t] = xr2; im[t] = xi2;               // X[k1b + 16*k2] == X[t]
    __syncthreads();
}

// ---- forward rfft along W: one block per (n,h) row ----------------------
// spec layout: [n][w2][h][c] float2
__global__ __launch_bounds__(256) void fftw_kernel(
    const float* __restrict__ du, float2* __restrict__ spec)
{
    __shared__ float twc[256], tws[256];
    __shared__ float xr[8][256], xi[8][256];
    int t = threadIdx.x;
    int n = blockIdx.x >> 8, h = blockIdx.x & 255;
    { float ang = -2.0f*3.14159265358979323846f*(float)t/256.0f;
      twc[t] = cosf(ang); tws[t] = sinf(ang); }
    const float* src = du + (size_t)blockIdx.x*2048;   // (w,c) row
    float4 a = *(const float4*)(src + t*8);
    float4 b = *(const float4*)(src + t*8 + 4);
    xr[0][t]=a.x; xr[1][t]=a.y; xr[2][t]=a.z; xr[3][t]=a.w;
    xr[4][t]=b.x; xr[5][t]=b.y; xr[6][t]=b.z; xr[7][t]=b.w;
#pragma unroll
    for (int c = 0; c < 8; ++c) xi[c][t] = 0.f;
    __syncthreads();
#pragma unroll
    for (int c = 0; c < 8; ++c) fft256_lds(xr[c], xi[c], twc, tws, t, false);
    if (t < 129){
        float4* dst = (float4*)(spec + (((size_t)n*129 + t)*256 + h)*8);
        dst[0] = make_float4(xr[0][t], xi[0][t], xr[1][t], xi[1][t]);
        dst[1] = make_float4(xr[2][t], xi[2][t], xr[3][t], xi[3][t]);
        dst[2] = make_float4(xr[4][t], xi[4][t], xr[5][t], xi[5][t]);
        dst[3] = make_float4(xr[6][t], xi[6][t], xr[7][t], xi[7][t]);
    }
}

// ---- fused: cfft along H -> per-frequency 8x8 complex mat -> icfft ------
// One block per (n,w2); thread t owns H-frequency bin h=t.
__global__ __launch_bounds__(256) void ffth_mult_kernel(
    float2* __restrict__ spec, const float* __restrict__ fre, const float* __restrict__ fim)
{
    __shared__ float twc[256], tws[256];
    __shared__ float xr[8][256], xi[8][256];
    int t = threadIdx.x;
    int n = blockIdx.x / 129, w2 = blockIdx.x % 129;
    { float ang = -2.0f*3.14159265358979323846f*(float)t/256.0f;
      twc[t] = cosf(ang); tws[t] = sinf(ang); }
    float2* base = spec + ((size_t)(n*129 + w2))*256*8;
    const float4* rp = (const float4*)(base + (size_t)t*8);
    float4 r0 = rp[0], r1 = rp[1], r2 = rp[2], r3 = rp[3];
    xr[0][t]=r0.x; xi[0][t]=r0.y; xr[1][t]=r0.z; xi[1][t]=r0.w;
    xr[2][t]=r1.x; xi[2][t]=r1.y; xr[3][t]=r1.z; xi[3][t]=r1.w;
    xr[4][t]=r2.x; xi[4][t]=r2.y; xr[5][t]=r2.z; xi[5][t]=r2.w;
    xr[6][t]=r3.x; xi[6][t]=r3.y; xr[7][t]=r3.z; xi[7][t]=r3.w;
    __syncthreads();
#pragma unroll
    for (int c = 0; c < 8; ++c) fft256_lds(xr[c], xi[c], twc, tws, t, false);
    // per-frequency complex 8x8: out[k] = sum_j S[j] * F[h=t][w2][j][k]
    float sr[8], si[8], orr[8], oii[8];
#pragma unroll
    for (int j = 0; j < 8; ++j){ sr[j] = xr[j][t]; si[j] = xi[j][t]; }
#pragma unroll
    for (int kq = 0; kq < 8; ++kq){ orr[kq] = 0.f; oii[kq] = 0.f; }
    const float4* frp = (const float4*)(fre + ((size_t)t*129 + w2)*64);
    const float4* fip = (const float4*)(fim + ((size_t)t*129 + w2)*64);
#pragma unroll
    for (int j = 0; j < 8; ++j){
        float4 fa = frp[j*2], fb = frp[j*2+1];
        float4 ga = fip[j*2], gb = fip[j*2+1];
        float fr_[8] = {fa.x,fa.y,fa.z,fa.w,fb.x,fb.y,fb.z,fb.w};
        float fi_[8] = {ga.x,ga.y,ga.z,ga.w,gb.x,gb.y,gb.z,gb.w};
        float sjr = sr[j], sji = si[j];
#pragma unroll
        for (int kq = 0; kq < 8; ++kq){
            orr[kq] += sjr*fr_[kq] - sji*fi_[kq];
            oii[kq] += sjr*fi_[kq] + sji*fr_[kq];
        }
    }
    __syncthreads();
#pragma unroll
    for (int kq = 0; kq < 8; ++kq){ xr[kq][t] = orr[kq]; xi[kq][t] = oii[kq]; }
    __syncthreads();
#pragma unroll
    for (int c = 0; c < 8; ++c) fft256_lds(xr[c], xi[c], twc, tws, t, true);
    float4* wp = (float4*)(base + (size_t)t*8);
    wp[0] = make_float4(xr[0][t], xi[0][t], xr[1][t], xi[1][t]);
    wp[1] = make_float4(xr[2][t], xi[2][t], xr[3][t], xi[3][t]);
    wp[2] = make_float4(xr[4][t], xi[4][t], xr[5][t], xi[5][t]);
    wp[3] = make_float4(xr[6][t], xi[6][t], xr[7][t], xi[7][t]);
}

// ---- inverse rfft along W: Hermitian reconstruct + icfft, keep real -----
__global__ __launch_bounds__(256) void ifftw_kernel(
    const float2* __restrict__ spec, float* __restrict__ gu)
{
    __shared__ float twc[256], tws[256];
    __shared__ float sre[8][132], sim[8][132];
    __shared__ float xr[8][256], xi[8][256];
    int t = threadIdx.x;
    int n = blockIdx.x >> 8, h = blockIdx.x & 255;
    { float ang = -2.0f*3.14159265358979323846f*(float)t/256.0f;
      twc[t] = cosf(ang); tws[t] = sinf(ang); }
    for (int idx = t; idx < 129*8; idx += 256){
        int w2 = idx >> 3, c = idx & 7;
        float2 v = spec[(((size_t)n*129 + w2)*256 + h)*8 + c];
        sre[c][w2] = v.x; sim[c][w2] = v.y;
    }
    __syncthreads();
#pragma unroll
    for (int c = 0; c < 8; ++c){
        if (t <= 128){ xr[c][t] = sre[c][t];       xi[c][t] = sim[c][t]; }
        else         { xr[c][t] = sre[c][256-t];   xi[c][t] = -sim[c][256-t]; }
    }
    __syncthreads();
#pragma unroll
    for (int c = 0; c < 8; ++c) fft256_lds(xr[c], xi[c], twc, tws, t, true);
    const float s = 1.0f/65536.0f;   // 1/(H*W) irfftn normalization
    float* dst = gu + (size_t)blockIdx.x*2048 + t*8;
    ((float4*)dst)[0] = make_float4(xr[0][t]*s, xr[1][t]*s, xr[2][t]*s, xr[3][t]*s);
    ((float4*)dst)[1] = make_float4(xr[4][t]*s, xr[5][t]*s, xr[6][t]*s, xr[7][t]*s);
}

extern "C" void kernel_launch(void* const* d_in, const int* in_sizes, int n_in,
                              void* d_out, int out_size, void* d_ws, size_t ws_size,
                              hipStream_t stream) {
    const float* u_in = (const float*)d_in[0];
    const float* k_in = (const float*)d_in[1];
    const float* Wp[24];
    for (int i = 0; i < 24; ++i) Wp[i] = (const float*)d_in[2+i];
    const float* bias = (const float*)d_in[26];

    char* base = (char*)d_ws;
    float*  gmat = (float*) (base);                    // 64 MiB
    float*  dmat = (float*) (base + 67108864ull);      // 64 MiB
    float*  fre  = (float*) (base + 134217728ull);     // 8.06 MiB
    float*  fim  = (float*) (base + 142671872ull);     // 8.06 MiB
    float*  u0   = (float*) (base + 151126016ull);     // 8 MiB
    float*  u1   = (float*) (base + 159514624ull);     // 8 MiB
    float*  loc  = (float*) (base + 167903232ull);     // 8 MiB
    float*  du   = (float*) (base + 176291840ull);     // 8 MiB (du and gu share)
    float2* spec = (float2*)(base + 184680448ull);     // 32.25 MiB -> total ~208 MiB

    mlp_gd_kernel<<<1024, 256, 0, stream>>>(k_in,
        Wp[0],Wp[1],Wp[2],Wp[3],Wp[4],Wp[5],
        Wp[6],Wp[7],Wp[8],Wp[9],Wp[10],Wp[11], gmat, dmat);
    filt_kernel<<<129, 256, 0, stream>>>(
        Wp[12],Wp[13],Wp[14],Wp[15],Wp[16],Wp[17],
        Wp[18],Wp[19],Wp[20],Wp[21],Wp[22],Wp[23], fre, fim);

    const float* uc = u_in;
    float* un = u0;
    for (int it = 0; it < 4; ++it){
        pre_kernel <<<8192, 256, 0, stream>>>(uc, gmat, dmat, loc, du);
        fftw_kernel<<<1024, 256, 0, stream>>>(du, spec);
        ffth_mult_kernel<<<516, 256, 0, stream>>>(spec, fre, fim);
        ifftw_kernel<<<1024, 256, 0, stream>>>(spec, du);   // du becomes gu
        upd_kernel <<<8192, 256, 0, stream>>>(loc, du, gmat, un);
        uc = un; un = (un == u0) ? u1 : u0;
    }
    post_kernel<<<8192, 256, 0, stream>>>(uc, bias, (float*)d_out);
}

// Round 2
// 760.558 us; speedup vs baseline: 1.2573x; 1.2573x over previous
//
#include <hip/hip_runtime.h>
#include <math.h>

// Problem constants
#define NB 4
#define HB 256
#define WB 256
#define CB 8
#define NPIX (NB*HB*WB)   // 262144
#define W2B 129           // rfft bins along W
#define PI_F 3.14159265358979323846f

__device__ __forceinline__ float gelu_f(float x){
    // 0.5x(1+tanh(z)) == x*sigmoid(2z)
    float z = 0.7978845608028654f*(x + 0.044715f*x*x*x);
    return x / (1.0f + __expf(-2.0f*z));
}

__device__ __forceinline__ void ldcp(float* dst, const float* __restrict__ src, int n, int t){
    for (int i = t; i < n; i += 256) dst[i] = src[i];
}

// 3-layer MLP (2 -> 16 -> 16 -> 64), weights packed in LDS at sw:
// [0:32) w1, [32:48) b1, [48:304) w2, [304:320) b2, [320:1344) w3, [1344:1408) b3
// Output written with a caller-chosen stride (for transposed layouts).
__device__ __forceinline__ void mlp_store(const float* sw, float a, float b,
                                          float* __restrict__ dst, int stride, float scale){
    float h1[16], h2[16];
#pragma unroll
    for (int o = 0; o < 16; ++o)
        h1[o] = gelu_f(a*sw[o] + b*sw[16+o] + sw[32+o]);
#pragma unroll
    for (int o = 0; o < 16; ++o){
        float acc = sw[304+o];
#pragma unroll
        for (int i = 0; i < 16; ++i) acc += h1[i]*sw[48+i*16+o];
        h2[o] = gelu_f(acc);
    }
#pragma unroll
    for (int o = 0; o < 64; ++o){
        float acc = sw[1344+o];
#pragma unroll
        for (int i = 0; i < 16; ++i) acc += h2[i]*sw[320+i*64+o];
        dst[o*stride] = acc*scale;
    }
}

// ---- gamma/delta matrices from k: one thread per pixel ------------------
// Transposed panel layout: gmat[(pix>>6)*4096 + (j*8+k)*64 + (pix&63)]
__global__ __launch_bounds__(256) void mlp_gd_kernel(
    const float* __restrict__ kin,
    const float* gw1,const float* gb1,const float* gw2,const float* gb2,const float* gw3,const float* gb3,
    const float* dw1,const float* db1,const float* dw2,const float* db2,const float* dw3,const float* db3,
    float* __restrict__ gmat, float* __restrict__ dmat)
{
    __shared__ float sw[2816];
    int t = threadIdx.x;
    ldcp(sw+0,   gw1,  32, t); ldcp(sw+32,  gb1, 16, t);
    ldcp(sw+48,  gw2, 256, t); ldcp(sw+304, gb2, 16, t);
    ldcp(sw+320, gw3,1024, t); ldcp(sw+1344,gb3, 64, t);
    ldcp(sw+1408+0,   dw1,  32, t); ldcp(sw+1408+32,  db1, 16, t);
    ldcp(sw+1408+48,  dw2, 256, t); ldcp(sw+1408+304, db2, 16, t);
    ldcp(sw+1408+320, dw3,1024, t); ldcp(sw+1408+1344,db3, 64, t);
    __syncthreads();
    int pix = blockIdx.x*256 + t;
    float a = kin[(size_t)pix*2+0], b = kin[(size_t)pix*2+1];
    size_t base = (size_t)(pix >> 6)*4096 + (pix & 63);
    mlp_store(sw,      a, b, gmat + base, 64, 1.0f/64.0f);
    mlp_store(sw+1408, a, b, dmat + base, 64, 1.0f/64.0f);
}

// ---- spectral filter: fpack[w2][j*8+k][h][{re,im}] ----------------------
__global__ __launch_bounds__(256) void filt_kernel(
    const float* fw1,const float* fb1,const float* fw2,const float* fb2,const float* fw3,const float* fb3,
    const float* iw1,const float* ib1,const float* iw2,const float* ib2,const float* iw3,const float* ib3,
    float* __restrict__ fpack)
{
    __shared__ float sw[2816];
    int t = threadIdx.x;
    ldcp(sw+0,   fw1,  32, t); ldcp(sw+32,  fb1, 16, t);
    ldcp(sw+48,  fw2, 256, t); ldcp(sw+304, fb2, 16, t);
    ldcp(sw+320, fw3,1024, t); ldcp(sw+1344,fb3, 64, t);
    ldcp(sw+1408+0,   iw1,  32, t); ldcp(sw+1408+32,  ib1, 16, t);
    ldcp(sw+1408+48,  iw2, 256, t); ldcp(sw+1408+304, ib2, 16, t);
    ldcp(sw+1408+320, iw3,1024, t); ldcp(sw+1408+1344,ib3, 64, t);
    __syncthreads();
    int w2 = blockIdx.x;                        // 0..128 (kx)
    float x = (float)w2;                        // kx = rfftfreq*H
    float y = (float)(t < 128 ? t : t - 256);   // ky = fftfreq*W signed, t = h-freq
    float* base = fpack + (size_t)w2*32768 + (size_t)t*2;
    mlp_store(sw,      x, y, base,     512, 1.0f/64.0f);  // real parts
    mlp_store(sw+1408, x, y, base + 1, 512, 1.0f/64.0f);  // imag parts
}

// ---- 256-point FFT via 16x16 Cooley-Tukey, 256 threads, data in LDS -----
__device__ __forceinline__ void fft256_lds(float* re, float* im,
                                           const float* twc, const float* tws,
                                           int t, bool inv)
{
    int n2 = t >> 4, k1 = t & 15;
    float ar = 0.f, ai = 0.f;
#pragma unroll
    for (int n1 = 0; n1 < 16; ++n1){
        int m = (n1*k1*16) & 255;
        float c = twc[m], s = tws[m]; if (inv) s = -s;
        float xr = re[16*n1 + n2], xi = im[16*n1 + n2];
        ar += xr*c - xi*s;
        ai += xr*s + xi*c;
    }
    int m2 = (n2*k1) & 255;
    float c2 = twc[m2], s2 = tws[m2]; if (inv) s2 = -s2;
    float br = ar*c2 - ai*s2, bi = ar*s2 + ai*c2;
    __syncthreads();
    re[t] = br; im[t] = bi;
    __syncthreads();
    int k1b = t & 15, k2 = t >> 4;
    float xr2 = 0.f, xi2 = 0.f;
#pragma unroll
    for (int n2b = 0; n2b < 16; ++n2b){
        int m3 = (n2b*k2*16) & 255;
        float c3 = twc[m3], s3 = tws[m3]; if (inv) s3 = -s3;
        float br2 = re[n2b*16 + k1b], bi2 = im[n2b*16 + k1b];
        xr2 += br2*c3 - bi2*s3;
        xi2 += br2*s3 + bi2*c3;
    }
    __syncthreads();
    re[t] = xr2; im[t] = xi2;
    __syncthreads();
}

// ---- fused: pre (loc/du) + forward rfft along W -------------------------
// One block per (n,h) row. spec layout: [n][w2][h][c] float2
__global__ __launch_bounds__(256) void fftw_fused_kernel(
    const float* __restrict__ u, const float* __restrict__ gmat,
    const float* __restrict__ dmat, float* __restrict__ loc,
    float2* __restrict__ spec)
{
    __shared__ float twc[256], tws[256];
    __shared__ float xr[8][256], xi[8][256];
    int t = threadIdx.x;
    int bid = blockIdx.x;             // n*256 + h
    int n = bid >> 8, h = bid & 255;
    { float ang = -2.0f*PI_F*(float)t/256.0f;
      twc[t] = cosf(ang); tws[t] = sinf(ang); }

    const float* up = u + (size_t)bid*2048 + (size_t)t*8;
    float4 ua = ((const float4*)up)[0], ub = ((const float4*)up)[1];
    float uv[8] = {ua.x,ua.y,ua.z,ua.w, ub.x,ub.y,ub.z,ub.w};

    const float* gp = gmat + ((size_t)bid*4 + (t>>6))*4096 + (t&63);
    const float* dp = dmat + ((size_t)bid*4 + (t>>6))*4096 + (t&63);
    float lg[8], dv[8];
#pragma unroll
    for (int k = 0; k < 8; ++k){ lg[k] = 2.0f*uv[k]; dv[k] = 0.f; }
#pragma unroll
    for (int j = 0; j < 8; ++j){
        float uj = uv[j];
#pragma unroll
        for (int k = 0; k < 8; ++k){
            lg[k] -= uj * gp[(j*8+k)*64];
            dv[k] += uj * dp[(j*8+k)*64];
        }
    }
    float* lp = loc + (size_t)bid*2048 + (size_t)t*8;
    ((float4*)lp)[0] = make_float4(lg[0],lg[1],lg[2],lg[3]);
    ((float4*)lp)[1] = make_float4(lg[4],lg[5],lg[6],lg[7]);

#pragma unroll
    for (int c = 0; c < 8; ++c){ xr[c][t] = dv[c]; xi[c][t] = 0.f; }
    __syncthreads();
#pragma unroll
    for (int c = 0; c < 8; ++c) fft256_lds(xr[c], xi[c], twc, tws, t, false);
    if (t < 129){
        float4* dst = (float4*)(spec + (((size_t)n*129 + t)*256 + h)*8);
        dst[0] = make_float4(xr[0][t], xi[0][t], xr[1][t], xi[1][t]);
        dst[1] = make_float4(xr[2][t], xi[2][t], xr[3][t], xi[3][t]);
        dst[2] = make_float4(xr[4][t], xi[4][t], xr[5][t], xi[5][t]);
        dst[3] = make_float4(xr[6][t], xi[6][t], xr[7][t], xi[7][t]);
    }
}

// ---- fused: cfft along H -> per-frequency 8x8 complex mat -> icfft ------
// One block per (n,w2); thread t owns H-frequency bin h=t.
__global__ __launch_bounds__(256) void ffth_mult_kernel(
    float2* __restrict__ spec, const float* __restrict__ fpack)
{
    __shared__ float twc[256], tws[256];
    __shared__ float xr[8][256], xi[8][256];
    int t = threadIdx.x;
    int n = blockIdx.x / 129, w2 = blockIdx.x % 129;
    { float ang = -2.0f*PI_F*(float)t/256.0f;
      twc[t] = cosf(ang); tws[t] = sinf(ang); }
    float2* base = spec + ((size_t)(n*129 + w2))*256*8;
    const float4* rp = (const float4*)(base + (size_t)t*8);
    float4 r0 = rp[0], r1 = rp[1], r2 = rp[2], r3 = rp[3];
    xr[0][t]=r0.x; xi[0][t]=r0.y; xr[1][t]=r0.z; xi[1][t]=r0.w;
    xr[2][t]=r1.x; xi[2][t]=r1.y; xr[3][t]=r1.z; xi[3][t]=r1.w;
    xr[4][t]=r2.x; xi[4][t]=r2.y; xr[5][t]=r2.z; xi[5][t]=r2.w;
    xr[6][t]=r3.x; xi[6][t]=r3.y; xr[7][t]=r3.z; xi[7][t]=r3.w;
    __syncthreads();
#pragma unroll
    for (int c = 0; c < 8; ++c) fft256_lds(xr[c], xi[c], twc, tws, t, false);

    float sr[8], si[8], orr[8], oii[8];
#pragma unroll
    for (int j = 0; j < 8; ++j){ sr[j] = xr[j][t]; si[j] = xi[j][t]; }
#pragma unroll
    for (int kq = 0; kq < 8; ++kq){ orr[kq] = 0.f; oii[kq] = 0.f; }
    // fpack[w2][jk][h=t][{re,im}] -> coalesced float2 loads per (j,k)
    const float2* fp = (const float2*)fpack + (size_t)w2*16384 + t;
#pragma unroll
    for (int j = 0; j < 8; ++j){
        float sjr = sr[j], sji = si[j];
#pragma unroll
        for (int kq = 0; kq < 8; ++kq){
            float2 f = fp[(j*8+kq)*256];
            orr[kq] += sjr*f.x - sji*f.y;
            oii[kq] += sjr*f.y + sji*f.x;
        }
    }
    __syncthreads();
#pragma unroll
    for (int kq = 0; kq < 8; ++kq){ xr[kq][t] = orr[kq]; xi[kq][t] = oii[kq]; }
    __syncthreads();
#pragma unroll
    for (int c = 0; c < 8; ++c) fft256_lds(xr[c], xi[c], twc, tws, t, true);
    float4* wp = (float4*)(base + (size_t)t*8);
    wp[0] = make_float4(xr[0][t], xi[0][t], xr[1][t], xi[1][t]);
    wp[1] = make_float4(xr[2][t], xi[2][t], xr[3][t], xi[3][t]);
    wp[2] = make_float4(xr[4][t], xi[4][t], xr[5][t], xi[5][t]);
    wp[3] = make_float4(xr[6][t], xi[6][t], xr[7][t], xi[7][t]);
}

// ---- fused: Hermitian + icfft along W -> upd (+ last-iter gelu+bias) ----
__global__ __launch_bounds__(256) void ifftw_fused_kernel(
    const float2* __restrict__ spec, const float* __restrict__ loc,
    const float* __restrict__ gmat, const float* __restrict__ bias,
    float* __restrict__ dst, int last)
{
    __shared__ float twc[256], tws[256];
    __shared__ float sre[8][132], sim[8][132];
    __shared__ float xr[8][256], xi[8][256];
    int t = threadIdx.x;
    int bid = blockIdx.x;             // n*256 + h
    int n = bid >> 8, h = bid & 255;
    { float ang = -2.0f*PI_F*(float)t/256.0f;
      twc[t] = cosf(ang); tws[t] = sinf(ang); }
    for (int idx = t; idx < 129*8; idx += 256){
        int w2 = idx >> 3, c = idx & 7;
        float2 v = spec[(((size_t)n*129 + w2)*256 + h)*8 + c];
        sre[c][w2] = v.x; sim[c][w2] = v.y;
    }
    __syncthreads();
#pragma unroll
    for (int c = 0; c < 8; ++c){
        if (t <= 128){ xr[c][t] = sre[c][t];       xi[c][t] = sim[c][t]; }
        else         { xr[c][t] = sre[c][256-t];   xi[c][t] = -sim[c][256-t]; }
    }
    __syncthreads();
#pragma unroll
    for (int c = 0; c < 8; ++c) fft256_lds(xr[c], xi[c], twc, tws, t, true);

    const float s = 1.0f/65536.0f;    // irfftn normalization
    float gu[8];
#pragma unroll
    for (int c = 0; c < 8; ++c) gu[c] = xr[c][t]*s;

    const float* lp = loc + (size_t)bid*2048 + (size_t)t*8;
    float4 la = ((const float4*)lp)[0], lb = ((const float4*)lp)[1];
    float acc[8] = {la.x,la.y,la.z,la.w, lb.x,lb.y,lb.z,lb.w};
    const float* gp = gmat + ((size_t)bid*4 + (t>>6))*4096 + (t&63);
#pragma unroll
    for (int j = 0; j < 8; ++j){
        float gj = gu[j];
#pragma unroll
        for (int k = 0; k < 8; ++k) acc[k] += gj * gp[(j*8+k)*64];
    }
    float* op = dst + (size_t)bid*2048 + (size_t)t*8;
    if (last){
#pragma unroll
        for (int k = 0; k < 8; ++k) acc[k] = gelu_f(acc[k] + bias[k]);
    }
    ((float4*)op)[0] = make_float4(acc[0],acc[1],acc[2],acc[3]);
    ((float4*)op)[1] = make_float4(acc[4],acc[5],acc[6],acc[7]);
}

extern "C" void kernel_launch(void* const* d_in, const int* in_sizes, int n_in,
                              void* d_out, int out_size, void* d_ws, size_t ws_size,
                              hipStream_t stream) {
    const float* u_in = (const float*)d_in[0];
    const float* k_in = (const float*)d_in[1];
    const float* Wp[24];
    for (int i = 0; i < 24; ++i) Wp[i] = (const float*)d_in[2+i];
    const float* bias = (const float*)d_in[26];

    char* base = (char*)d_ws;
    float*  gmat  = (float*) (base);                    // 64 MiB
    float*  dmat  = (float*) (base + 67108864ull);      // 64 MiB
    float*  fpack = (float*) (base + 134217728ull);     // 16.9 MB (129*64*256*2 f32)
    float*  u0    = (float*) (base + 151126016ull);     // 8 MiB
    float*  u1    = (float*) (base + 159514624ull);     // 8 MiB
    float*  loc   = (float*) (base + 167903232ull);     // 8 MiB
    float2* spec  = (float2*)(base + 176291840ull);     // 8.45 MB -> total ~185 MB

    mlp_gd_kernel<<<1024, 256, 0, stream>>>(k_in,
        Wp[0],Wp[1],Wp[2],Wp[3],Wp[4],Wp[5],
        Wp[6],Wp[7],Wp[8],Wp[9],Wp[10],Wp[11], gmat, dmat);
    filt_kernel<<<129, 256, 0, stream>>>(
        Wp[12],Wp[13],Wp[14],Wp[15],Wp[16],Wp[17],
        Wp[18],Wp[19],Wp[20],Wp[21],Wp[22],Wp[23], fpack);

    const float* uc = u_in;
    float* un = u0;
    for (int it = 0; it < 4; ++it){
        int last = (it == 3);
        fftw_fused_kernel<<<1024, 256, 0, stream>>>(uc, gmat, dmat, loc, spec);
        ffth_mult_kernel <<<516, 256, 0, stream>>>(spec, fpack);
        ifftw_fused_kernel<<<1024, 256, 0, stream>>>(spec, loc, gmat, bias,
                                                     last ? (float*)d_out : un, last);
        uc = un; un = (un == u0) ? u1 : u0;
    }
}

// Round 3
// 361.675 us; speedup vs baseline: 2.6439x; 2.1029x over previous
//
#include <hip/hip_runtime.h>
#include <math.h>

// Problem constants
#define NB 4
#define HB 256
#define WB 256
#define CB 8
#define NPIX (NB*HB*WB)   // 262144
#define W2B 129           // rfft bins along W
#define TWO_PI_F 6.283185307179586f

__device__ __forceinline__ float gelu_f(float x){
    // 0.5x(1+tanh(z)) == x*sigmoid(2z)
    float z = 0.7978845608028654f*(x + 0.044715f*x*x*x);
    return x / (1.0f + __expf(-2.0f*z));
}

__device__ __forceinline__ void ldcp(float* dst, const float* __restrict__ src, int n, int t){
    for (int i = t; i < n; i += 256) dst[i] = src[i];
}

// 3-layer MLP (2 -> 16 -> 16 -> 64), weights packed in LDS at sw:
// [0:32) w1, [32:48) b1, [48:304) w2, [304:320) b2, [320:1344) w3, [1344:1408) b3
__device__ __forceinline__ void mlp_store(const float* sw, float a, float b,
                                          float* __restrict__ dst, int stride, float scale){
    float h1[16], h2[16];
#pragma unroll
    for (int o = 0; o < 16; ++o)
        h1[o] = gelu_f(a*sw[o] + b*sw[16+o] + sw[32+o]);
#pragma unroll
    for (int o = 0; o < 16; ++o){
        float acc = sw[304+o];
#pragma unroll
        for (int i = 0; i < 16; ++i) acc += h1[i]*sw[48+i*16+o];
        h2[o] = gelu_f(acc);
    }
#pragma unroll
    for (int o = 0; o < 64; ++o){
        float acc = sw[1344+o];
#pragma unroll
        for (int i = 0; i < 16; ++i) acc += h2[i]*sw[320+i*64+o];
        dst[o*stride] = acc*scale;
    }
}

// ---- gamma/delta matrices from k: one thread per pixel ------------------
// Transposed panel layout: gmat[(pix>>6)*4096 + (j*8+k)*64 + (pix&63)]
__global__ __launch_bounds__(256) void mlp_gd_kernel(
    const float* __restrict__ kin,
    const float* gw1,const float* gb1,const float* gw2,const float* gb2,const float* gw3,const float* gb3,
    const float* dw1,const float* db1,const float* dw2,const float* db2,const float* dw3,const float* db3,
    float* __restrict__ gmat, float* __restrict__ dmat)
{
    __shared__ float sw[2816];
    int t = threadIdx.x;
    ldcp(sw+0,   gw1,  32, t); ldcp(sw+32,  gb1, 16, t);
    ldcp(sw+48,  gw2, 256, t); ldcp(sw+304, gb2, 16, t);
    ldcp(sw+320, gw3,1024, t); ldcp(sw+1344,gb3, 64, t);
    ldcp(sw+1408+0,   dw1,  32, t); ldcp(sw+1408+32,  db1, 16, t);
    ldcp(sw+1408+48,  dw2, 256, t); ldcp(sw+1408+304, db2, 16, t);
    ldcp(sw+1408+320, dw3,1024, t); ldcp(sw+1408+1344,db3, 64, t);
    __syncthreads();
    int pix = blockIdx.x*256 + t;
    float a = kin[(size_t)pix*2+0], b = kin[(size_t)pix*2+1];
    size_t base = (size_t)(pix >> 6)*4096 + (pix & 63);
    mlp_store(sw,      a, b, gmat + base, 64, 1.0f/64.0f);
    mlp_store(sw+1408, a, b, dmat + base, 64, 1.0f/64.0f);
}

// ---- spectral filter: fpack[w2][j*8+k][h][{re,im}] ----------------------
__global__ __launch_bounds__(256) void filt_kernel(
    const float* fw1,const float* fb1,const float* fw2,const float* fb2,const float* fw3,const float* fb3,
    const float* iw1,const float* ib1,const float* iw2,const float* ib2,const float* iw3,const float* ib3,
    float* __restrict__ fpack)
{
    __shared__ float sw[2816];
    int t = threadIdx.x;
    ldcp(sw+0,   fw1,  32, t); ldcp(sw+32,  fb1, 16, t);
    ldcp(sw+48,  fw2, 256, t); ldcp(sw+304, fb2, 16, t);
    ldcp(sw+320, fw3,1024, t); ldcp(sw+1344,fb3, 64, t);
    ldcp(sw+1408+0,   iw1,  32, t); ldcp(sw+1408+32,  ib1, 16, t);
    ldcp(sw+1408+48,  iw2, 256, t); ldcp(sw+1408+304, ib2, 16, t);
    ldcp(sw+1408+320, iw3,1024, t); ldcp(sw+1408+1344,ib3, 64, t);
    __syncthreads();
    int w2 = blockIdx.x;                        // 0..128 (kx)
    float x = (float)w2;                        // kx = rfftfreq*H
    float y = (float)(t < 128 ? t : t - 256);   // ky = fftfreq*W signed, t = h-freq
    float* base = fpack + (size_t)w2*32768 + (size_t)t*2;
    mlp_store(sw,      x, y, base,     512, 1.0f/64.0f);  // real parts
    mlp_store(sw+1408, x, y, base + 1, 512, 1.0f/64.0f);  // imag parts
}

// ---- 256-pt FFT, 16x16 Cooley-Tukey, CH channels/thread batched ---------
// Register twiddles (sincos + rotation recurrence); 4 barriers total.
// sgn = -1 forward, +1 inverse (unnormalized).
template<int CH, bool REAL_IN, bool REAL_OUT>
__device__ __forceinline__ void fft256_batch(
    float (*xr)[256], float (*xi)[256], int c0, int t, float sgn)
{
    int n2 = t >> 4, k1 = t & 15;
    float csA, snA; __sincosf(sgn*TWO_PI_F*(float)k1*(1.0f/16.0f), &snA, &csA);
    float ar[CH], ai[CH];
#pragma unroll
    for (int c = 0; c < CH; ++c){ ar[c]=0.f; ai[c]=0.f; }
    float cw = 1.f, sw = 0.f;
#pragma unroll
    for (int n1 = 0; n1 < 16; ++n1){
#pragma unroll
        for (int c = 0; c < CH; ++c){
            float xrv = xr[c0+c][16*n1+n2];
            if (REAL_IN){
                ar[c] += xrv*cw; ai[c] += xrv*sw;
            } else {
                float xiv = xi[c0+c][16*n1+n2];
                ar[c] += xrv*cw - xiv*sw;
                ai[c] += xrv*sw + xiv*cw;
            }
        }
        float cn = cw*csA - sw*snA;
        sw = cw*snA + sw*csA; cw = cn;
    }
    float cs2, sn2; __sincosf(sgn*TWO_PI_F*(float)(n2*k1)*(1.0f/256.0f), &sn2, &cs2);
#pragma unroll
    for (int c = 0; c < CH; ++c){
        float br = ar[c]*cs2 - ai[c]*sn2;
        float bi = ar[c]*sn2 + ai[c]*cs2;
        ar[c] = br; ai[c] = bi;
    }
    __syncthreads();
#pragma unroll
    for (int c = 0; c < CH; ++c){ xr[c0+c][t] = ar[c]; xi[c0+c][t] = ai[c]; }
    __syncthreads();
    int k1b = t & 15, k2 = t >> 4;
    float csB, snB; __sincosf(sgn*TWO_PI_F*(float)k2*(1.0f/16.0f), &snB, &csB);
    float yr[CH], yi[CH];
#pragma unroll
    for (int c = 0; c < CH; ++c){ yr[c]=0.f; yi[c]=0.f; }
    cw = 1.f; sw = 0.f;
#pragma unroll
    for (int n2b = 0; n2b < 16; ++n2b){
#pragma unroll
        for (int c = 0; c < CH; ++c){
            float br = xr[c0+c][n2b*16+k1b];
            float bi = xi[c0+c][n2b*16+k1b];
            yr[c] += br*cw - bi*sw;
            if (!REAL_OUT) yi[c] += br*sw + bi*cw;
        }
        float cn = cw*csB - sw*snB;
        sw = cw*snB + sw*csB; cw = cn;
    }
    __syncthreads();
#pragma unroll
    for (int c = 0; c < CH; ++c){ xr[c0+c][t] = yr[c]; if (!REAL_OUT) xi[c0+c][t] = yi[c]; }
    __syncthreads();
}

// ---- fused: pre (loc/du) + forward rfft along W -------------------------
// One block per (n,h) row. spec layout: [n][w2][h][c] float2
__global__ __launch_bounds__(256) void fftw_fused_kernel(
    const float* __restrict__ u, const float* __restrict__ gmat,
    const float* __restrict__ dmat, float* __restrict__ loc,
    float2* __restrict__ spec)
{
    __shared__ float xr[8][256], xi[8][256];
    int t = threadIdx.x;
    int bid = blockIdx.x;             // n*256 + h
    int n = bid >> 8, h = bid & 255;

    const float* up = u + (size_t)bid*2048 + (size_t)t*8;
    float4 ua = ((const float4*)up)[0], ub = ((const float4*)up)[1];
    float uv[8] = {ua.x,ua.y,ua.z,ua.w, ub.x,ub.y,ub.z,ub.w};

    const float* gp = gmat + ((size_t)bid*4 + (t>>6))*4096 + (t&63);
    const float* dp = dmat + ((size_t)bid*4 + (t>>6))*4096 + (t&63);
    float lg[8], dv[8];
#pragma unroll
    for (int k = 0; k < 8; ++k){ lg[k] = 2.0f*uv[k]; dv[k] = 0.f; }
#pragma unroll
    for (int j = 0; j < 8; ++j){
        float uj = uv[j];
#pragma unroll
        for (int k = 0; k < 8; ++k){
            lg[k] -= uj * gp[(j*8+k)*64];
            dv[k] += uj * dp[(j*8+k)*64];
        }
    }
    float* lp = loc + (size_t)bid*2048 + (size_t)t*8;
    ((float4*)lp)[0] = make_float4(lg[0],lg[1],lg[2],lg[3]);
    ((float4*)lp)[1] = make_float4(lg[4],lg[5],lg[6],lg[7]);

#pragma unroll
    for (int c = 0; c < 8; ++c) xr[c][t] = dv[c];
    __syncthreads();
    fft256_batch<8, true, false>(xr, xi, 0, t, -1.f);
    if (t < 129){
        float4* dst = (float4*)(spec + (((size_t)n*129 + t)*256 + h)*8);
        dst[0] = make_float4(xr[0][t], xi[0][t], xr[1][t], xi[1][t]);
        dst[1] = make_float4(xr[2][t], xi[2][t], xr[3][t], xi[3][t]);
        dst[2] = make_float4(xr[4][t], xi[4][t], xr[5][t], xi[5][t]);
        dst[3] = make_float4(xr[6][t], xi[6][t], xr[7][t], xi[7][t]);
    }
}

// ---- fused: cfft along H -> per-frequency 8x8 complex mat -> icfft ------
// One block per (n,w2); 512 threads: group g=tid>>8 owns channels 4g..4g+3.
__global__ __launch_bounds__(512) void ffth_mult_kernel(
    float2* __restrict__ spec, const float* __restrict__ fpack)
{
    __shared__ float xr[8][256], xi[8][256];
    int tid = threadIdx.x;
    int t = tid & 255, g = tid >> 8;
    int c0 = g*4;
    int n = blockIdx.x / 129, w2 = blockIdx.x % 129;
    float2* base = spec + ((size_t)(n*129 + w2))*2048;
    const float4* rp = (const float4*)(base + (size_t)t*8);
    float4 ra = rp[g*2], rb = rp[g*2+1];
    xr[c0+0][t]=ra.x; xi[c0+0][t]=ra.y; xr[c0+1][t]=ra.z; xi[c0+1][t]=ra.w;
    xr[c0+2][t]=rb.x; xi[c0+2][t]=rb.y; xr[c0+3][t]=rb.z; xi[c0+3][t]=rb.w;
    __syncthreads();
    fft256_batch<4, false, false>(xr, xi, c0, t, -1.f);

    // per-frequency complex 8x8: group g computes out channels c0..c0+3
    float sr[8], si[8];
#pragma unroll
    for (int j = 0; j < 8; ++j){ sr[j] = xr[j][t]; si[j] = xi[j][t]; }
    float orr[4], oii[4];
#pragma unroll
    for (int kq = 0; kq < 4; ++kq){ orr[kq]=0.f; oii[kq]=0.f; }
    const float2* fp = (const float2*)fpack + (size_t)w2*16384 + t;
#pragma unroll
    for (int j = 0; j < 8; ++j){
        float sjr = sr[j], sji = si[j];
#pragma unroll
        for (int kq = 0; kq < 4; ++kq){
            float2 f = fp[(j*8 + c0 + kq)*256];
            orr[kq] += sjr*f.x - sji*f.y;
            oii[kq] += sjr*f.y + sji*f.x;
        }
    }
    __syncthreads();
#pragma unroll
    for (int kq = 0; kq < 4; ++kq){ xr[c0+kq][t] = orr[kq]; xi[c0+kq][t] = oii[kq]; }
    __syncthreads();
    fft256_batch<4, false, false>(xr, xi, c0, t, +1.f);
    float4* wp = (float4*)(base + (size_t)t*8);
    wp[g*2]   = make_float4(xr[c0+0][t], xi[c0+0][t], xr[c0+1][t], xi[c0+1][t]);
    wp[g*2+1] = make_float4(xr[c0+2][t], xi[c0+2][t], xr[c0+3][t], xi[c0+3][t]);
}

// ---- fused: Hermitian + icfft along W -> upd (+ last-iter gelu+bias) ----
__global__ __launch_bounds__(256) void ifftw_fused_kernel(
    const float2* __restrict__ spec, const float* __restrict__ loc,
    const float* __restrict__ gmat, const float* __restrict__ bias,
    float* __restrict__ dst, int last)
{
    __shared__ float sre[8][132], sim[8][132];
    __shared__ float xr[8][256], xi[8][256];
    int t = threadIdx.x;
    int bid = blockIdx.x;             // n*256 + h
    int n = bid >> 8, h = bid & 255;
    for (int idx = t; idx < 129*8; idx += 256){
        int w2 = idx >> 3, c = idx & 7;
        float2 v = spec[(((size_t)n*129 + w2)*256 + h)*8 + c];
        sre[c][w2] = v.x; sim[c][w2] = v.y;
    }
    __syncthreads();
#pragma unroll
    for (int c = 0; c < 8; ++c){
        if (t <= 128){ xr[c][t] = sre[c][t];       xi[c][t] = sim[c][t]; }
        else         { xr[c][t] = sre[c][256-t];   xi[c][t] = -sim[c][256-t]; }
    }
    __syncthreads();
    fft256_batch<8, false, true>(xr, xi, 0, t, +1.f);

    const float s = 1.0f/65536.0f;    // irfftn normalization
    float gu[8];
#pragma unroll
    for (int c = 0; c < 8; ++c) gu[c] = xr[c][t]*s;

    const float* lp = loc + (size_t)bid*2048 + (size_t)t*8;
    float4 la = ((const float4*)lp)[0], lb = ((const float4*)lp)[1];
    float acc[8] = {la.x,la.y,la.z,la.w, lb.x,lb.y,lb.z,lb.w};
    const float* gp = gmat + ((size_t)bid*4 + (t>>6))*4096 + (t&63);
#pragma unroll
    for (int j = 0; j < 8; ++j){
        float gj = gu[j];
#pragma unroll
        for (int k = 0; k < 8; ++k) acc[k] += gj * gp[(j*8+k)*64];
    }
    float* op = dst + (size_t)bid*2048 + (size_t)t*8;
    if (last){
#pragma unroll
        for (int k = 0; k < 8; ++k) acc[k] = gelu_f(acc[k] + bias[k]);
    }
    ((float4*)op)[0] = make_float4(acc[0],acc[1],acc[2],acc[3]);
    ((float4*)op)[1] = make_float4(acc[4],acc[5],acc[6],acc[7]);
}

extern "C" void kernel_launch(void* const* d_in, const int* in_sizes, int n_in,
                              void* d_out, int out_size, void* d_ws, size_t ws_size,
                              hipStream_t stream) {
    const float* u_in = (const float*)d_in[0];
    const float* k_in = (const float*)d_in[1];
    const float* Wp[24];
    for (int i = 0; i < 24; ++i) Wp[i] = (const float*)d_in[2+i];
    const float* bias = (const float*)d_in[26];

    char* base = (char*)d_ws;
    float*  gmat  = (float*) (base);                    // 64 MiB
    float*  dmat  = (float*) (base + 67108864ull);      // 64 MiB
    float*  fpack = (float*) (base + 134217728ull);     // 16.9 MB (129*64*256*2 f32)
    float*  u0    = (float*) (base + 151126016ull);     // 8 MiB
    float*  u1    = (float*) (base + 159514624ull);     // 8 MiB
    float*  loc   = (float*) (base + 167903232ull);     // 8 MiB
    float2* spec  = (float2*)(base + 176291840ull);     // 8.45 MB -> total ~185 MB

    mlp_gd_kernel<<<1024, 256, 0, stream>>>(k_in,
        Wp[0],Wp[1],Wp[2],Wp[3],Wp[4],Wp[5],
        Wp[6],Wp[7],Wp[8],Wp[9],Wp[10],Wp[11], gmat, dmat);
    filt_kernel<<<129, 256, 0, stream>>>(
        Wp[12],Wp[13],Wp[14],Wp[15],Wp[16],Wp[17],
        Wp[18],Wp[19],Wp[20],Wp[21],Wp[22],Wp[23], fpack);

    const float* uc = u_in;
    float* un = u0;
    for (int it = 0; it < 4; ++it){
        int last = (it == 3);
        fftw_fused_kernel<<<1024, 256, 0, stream>>>(uc, gmat, dmat, loc, spec);
        ffth_mult_kernel <<<516, 512, 0, stream>>>(spec, fpack);
        ifftw_fused_kernel<<<1024, 256, 0, stream>>>(spec, loc, gmat, bias,
                                                     last ? (float*)d_out : un, last);
        uc = un; un = (un == u0) ? u1 : u0;
    }
}

// Round 4
// 299.324 us; speedup vs baseline: 3.1946x; 1.2083x over previous
//
#include <hip/hip_runtime.h>
#include <math.h>

// Problem constants
#define NB 4
#define HB 256
#define WB 256
#define CB 8
#define NPIX (NB*HB*WB)   // 262144
#define W2B 129           // rfft bins along W
#define TWO_PI_F 6.283185307179586f

__device__ __forceinline__ float gelu_f(float x){
    float z = 0.7978845608028654f*(x + 0.044715f*x*x*x);
    return x / (1.0f + __expf(-2.0f*z));
}

__device__ __forceinline__ unsigned pack_bf16x2(float a, float b){
    unsigned ua = __float_as_uint(a), ub = __float_as_uint(b);
    ua = (ua + 0x7FFFu + ((ua >> 16) & 1u)) >> 16;
    ub = (ub + 0x7FFFu + ((ub >> 16) & 1u)) >> 16;
    return ua | (ub << 16);
}
__device__ __forceinline__ float2 unpack_bf16x2(unsigned v){
    return make_float2(__uint_as_float(v << 16), __uint_as_float(v & 0xFFFF0000u));
}

__device__ __forceinline__ void ldcp(float* dst, const float* __restrict__ src, int n, int t){
    for (int i = t; i < n; i += 256) dst[i] = src[i];
}

// layers 1+2 of MLP (2->16->16), weights in LDS at sw
__device__ __forceinline__ void mlp_h2(const float* sw, float a, float b, float* h2){
    float h1[16];
#pragma unroll
    for (int o = 0; o < 16; ++o)
        h1[o] = gelu_f(a*sw[o] + b*sw[16+o] + sw[32+o]);
#pragma unroll
    for (int o = 0; o < 16; ++o){
        float acc = sw[304+o];
#pragma unroll
        for (int i = 0; i < 16; ++i) acc += h1[i]*sw[48+i*16+o];
        h2[o] = gelu_f(acc);
    }
}

// full MLP with f32 strided store (for the spectral filter)
__device__ __forceinline__ void mlp_store(const float* sw, float a, float b,
                                          float* __restrict__ dst, int stride, float scale){
    float h2[16];
    mlp_h2(sw, a, b, h2);
#pragma unroll
    for (int o = 0; o < 64; ++o){
        float acc = sw[1344+o];
#pragma unroll
        for (int i = 0; i < 16; ++i) acc += h2[i]*sw[320+i*64+o];
        dst[o*stride] = acc*scale;
    }
}

// final layer -> packed bf16 pairs into panel layout
__device__ __forceinline__ void mlp_store_bf16(const float* sw, const float* h2,
                                               unsigned* __restrict__ dst, float scale){
#pragma unroll
    for (int o = 0; o < 64; o += 2){
        float a0 = sw[1344+o], a1 = sw[1344+o+1];
#pragma unroll
        for (int i = 0; i < 16; ++i){
            a0 += h2[i]*sw[320+i*64+o];
            a1 += h2[i]*sw[320+i*64+o+1];
        }
        dst[(o>>1)*64] = pack_bf16x2(a0*scale, a1*scale);
    }
}

// ---- gamma/delta matrices from k --------------------------------------
// bf16 pair panel layout: mat[(pix>>6)*2048 + (j*4 + (k>>1))*64 + (pix&63)]
// each uint = {k even, k odd} bf16 pair.
__global__ __launch_bounds__(256) void mlp_gd_kernel(
    const float* __restrict__ kin,
    const float* gw1,const float* gb1,const float* gw2,const float* gb2,const float* gw3,const float* gb3,
    const float* dw1,const float* db1,const float* dw2,const float* db2,const float* dw3,const float* db3,
    unsigned* __restrict__ gmat, unsigned* __restrict__ dmat)
{
    __shared__ float sw[2816];
    int t = threadIdx.x;
    ldcp(sw+0,   gw1,  32, t); ldcp(sw+32,  gb1, 16, t);
    ldcp(sw+48,  gw2, 256, t); ldcp(sw+304, gb2, 16, t);
    ldcp(sw+320, gw3,1024, t); ldcp(sw+1344,gb3, 64, t);
    ldcp(sw+1408+0,   dw1,  32, t); ldcp(sw+1408+32,  db1, 16, t);
    ldcp(sw+1408+48,  dw2, 256, t); ldcp(sw+1408+304, db2, 16, t);
    ldcp(sw+1408+320, dw3,1024, t); ldcp(sw+1408+1344,db3, 64, t);
    __syncthreads();
    int pix = blockIdx.x*256 + t;
    float a = kin[(size_t)pix*2+0], b = kin[(size_t)pix*2+1];
    size_t base = (size_t)(pix >> 6)*2048 + (pix & 63);
    float h2[16];
    mlp_h2(sw, a, b, h2);
    mlp_store_bf16(sw, h2, gmat + base, 1.0f/64.0f);
    mlp_h2(sw+1408, a, b, h2);
    mlp_store_bf16(sw+1408, h2, dmat + base, 1.0f/64.0f);
}

// ---- spectral filter: fpack[w2][j*8+k][h][{re,im}] (f32) ---------------
__global__ __launch_bounds__(256) void filt_kernel(
    const float* fw1,const float* fb1,const float* fw2,const float* fb2,const float* fw3,const float* fb3,
    const float* iw1,const float* ib1,const float* iw2,const float* ib2,const float* iw3,const float* ib3,
    float* __restrict__ fpack)
{
    __shared__ float sw[2816];
    int t = threadIdx.x;
    ldcp(sw+0,   fw1,  32, t); ldcp(sw+32,  fb1, 16, t);
    ldcp(sw+48,  fw2, 256, t); ldcp(sw+304, fb2, 16, t);
    ldcp(sw+320, fw3,1024, t); ldcp(sw+1344,fb3, 64, t);
    ldcp(sw+1408+0,   iw1,  32, t); ldcp(sw+1408+32,  ib1, 16, t);
    ldcp(sw+1408+48,  iw2, 256, t); ldcp(sw+1408+304, ib2, 16, t);
    ldcp(sw+1408+320, iw3,1024, t); ldcp(sw+1408+1344,ib3, 64, t);
    __syncthreads();
    int w2 = blockIdx.x;                        // 0..128 (kx)
    float x = (float)w2;
    float y = (float)(t < 128 ? t : t - 256);   // ky signed, t = h-freq
    float* base = fpack + (size_t)w2*32768 + (size_t)t*2;
    mlp_store(sw,      x, y, base,     512, 1.0f/64.0f);  // real
    mlp_store(sw+1408, x, y, base + 1, 512, 1.0f/64.0f);  // imag
}

// ---- 256-pt FFT, 16x16 Cooley-Tukey, CH channels/thread batched --------
template<int CH, bool REAL_IN, bool REAL_OUT>
__device__ __forceinline__ void fft256_batch(
    float (*xr)[256], float (*xi)[256], int c0, int t, float sgn)
{
    int n2 = t >> 4, k1 = t & 15;
    float csA, snA; __sincosf(sgn*TWO_PI_F*(float)k1*(1.0f/16.0f), &snA, &csA);
    float ar[CH], ai[CH];
#pragma unroll
    for (int c = 0; c < CH; ++c){ ar[c]=0.f; ai[c]=0.f; }
    float cw = 1.f, sw = 0.f;
#pragma unroll
    for (int n1 = 0; n1 < 16; ++n1){
#pragma unroll
        for (int c = 0; c < CH; ++c){
            float xrv = xr[c0+c][16*n1+n2];
            if (REAL_IN){
                ar[c] += xrv*cw; ai[c] += xrv*sw;
            } else {
                float xiv = xi[c0+c][16*n1+n2];
                ar[c] += xrv*cw - xiv*sw;
                ai[c] += xrv*sw + xiv*cw;
            }
        }
        float cn = cw*csA - sw*snA;
        sw = cw*snA + sw*csA; cw = cn;
    }
    float cs2, sn2; __sincosf(sgn*TWO_PI_F*(float)(n2*k1)*(1.0f/256.0f), &sn2, &cs2);
#pragma unroll
    for (int c = 0; c < CH; ++c){
        float br = ar[c]*cs2 - ai[c]*sn2;
        float bi = ar[c]*sn2 + ai[c]*cs2;
        ar[c] = br; ai[c] = bi;
    }
    __syncthreads();
#pragma unroll
    for (int c = 0; c < CH; ++c){ xr[c0+c][t] = ar[c]; xi[c0+c][t] = ai[c]; }
    __syncthreads();
    int k1b = t & 15, k2 = t >> 4;
    float csB, snB; __sincosf(sgn*TWO_PI_F*(float)k2*(1.0f/16.0f), &snB, &csB);
    float yr[CH], yi[CH];
#pragma unroll
    for (int c = 0; c < CH; ++c){ yr[c]=0.f; yi[c]=0.f; }
    cw = 1.f; sw = 0.f;
#pragma unroll
    for (int n2b = 0; n2b < 16; ++n2b){
#pragma unroll
        for (int c = 0; c < CH; ++c){
            float br = xr[c0+c][n2b*16+k1b];
            float bi = xi[c0+c][n2b*16+k1b];
            yr[c] += br*cw - bi*sw;
            if (!REAL_OUT) yi[c] += br*sw + bi*cw;
        }
        float cn = cw*csB - sw*snB;
        sw = cw*snB + sw*csB; cw = cn;
    }
    __syncthreads();
#pragma unroll
    for (int c = 0; c < CH; ++c){ xr[c0+c][t] = yr[c]; if (!REAL_OUT) xi[c0+c][t] = yi[c]; }
    __syncthreads();
}

// ---- fused: du = u*Delta + forward rfft along W ------------------------
// One block per (n,h) row. spec layout: [n][w2][h][c] float2
__global__ __launch_bounds__(256) void fftw_fused_kernel(
    const float* __restrict__ u, const unsigned* __restrict__ dmat,
    float2* __restrict__ spec)
{
    __shared__ float xr[8][256], xi[8][256];
    int t = threadIdx.x;
    int bid = blockIdx.x;             // n*256 + h
    int n = bid >> 8, h = bid & 255;

    const float* up = u + (size_t)bid*2048 + (size_t)t*8;
    float4 ua = ((const float4*)up)[0], ub = ((const float4*)up)[1];
    float uv[8] = {ua.x,ua.y,ua.z,ua.w, ub.x,ub.y,ub.z,ub.w};

    const unsigned* dp = dmat + ((size_t)bid*4 + (t>>6))*2048 + (t&63);
    float dv[8];
#pragma unroll
    for (int k = 0; k < 8; ++k) dv[k] = 0.f;
#pragma unroll
    for (int j = 0; j < 8; ++j){
        float uj = uv[j];
#pragma unroll
        for (int k2 = 0; k2 < 4; ++k2){
            float2 f = unpack_bf16x2(dp[(j*4+k2)*64]);
            dv[2*k2]   += uj * f.x;
            dv[2*k2+1] += uj * f.y;
        }
    }
#pragma unroll
    for (int c = 0; c < 8; ++c) xr[c][t] = dv[c];
    __syncthreads();
    fft256_batch<8, true, false>(xr, xi, 0, t, -1.f);
    if (t < 129){
        float4* dst = (float4*)(spec + (((size_t)n*129 + t)*256 + h)*8);
        dst[0] = make_float4(xr[0][t], xi[0][t], xr[1][t], xi[1][t]);
        dst[1] = make_float4(xr[2][t], xi[2][t], xr[3][t], xi[3][t]);
        dst[2] = make_float4(xr[4][t], xi[4][t], xr[5][t], xi[5][t]);
        dst[3] = make_float4(xr[6][t], xi[6][t], xr[7][t], xi[7][t]);
    }
}

// ---- fused: cfft along H -> per-frequency 8x8 complex mat -> icfft -----
__global__ __launch_bounds__(512) void ffth_mult_kernel(
    float2* __restrict__ spec, const float* __restrict__ fpack)
{
    __shared__ float xr[8][256], xi[8][256];
    int tid = threadIdx.x;
    int t = tid & 255, g = tid >> 8;
    int c0 = g*4;
    int n = blockIdx.x / 129, w2 = blockIdx.x % 129;
    float2* base = spec + ((size_t)(n*129 + w2))*2048;
    const float4* rp = (const float4*)(base + (size_t)t*8);
    float4 ra = rp[g*2], rb = rp[g*2+1];
    xr[c0+0][t]=ra.x; xi[c0+0][t]=ra.y; xr[c0+1][t]=ra.z; xi[c0+1][t]=ra.w;
    xr[c0+2][t]=rb.x; xi[c0+2][t]=rb.y; xr[c0+3][t]=rb.z; xi[c0+3][t]=rb.w;
    __syncthreads();
    fft256_batch<4, false, false>(xr, xi, c0, t, -1.f);

    float sr[8], si[8];
#pragma unroll
    for (int j = 0; j < 8; ++j){ sr[j] = xr[j][t]; si[j] = xi[j][t]; }
    float orr[4], oii[4];
#pragma unroll
    for (int kq = 0; kq < 4; ++kq){ orr[kq]=0.f; oii[kq]=0.f; }
    const float2* fp = (const float2*)fpack + (size_t)w2*16384 + t;
#pragma unroll
    for (int j = 0; j < 8; ++j){
        float sjr = sr[j], sji = si[j];
#pragma unroll
        for (int kq = 0; kq < 4; ++kq){
            float2 f = fp[(j*8 + c0 + kq)*256];
            orr[kq] += sjr*f.x - sji*f.y;
            oii[kq] += sjr*f.y + sji*f.x;
        }
    }
    __syncthreads();
#pragma unroll
    for (int kq = 0; kq < 4; ++kq){ xr[c0+kq][t] = orr[kq]; xi[c0+kq][t] = oii[kq]; }
    __syncthreads();
    fft256_batch<4, false, false>(xr, xi, c0, t, +1.f);
    float4* wp = (float4*)(base + (size_t)t*8);
    wp[g*2]   = make_float4(xr[c0+0][t], xi[c0+0][t], xr[c0+1][t], xi[c0+1][t]);
    wp[g*2+1] = make_float4(xr[c0+2][t], xi[c0+2][t], xr[c0+3][t], xi[c0+3][t]);
}

// ---- fused: Hermitian + icfft along W -> u' = 2u + (gu-u)*Gamma --------
__global__ __launch_bounds__(256) void ifftw_fused_kernel(
    const float2* __restrict__ spec, const float* __restrict__ u,
    const unsigned* __restrict__ gmat, const float* __restrict__ bias,
    float* __restrict__ dst, int last)
{
    __shared__ float sre[8][132], sim[8][132];
    __shared__ float xr[8][256], xi[8][256];
    int t = threadIdx.x;
    int bid = blockIdx.x;             // n*256 + h
    int n = bid >> 8, h = bid & 255;
    for (int idx = t; idx < 129*8; idx += 256){
        int w2 = idx >> 3, c = idx & 7;
        float2 v = spec[(((size_t)n*129 + w2)*256 + h)*8 + c];
        sre[c][w2] = v.x; sim[c][w2] = v.y;
    }
    __syncthreads();
#pragma unroll
    for (int c = 0; c < 8; ++c){
        if (t <= 128){ xr[c][t] = sre[c][t];       xi[c][t] = sim[c][t]; }
        else         { xr[c][t] = sre[c][256-t];   xi[c][t] = -sim[c][256-t]; }
    }
    __syncthreads();
    fft256_batch<8, false, true>(xr, xi, 0, t, +1.f);

    const float s = 1.0f/65536.0f;    // irfftn normalization
    const float* up = u + (size_t)bid*2048 + (size_t)t*8;
    float4 ua = ((const float4*)up)[0], ub = ((const float4*)up)[1];
    float uv[8] = {ua.x,ua.y,ua.z,ua.w, ub.x,ub.y,ub.z,ub.w};
    float e[8], acc[8];
#pragma unroll
    for (int c = 0; c < 8; ++c){ e[c] = xr[c][t]*s - uv[c]; acc[c] = 2.0f*uv[c]; }

    const unsigned* gp = gmat + ((size_t)bid*4 + (t>>6))*2048 + (t&63);
#pragma unroll
    for (int j = 0; j < 8; ++j){
        float ej = e[j];
#pragma unroll
        for (int k2 = 0; k2 < 4; ++k2){
            float2 f = unpack_bf16x2(gp[(j*4+k2)*64]);
            acc[2*k2]   += ej * f.x;
            acc[2*k2+1] += ej * f.y;
        }
    }
    float* op = dst + (size_t)bid*2048 + (size_t)t*8;
    if (last){
#pragma unroll
        for (int k = 0; k < 8; ++k) acc[k] = gelu_f(acc[k] + bias[k]);
    }
    ((float4*)op)[0] = make_float4(acc[0],acc[1],acc[2],acc[3]);
    ((float4*)op)[1] = make_float4(acc[4],acc[5],acc[6],acc[7]);
}

extern "C" void kernel_launch(void* const* d_in, const int* in_sizes, int n_in,
                              void* d_out, int out_size, void* d_ws, size_t ws_size,
                              hipStream_t stream) {
    const float* u_in = (const float*)d_in[0];
    const float* k_in = (const float*)d_in[1];
    const float* Wp[24];
    for (int i = 0; i < 24; ++i) Wp[i] = (const float*)d_in[2+i];
    const float* bias = (const float*)d_in[26];

    char* base = (char*)d_ws;
    unsigned* gmat  = (unsigned*)(base);                  // 32 MiB (bf16 pairs)
    unsigned* dmat  = (unsigned*)(base + 33554432ull);    // 32 MiB
    float*    fpack = (float*)   (base + 67108864ull);    // 16.9 MB
    float*    u0    = (float*)   (base + 84017152ull);    // 8 MiB
    float*    u1    = (float*)   (base + 92405760ull);    // 8 MiB
    float2*   spec  = (float2*)  (base + 100794368ull);   // 8.45 MB -> ~109 MB

    mlp_gd_kernel<<<1024, 256, 0, stream>>>(k_in,
        Wp[0],Wp[1],Wp[2],Wp[3],Wp[4],Wp[5],
        Wp[6],Wp[7],Wp[8],Wp[9],Wp[10],Wp[11], gmat, dmat);
    filt_kernel<<<129, 256, 0, stream>>>(
        Wp[12],Wp[13],Wp[14],Wp[15],Wp[16],Wp[17],
        Wp[18],Wp[19],Wp[20],Wp[21],Wp[22],Wp[23], fpack);

    const float* uc = u_in;
    float* un = u0;
    for (int it = 0; it < 4; ++it){
        int last = (it == 3);
        fftw_fused_kernel<<<1024, 256, 0, stream>>>(uc, dmat, spec);
        ffth_mult_kernel <<<516, 512, 0, stream>>>(spec, fpack);
        ifftw_fused_kernel<<<1024, 256, 0, stream>>>(spec, uc, gmat, bias,
                                                     last ? (float*)d_out : un, last);
        uc = un; un = (un == u0) ? u1 : u0;
    }
}

// Round 5
// 265.098 us; speedup vs baseline: 3.6071x; 1.1291x over previous
//
#include <hip/hip_runtime.h>
#include <math.h>

// Problem constants
#define NB 4
#define HB 256
#define WB 256
#define CB 8
#define NPIX (NB*HB*WB)   // 262144
#define W2B 129           // rfft bins along W
#define TWO_PI_F 6.283185307179586f

__device__ __forceinline__ float gelu_f(float x){
    float z = 0.7978845608028654f*(x + 0.044715f*x*x*x);
    return x / (1.0f + __expf(-2.0f*z));
}

__device__ __forceinline__ unsigned pack_bf16x2(float a, float b){
    unsigned ua = __float_as_uint(a), ub = __float_as_uint(b);
    ua = (ua + 0x7FFFu + ((ua >> 16) & 1u)) >> 16;
    ub = (ub + 0x7FFFu + ((ub >> 16) & 1u)) >> 16;
    return ua | (ub << 16);
}
__device__ __forceinline__ float2 unpack_bf16x2(unsigned v){
    return make_float2(__uint_as_float(v << 16), __uint_as_float(v & 0xFFFF0000u));
}

__device__ __forceinline__ void ldcp(float* dst, const float* __restrict__ src, int n, int t){
    for (int i = t; i < n; i += 256) dst[i] = src[i];
}

// ---- MLP pieces (weights in LDS at sw, layout:
// [0:32) w1, [32:48) b1, [48:304) w2, [304:320) b2, [320:1344) w3, [1344:1408) b3)

// 4 pixels per thread: layers 1+2 (2->16->16)
__device__ __forceinline__ void mlp_h2_4(const float* sw, const float* a, const float* b,
                                         float h2[4][16]){
    float h1[4][16];
#pragma unroll
    for (int o = 0; o < 16; ++o){
        float w0 = sw[o], w1 = sw[16+o], bb = sw[32+o];
#pragma unroll
        for (int p = 0; p < 4; ++p) h1[p][o] = gelu_f(a[p]*w0 + b[p]*w1 + bb);
    }
#pragma unroll
    for (int o = 0; o < 16; ++o){
        float acc[4];
#pragma unroll
        for (int p = 0; p < 4; ++p) acc[p] = sw[304+o];
#pragma unroll
        for (int i = 0; i < 16; ++i){
            float w = sw[48+i*16+o];
#pragma unroll
            for (int p = 0; p < 4; ++p) acc[p] += h1[p][i]*w;
        }
#pragma unroll
        for (int p = 0; p < 4; ++p) h2[p][o] = gelu_f(acc[p]);
    }
}

// 4 pixels: final layer -> packed bf16 pairs into panel layout
__device__ __forceinline__ void mlp_store_bf16_4(const float* sw, float h2[4][16],
                                                 unsigned* __restrict__ mat,
                                                 const size_t* base, float scale){
#pragma unroll
    for (int o = 0; o < 64; o += 2){
        float a0[4], a1[4];
#pragma unroll
        for (int p = 0; p < 4; ++p){ a0[p] = sw[1344+o]; a1[p] = sw[1344+o+1]; }
#pragma unroll
        for (int i = 0; i < 16; ++i){
            float w0 = sw[320+i*64+o], w1 = sw[320+i*64+o+1];
#pragma unroll
            for (int p = 0; p < 4; ++p){ a0[p] += h2[p][i]*w0; a1[p] += h2[p][i]*w1; }
        }
#pragma unroll
        for (int p = 0; p < 4; ++p)
            mat[base[p] + (size_t)(o>>1)*64] = pack_bf16x2(a0[p]*scale, a1[p]*scale);
    }
}

// single-point full MLP with f32 strided store (spectral filter path)
__device__ __forceinline__ void mlp_store(const float* sw, float a, float b,
                                          float* __restrict__ dst, int stride, float scale){
    float h1[16], h2[16];
#pragma unroll
    for (int o = 0; o < 16; ++o)
        h1[o] = gelu_f(a*sw[o] + b*sw[16+o] + sw[32+o]);
#pragma unroll
    for (int o = 0; o < 16; ++o){
        float acc = sw[304+o];
#pragma unroll
        for (int i = 0; i < 16; ++i) acc += h1[i]*sw[48+i*16+o];
        h2[o] = gelu_f(acc);
    }
#pragma unroll
    for (int o = 0; o < 64; ++o){
        float acc = sw[1344+o];
#pragma unroll
        for (int i = 0; i < 16; ++i) acc += h2[i]*sw[320+i*64+o];
        dst[o*stride] = acc*scale;
    }
}

// ---- merged prep: blocks 0..255 -> gamma/delta (4 px/thread);
//      blocks 256..384 -> spectral filter ------------------------------
// bf16 pair panel layout: mat[(pix>>6)*2048 + (j*4 + (k>>1))*64 + (pix&63)]
__global__ __launch_bounds__(256) void prep_kernel(
    const float* __restrict__ kin,
    const float* gw1,const float* gb1,const float* gw2,const float* gb2,const float* gw3,const float* gb3,
    const float* dw1,const float* db1,const float* dw2,const float* db2,const float* dw3,const float* db3,
    const float* fw1,const float* fb1,const float* fw2,const float* fb2,const float* fw3,const float* fb3,
    const float* iw1,const float* ib1,const float* iw2,const float* ib2,const float* iw3,const float* ib3,
    unsigned* __restrict__ gmat, unsigned* __restrict__ dmat,
    float* __restrict__ fpack)
{
    __shared__ float sw[2816];
    int t = threadIdx.x;
    if (blockIdx.x < 256){
        ldcp(sw+0,   gw1,  32, t); ldcp(sw+32,  gb1, 16, t);
        ldcp(sw+48,  gw2, 256, t); ldcp(sw+304, gb2, 16, t);
        ldcp(sw+320, gw3,1024, t); ldcp(sw+1344,gb3, 64, t);
        ldcp(sw+1408+0,   dw1,  32, t); ldcp(sw+1408+32,  db1, 16, t);
        ldcp(sw+1408+48,  dw2, 256, t); ldcp(sw+1408+304, db2, 16, t);
        ldcp(sw+1408+320, dw3,1024, t); ldcp(sw+1408+1344,db3, 64, t);
        __syncthreads();
        float a[4], b[4]; size_t base[4];
#pragma unroll
        for (int p = 0; p < 4; ++p){
            int pix = blockIdx.x*1024 + p*256 + t;
            float2 kv = ((const float2*)kin)[pix];
            a[p] = kv.x; b[p] = kv.y;
            base[p] = (size_t)(pix >> 6)*2048 + (pix & 63);
        }
        float h2[4][16];
        mlp_h2_4(sw, a, b, h2);
        mlp_store_bf16_4(sw, h2, gmat, base, 1.0f/64.0f);
        mlp_h2_4(sw+1408, a, b, h2);
        mlp_store_bf16_4(sw+1408, h2, dmat, base, 1.0f/64.0f);
    } else {
        ldcp(sw+0,   fw1,  32, t); ldcp(sw+32,  fb1, 16, t);
        ldcp(sw+48,  fw2, 256, t); ldcp(sw+304, fb2, 16, t);
        ldcp(sw+320, fw3,1024, t); ldcp(sw+1344,fb3, 64, t);
        ldcp(sw+1408+0,   iw1,  32, t); ldcp(sw+1408+32,  ib1, 16, t);
        ldcp(sw+1408+48,  iw2, 256, t); ldcp(sw+1408+304, ib2, 16, t);
        ldcp(sw+1408+320, iw3,1024, t); ldcp(sw+1408+1344,ib3, 64, t);
        __syncthreads();
        int w2 = blockIdx.x - 256;                  // 0..128 (kx)
        float x = (float)w2;
        float y = (float)(t < 128 ? t : t - 256);   // ky signed, t = h-freq
        float* base2 = fpack + (size_t)w2*32768 + (size_t)t*2;
        mlp_store(sw,      x, y, base2,     512, 1.0f/64.0f);  // real
        mlp_store(sw+1408, x, y, base2 + 1, 512, 1.0f/64.0f);  // imag
    }
}

// ---- 256-pt complex FFT, 16x16 Cooley-Tukey, CH channels batched -------
// xr,xi: CH contiguous [256] LDS arrays. Register twiddles; 4 barriers.
template<int CH>
__device__ __forceinline__ void fft256c(float* xr, float* xi, int t, float sgn)
{
    int n2 = t >> 4, k1 = t & 15;
    float csA, snA; __sincosf(sgn*TWO_PI_F*(float)k1*(1.0f/16.0f), &snA, &csA);
    float ar[CH], ai[CH];
#pragma unroll
    for (int c = 0; c < CH; ++c){ ar[c]=0.f; ai[c]=0.f; }
    float cw = 1.f, sw = 0.f;
#pragma unroll
    for (int n1 = 0; n1 < 16; ++n1){
#pragma unroll
        for (int c = 0; c < CH; ++c){
            float xrv = xr[c*256 + 16*n1 + n2];
            float xiv = xi[c*256 + 16*n1 + n2];
            ar[c] += xrv*cw - xiv*sw;
            ai[c] += xrv*sw + xiv*cw;
        }
        float cn = cw*csA - sw*snA;
        sw = cw*snA + sw*csA; cw = cn;
    }
    float cs2, sn2; __sincosf(sgn*TWO_PI_F*(float)(n2*k1)*(1.0f/256.0f), &sn2, &cs2);
#pragma unroll
    for (int c = 0; c < CH; ++c){
        float br = ar[c]*cs2 - ai[c]*sn2;
        float bi = ar[c]*sn2 + ai[c]*cs2;
        ar[c] = br; ai[c] = bi;
    }
    __syncthreads();
#pragma unroll
    for (int c = 0; c < CH; ++c){ xr[c*256+t] = ar[c]; xi[c*256+t] = ai[c]; }
    __syncthreads();
    int k1b = t & 15, k2 = t >> 4;
    float csB, snB; __sincosf(sgn*TWO_PI_F*(float)k2*(1.0f/16.0f), &snB, &csB);
    float yr[CH], yi[CH];
#pragma unroll
    for (int c = 0; c < CH; ++c){ yr[c]=0.f; yi[c]=0.f; }
    cw = 1.f; sw = 0.f;
#pragma unroll
    for (int n2b = 0; n2b < 16; ++n2b){
#pragma unroll
        for (int c = 0; c < CH; ++c){
            float br = xr[c*256 + n2b*16 + k1b];
            float bi = xi[c*256 + n2b*16 + k1b];
            yr[c] += br*cw - bi*sw;
            yi[c] += br*sw + bi*cw;
        }
        float cn = cw*csB - sw*snB;
        sw = cw*snB + sw*csB; cw = cn;
    }
    __syncthreads();
#pragma unroll
    for (int c = 0; c < CH; ++c){ xr[c*256+t] = yr[c]; xi[c*256+t] = yi[c]; }
    __syncthreads();
}

// du row -> pack pairs -> fwd FFT -> Hermitian split -> spec write (t<=128)
__device__ __forceinline__ void fwd_pack_fft_store(
    float* xr, float* xi, const float* dv, int t, int n, int h,
    float2* __restrict__ spec)
{
#pragma unroll
    for (int c2 = 0; c2 < 4; ++c2){ xr[c2*256+t] = dv[2*c2]; xi[c2*256+t] = dv[2*c2+1]; }
    __syncthreads();
    fft256c<4>(xr, xi, t, -1.f);
    if (t <= 128){
        int m = (256 - t) & 255;
        float4* dst = (float4*)(spec + (((size_t)n*129 + t)*256 + h)*8);
#pragma unroll
        for (int c2 = 0; c2 < 4; ++c2){
            float Zr = xr[c2*256+t], Zi = xi[c2*256+t];
            float Yr = xr[c2*256+m], Yi = xi[c2*256+m];
            // A = (Z + conj(Y))/2 ; B = (Z - conj(Y))/(2i)
            dst[c2] = make_float4(0.5f*(Zr+Yr), 0.5f*(Zi-Yi),
                                  0.5f*(Zi+Yi), 0.5f*(Yr-Zr));
        }
    }
}

// spec row -> Hermitian pair-merge -> inv FFT -> gu row (registers)
__device__ __forceinline__ void inv_fft_to_gu(
    const float2* __restrict__ spec, float* xr, float* xi,
    float (*sre)[132], float (*sim)[132], int t, int n, int h, float* gu)
{
    for (int idx = t; idx < 129*8; idx += 256){
        int w2 = idx >> 3, c = idx & 7;
        float2 v = spec[(((size_t)n*129 + w2)*256 + h)*8 + c];
        sre[c][w2] = v.x; sim[c][w2] = v.y;
    }
    __syncthreads();
#pragma unroll
    for (int c2 = 0; c2 < 4; ++c2){
        int a = 2*c2, b = 2*c2+1;
        if (t <= 128){
            xr[c2*256+t] = sre[a][t] - sim[b][t];
            xi[c2*256+t] = sim[a][t] + sre[b][t];
        } else {
            int m = 256 - t;
            xr[c2*256+t] =  sre[a][m] + sim[b][m];
            xi[c2*256+t] = -sim[a][m] + sre[b][m];
        }
    }
    __syncthreads();
    fft256c<4>(xr, xi, t, +1.f);
    const float s = 1.0f/65536.0f;   // irfftn normalization
#pragma unroll
    for (int c2 = 0; c2 < 4; ++c2){
        gu[2*c2]   = xr[c2*256+t]*s;
        gu[2*c2+1] = xi[c2*256+t]*s;
    }
}

// ---- initial: du = u*Delta, forward rfft along W -----------------------
__global__ __launch_bounds__(256) void fft_fwd_kernel(
    const float* __restrict__ u, const unsigned* __restrict__ dmat,
    float2* __restrict__ spec)
{
    __shared__ float xr[4][256], xi[4][256];
    int t = threadIdx.x, bid = blockIdx.x;
    int n = bid >> 8, h = bid & 255;
    const float* up = u + (size_t)bid*2048 + (size_t)t*8;
    float4 ua = ((const float4*)up)[0], ub = ((const float4*)up)[1];
    float uv[8] = {ua.x,ua.y,ua.z,ua.w, ub.x,ub.y,ub.z,ub.w};
    const unsigned* dp = dmat + ((size_t)bid*4 + (t>>6))*2048 + (t&63);
    float dv[8];
#pragma unroll
    for (int k = 0; k < 8; ++k) dv[k] = 0.f;
#pragma unroll
    for (int j = 0; j < 8; ++j){
        float uj = uv[j];
#pragma unroll
        for (int k2 = 0; k2 < 4; ++k2){
            float2 f = unpack_bf16x2(dp[(j*4+k2)*64]);
            dv[2*k2]   += uj * f.x;
            dv[2*k2+1] += uj * f.y;
        }
    }
    fwd_pack_fft_store(&xr[0][0], &xi[0][0], dv, t, n, h, spec);
}

// ---- fused: cfft along H -> per-frequency 8x8 complex mat -> icfft -----
__global__ __launch_bounds__(512) void ffth_mult_kernel(
    float2* __restrict__ spec, const float* __restrict__ fpack)
{
    __shared__ float xr[8][256], xi[8][256];
    int tid = threadIdx.x;
    int t = tid & 255, g = tid >> 8;
    int c0 = g*4;
    int n = blockIdx.x / 129, w2 = blockIdx.x % 129;
    float2* base = spec + ((size_t)(n*129 + w2))*2048;
    const float4* rp = (const float4*)(base + (size_t)t*8);
    float4 ra = rp[g*2], rb = rp[g*2+1];
    xr[c0+0][t]=ra.x; xi[c0+0][t]=ra.y; xr[c0+1][t]=ra.z; xi[c0+1][t]=ra.w;
    xr[c0+2][t]=rb.x; xi[c0+2][t]=rb.y; xr[c0+3][t]=rb.z; xi[c0+3][t]=rb.w;
    __syncthreads();
    fft256c<4>(&xr[c0][0], &xi[c0][0], t, -1.f);

    float sr[8], si[8];
#pragma unroll
    for (int j = 0; j < 8; ++j){ sr[j] = xr[j][t]; si[j] = xi[j][t]; }
    float orr[4], oii[4];
#pragma unroll
    for (int kq = 0; kq < 4; ++kq){ orr[kq]=0.f; oii[kq]=0.f; }
    const float2* fp = (const float2*)fpack + (size_t)w2*16384 + t;
#pragma unroll
    for (int j = 0; j < 8; ++j){
        float sjr = sr[j], sji = si[j];
#pragma unroll
        for (int kq = 0; kq < 4; ++kq){
            float2 f = fp[(j*8 + c0 + kq)*256];
            orr[kq] += sjr*f.x - sji*f.y;
            oii[kq] += sjr*f.y + sji*f.x;
        }
    }
    __syncthreads();
#pragma unroll
    for (int kq = 0; kq < 4; ++kq){ xr[c0+kq][t] = orr[kq]; xi[c0+kq][t] = oii[kq]; }
    __syncthreads();
    fft256c<4>(&xr[c0][0], &xi[c0][0], t, +1.f);
    float4* wp = (float4*)(base + (size_t)t*8);
    wp[g*2]   = make_float4(xr[c0+0][t], xi[c0+0][t], xr[c0+1][t], xi[c0+1][t]);
    wp[g*2+1] = make_float4(xr[c0+2][t], xi[c0+2][t], xr[c0+3][t], xi[c0+3][t]);
}

// ---- fused step: inv-W-FFT -> u' = 2u+(gu-u)G -> du = u'D -> fwd-W-FFT -
__global__ __launch_bounds__(256) void born_step_kernel(
    float2* __restrict__ spec, const float* __restrict__ u_in,
    float* __restrict__ u_out, const unsigned* __restrict__ gmat,
    const unsigned* __restrict__ dmat)
{
    __shared__ float sre[8][132], sim[8][132];
    __shared__ float xr[4][256], xi[4][256];
    int t = threadIdx.x, bid = blockIdx.x;
    int n = bid >> 8, h = bid & 255;
    float gu[8];
    inv_fft_to_gu(spec, &xr[0][0], &xi[0][0], sre, sim, t, n, h, gu);

    const float* up = u_in + (size_t)bid*2048 + (size_t)t*8;
    float4 ua = ((const float4*)up)[0], ub = ((const float4*)up)[1];
    float uv[8] = {ua.x,ua.y,ua.z,ua.w, ub.x,ub.y,ub.z,ub.w};
    float e[8], acc[8];
#pragma unroll
    for (int c = 0; c < 8; ++c){ e[c] = gu[c] - uv[c]; acc[c] = 2.0f*uv[c]; }
    const unsigned* gp = gmat + ((size_t)bid*4 + (t>>6))*2048 + (t&63);
#pragma unroll
    for (int j = 0; j < 8; ++j){
        float ej = e[j];
#pragma unroll
        for (int k2 = 0; k2 < 4; ++k2){
            float2 f = unpack_bf16x2(gp[(j*4+k2)*64]);
            acc[2*k2]   += ej * f.x;
            acc[2*k2+1] += ej * f.y;
        }
    }
    float* op = u_out + (size_t)bid*2048 + (size_t)t*8;
    ((float4*)op)[0] = make_float4(acc[0],acc[1],acc[2],acc[3]);
    ((float4*)op)[1] = make_float4(acc[4],acc[5],acc[6],acc[7]);

    // du for next iteration from u'
    const unsigned* dp = dmat + ((size_t)bid*4 + (t>>6))*2048 + (t&63);
    float dv[8];
#pragma unroll
    for (int k = 0; k < 8; ++k) dv[k] = 0.f;
#pragma unroll
    for (int j = 0; j < 8; ++j){
        float uj = acc[j];
#pragma unroll
        for (int k2 = 0; k2 < 4; ++k2){
            float2 f = unpack_bf16x2(dp[(j*4+k2)*64]);
            dv[2*k2]   += uj * f.x;
            dv[2*k2+1] += uj * f.y;
        }
    }
    fwd_pack_fft_store(&xr[0][0], &xi[0][0], dv, t, n, h, spec);
}

// ---- final: inv-W-FFT -> u' -> gelu(u'+bias) -> out --------------------
__global__ __launch_bounds__(256) void final_kernel(
    const float2* __restrict__ spec, const float* __restrict__ u_in,
    const unsigned* __restrict__ gmat, const float* __restrict__ bias,
    float* __restrict__ out)
{
    __shared__ float sre[8][132], sim[8][132];
    __shared__ float xr[4][256], xi[4][256];
    int t = threadIdx.x, bid = blockIdx.x;
    int n = bid >> 8, h = bid & 255;
    float gu[8];
    inv_fft_to_gu(spec, &xr[0][0], &xi[0][0], sre, sim, t, n, h, gu);

    const float* up = u_in + (size_t)bid*2048 + (size_t)t*8;
    float4 ua = ((const float4*)up)[0], ub = ((const float4*)up)[1];
    float uv[8] = {ua.x,ua.y,ua.z,ua.w, ub.x,ub.y,ub.z,ub.w};
    float e[8], acc[8];
#pragma unroll
    for (int c = 0; c < 8; ++c){ e[c] = gu[c] - uv[c]; acc[c] = 2.0f*uv[c]; }
    const unsigned* gp = gmat + ((size_t)bid*4 + (t>>6))*2048 + (t&63);
#pragma unroll
    for (int j = 0; j < 8; ++j){
        float ej = e[j];
#pragma unroll
        for (int k2 = 0; k2 < 4; ++k2){
            float2 f = unpack_bf16x2(gp[(j*4+k2)*64]);
            acc[2*k2]   += ej * f.x;
            acc[2*k2+1] += ej * f.y;
        }
    }
#pragma unroll
    for (int k = 0; k < 8; ++k) acc[k] = gelu_f(acc[k] + bias[k]);
    float* op = out + (size_t)bid*2048 + (size_t)t*8;
    ((float4*)op)[0] = make_float4(acc[0],acc[1],acc[2],acc[3]);
    ((float4*)op)[1] = make_float4(acc[4],acc[5],acc[6],acc[7]);
}

extern "C" void kernel_launch(void* const* d_in, const int* in_sizes, int n_in,
                              void* d_out, int out_size, void* d_ws, size_t ws_size,
                              hipStream_t stream) {
    const float* u_in = (const float*)d_in[0];
    const float* k_in = (const float*)d_in[1];
    const float* Wp[24];
    for (int i = 0; i < 24; ++i) Wp[i] = (const float*)d_in[2+i];
    const float* bias = (const float*)d_in[26];

    char* base = (char*)d_ws;
    unsigned* gmat  = (unsigned*)(base);                  // 32 MiB (bf16 pairs)
    unsigned* dmat  = (unsigned*)(base + 33554432ull);    // 32 MiB
    float*    fpack = (float*)   (base + 67108864ull);    // 16.9 MB
    float*    u_ws  = (float*)   (base + 84017152ull);    // 8 MiB
    float2*   spec  = (float2*)  (base + 92405760ull);    // 8.45 MB -> ~101 MB

    prep_kernel<<<385, 256, 0, stream>>>(k_in,
        Wp[0],Wp[1],Wp[2],Wp[3],Wp[4],Wp[5],
        Wp[6],Wp[7],Wp[8],Wp[9],Wp[10],Wp[11],
        Wp[12],Wp[13],Wp[14],Wp[15],Wp[16],Wp[17],
        Wp[18],Wp[19],Wp[20],Wp[21],Wp[22],Wp[23],
        gmat, dmat, fpack);

    fft_fwd_kernel<<<1024, 256, 0, stream>>>(u_in, dmat, spec);
    for (int it = 0; it < 4; ++it){
        ffth_mult_kernel<<<516, 512, 0, stream>>>(spec, fpack);
        if (it < 3){
            born_step_kernel<<<1024, 256, 0, stream>>>(
                spec, (it == 0) ? u_in : u_ws, u_ws, gmat, dmat);
        } else {
            final_kernel<<<1024, 256, 0, stream>>>(spec, u_ws, gmat, bias, (float*)d_out);
        }
    }
}

// Round 6
// 246.040 us; speedup vs baseline: 3.8865x; 1.0775x over previous
//
#include <hip/hip_runtime.h>
#include <math.h>

// Problem constants
#define NB 4
#define HB 256
#define WB 256
#define CB 8
#define NPIX (NB*HB*WB)   // 262144
#define W2B 129           // rfft bins along W
#define TWO_PI_F 6.283185307179586f

__device__ __forceinline__ float gelu_f(float x){
    float z = 0.7978845608028654f*(x + 0.044715f*x*x*x);
    return x / (1.0f + __expf(-2.0f*z));
}

__device__ __forceinline__ unsigned pack_bf16x2(float a, float b){
    unsigned ua = __float_as_uint(a), ub = __float_as_uint(b);
    ua = (ua + 0x7FFFu + ((ua >> 16) & 1u)) >> 16;
    ub = (ub + 0x7FFFu + ((ub >> 16) & 1u)) >> 16;
    return ua | (ub << 16);
}
__device__ __forceinline__ float2 unpack_bf16x2(unsigned v){
    return make_float2(__uint_as_float(v << 16), __uint_as_float(v & 0xFFFF0000u));
}

// ---- MLP pieces, weights read DIRECTLY from global (wave-uniform ->
// compiler emits s_load through the scalar pipe; no LDS, no barriers) ----

// layers 1+2 (2->16->16) for one point
__device__ __forceinline__ void mlp_h2_g(
    const float* __restrict__ w1, const float* __restrict__ b1,
    const float* __restrict__ w2, const float* __restrict__ b2,
    float a, float b, float* h2)
{
    float h1[16];
#pragma unroll
    for (int o = 0; o < 16; ++o)
        h1[o] = gelu_f(a*w1[o] + b*w1[16+o] + b1[o]);
#pragma unroll
    for (int o = 0; o < 16; ++o){
        float acc = b2[o];
#pragma unroll
        for (int i = 0; i < 16; ++i) acc += h1[i]*w2[i*16+o];
        h2[o] = gelu_f(acc);
    }
}

// full MLP for 2 pixels -> packed bf16 pairs into panel layout
__device__ __forceinline__ void mlp_gd2(
    const float* __restrict__ w1, const float* __restrict__ b1,
    const float* __restrict__ w2, const float* __restrict__ b2,
    const float* __restrict__ w3, const float* __restrict__ b3,
    const float* a, const float* bb, unsigned* __restrict__ mat,
    const size_t* base, float scale)
{
    float h1[2][16], h2[2][16];
#pragma unroll
    for (int o = 0; o < 16; ++o){
        float wx = w1[o], wy = w1[16+o], bo = b1[o];
#pragma unroll
        for (int p = 0; p < 2; ++p) h1[p][o] = gelu_f(a[p]*wx + bb[p]*wy + bo);
    }
#pragma unroll
    for (int o = 0; o < 16; ++o){
        float acc0 = b2[o], acc1 = b2[o];
#pragma unroll
        for (int i = 0; i < 16; ++i){
            float w = w2[i*16+o];
            acc0 += h1[0][i]*w; acc1 += h1[1][i]*w;
        }
        h2[0][o] = gelu_f(acc0); h2[1][o] = gelu_f(acc1);
    }
#pragma unroll
    for (int o = 0; o < 64; o += 2){
        float a0[2], a1[2];
#pragma unroll
        for (int p = 0; p < 2; ++p){ a0[p] = b3[o]; a1[p] = b3[o+1]; }
#pragma unroll
        for (int i = 0; i < 16; ++i){
            float w0 = w3[i*64+o], w1v = w3[i*64+o+1];
#pragma unroll
            for (int p = 0; p < 2; ++p){ a0[p] += h2[p][i]*w0; a1[p] += h2[p][i]*w1v; }
        }
#pragma unroll
        for (int p = 0; p < 2; ++p)
            mat[base[p] + (size_t)(o>>1)*64] = pack_bf16x2(a0[p]*scale, a1[p]*scale);
    }
}

// ---- prep: blocks 0..511 gamma (2px/thr), 512..1023 delta (2px/thr),
//      1024..1152 spectral filter (bf16-packed) -------------------------
// bf16 pair panel layout: mat[(pix>>6)*2048 + (j*4 + (k>>1))*64 + (pix&63)]
// fpack[w2][j*8+k][h] = bf16x2{re,im}
__global__ __launch_bounds__(256) void prep_kernel(
    const float* __restrict__ kin,
    const float* gw1,const float* gb1,const float* gw2,const float* gb2,const float* gw3,const float* gb3,
    const float* dw1,const float* db1,const float* dw2,const float* db2,const float* dw3,const float* db3,
    const float* fw1,const float* fb1,const float* fw2,const float* fb2,const float* fw3,const float* fb3,
    const float* iw1,const float* ib1,const float* iw2,const float* ib2,const float* iw3,const float* ib3,
    unsigned* __restrict__ gmat, unsigned* __restrict__ dmat,
    unsigned* __restrict__ fpack)
{
    int t = threadIdx.x;
    int b = blockIdx.x;
    if (b < 1024){
        int gd = (b >= 512);
        int bb_ = b & 511;
        float a[2], bv[2]; size_t base[2];
#pragma unroll
        for (int p = 0; p < 2; ++p){
            int pix = bb_*512 + p*256 + t;
            float2 kv = ((const float2*)kin)[pix];
            a[p] = kv.x; bv[p] = kv.y;
            base[p] = (size_t)(pix >> 6)*2048 + (pix & 63);
        }
        if (!gd) mlp_gd2(gw1,gb1,gw2,gb2,gw3,gb3, a, bv, gmat, base, 1.0f/64.0f);
        else     mlp_gd2(dw1,db1,dw2,db2,dw3,db3, a, bv, dmat, base, 1.0f/64.0f);
    } else {
        int w2 = b - 1024;                          // 0..128 (kx)
        float x = (float)w2;
        float y = (float)(t < 128 ? t : t - 256);   // ky signed, t = h-freq
        float h2r[16], h2i[16];
        mlp_h2_g(fw1, fb1, fw2, fb2, x, y, h2r);
        mlp_h2_g(iw1, ib1, iw2, ib2, x, y, h2i);
        unsigned* dst = fpack + (size_t)w2*16384 + t;
        const float s = 1.0f/64.0f;
#pragma unroll
        for (int o = 0; o < 64; ++o){
            float ar = fb3[o], ai = ib3[o];
#pragma unroll
            for (int i = 0; i < 16; ++i){
                ar += h2r[i]*fw3[i*64+o];
                ai += h2i[i]*iw3[i*64+o];
            }
            dst[o*256] = pack_bf16x2(ar*s, ai*s);
        }
    }
}

// ---- 256-pt complex FFT, 16x16 Cooley-Tukey, CH channels batched -------
// xr,xi: CH contiguous [256] LDS arrays. Register twiddles; 4 barriers.
template<int CH>
__device__ __forceinline__ void fft256c(float* xr, float* xi, int t, float sgn)
{
    int n2 = t >> 4, k1 = t & 15;
    float csA, snA; __sincosf(sgn*TWO_PI_F*(float)k1*(1.0f/16.0f), &snA, &csA);
    float ar[CH], ai[CH];
#pragma unroll
    for (int c = 0; c < CH; ++c){ ar[c]=0.f; ai[c]=0.f; }
    float cw = 1.f, sw = 0.f;
#pragma unroll
    for (int n1 = 0; n1 < 16; ++n1){
#pragma unroll
        for (int c = 0; c < CH; ++c){
            float xrv = xr[c*256 + 16*n1 + n2];
            float xiv = xi[c*256 + 16*n1 + n2];
            ar[c] += xrv*cw - xiv*sw;
            ai[c] += xrv*sw + xiv*cw;
        }
        float cn = cw*csA - sw*snA;
        sw = cw*snA + sw*csA; cw = cn;
    }
    float cs2, sn2; __sincosf(sgn*TWO_PI_F*(float)(n2*k1)*(1.0f/256.0f), &sn2, &cs2);
#pragma unroll
    for (int c = 0; c < CH; ++c){
        float br = ar[c]*cs2 - ai[c]*sn2;
        float bi = ar[c]*sn2 + ai[c]*cs2;
        ar[c] = br; ai[c] = bi;
    }
    __syncthreads();
#pragma unroll
    for (int c = 0; c < CH; ++c){ xr[c*256+t] = ar[c]; xi[c*256+t] = ai[c]; }
    __syncthreads();
    int k1b = t & 15, k2 = t >> 4;
    float csB, snB; __sincosf(sgn*TWO_PI_F*(float)k2*(1.0f/16.0f), &snB, &csB);
    float yr[CH], yi[CH];
#pragma unroll
    for (int c = 0; c < CH; ++c){ yr[c]=0.f; yi[c]=0.f; }
    cw = 1.f; sw = 0.f;
#pragma unroll
    for (int n2b = 0; n2b < 16; ++n2b){
#pragma unroll
        for (int c = 0; c < CH; ++c){
            float br = xr[c*256 + n2b*16 + k1b];
            float bi = xi[c*256 + n2b*16 + k1b];
            yr[c] += br*cw - bi*sw;
            yi[c] += br*sw + bi*cw;
        }
        float cn = cw*csB - sw*snB;
        sw = cw*snB + sw*csB; cw = cn;
    }
    __syncthreads();
#pragma unroll
    for (int c = 0; c < CH; ++c){ xr[c*256+t] = yr[c]; xi[c*256+t] = yi[c]; }
    __syncthreads();
}

// du row -> pack pairs -> fwd FFT -> Hermitian split -> spec write (t<=128)
__device__ __forceinline__ void fwd_pack_fft_store(
    float* xr, float* xi, const float* dv, int t, int n, int h,
    float2* __restrict__ spec)
{
#pragma unroll
    for (int c2 = 0; c2 < 4; ++c2){ xr[c2*256+t] = dv[2*c2]; xi[c2*256+t] = dv[2*c2+1]; }
    __syncthreads();
    fft256c<4>(xr, xi, t, -1.f);
    if (t <= 128){
        int m = (256 - t) & 255;
        float4* dst = (float4*)(spec + (((size_t)n*129 + t)*256 + h)*8);
#pragma unroll
        for (int c2 = 0; c2 < 4; ++c2){
            float Zr = xr[c2*256+t], Zi = xi[c2*256+t];
            float Yr = xr[c2*256+m], Yi = xi[c2*256+m];
            // A = (Z + conj(Y))/2 ; B = (Z - conj(Y))/(2i)
            dst[c2] = make_float4(0.5f*(Zr+Yr), 0.5f*(Zi-Yi),
                                  0.5f*(Zi+Yi), 0.5f*(Yr-Zr));
        }
    }
}

// spec row -> Hermitian pair-merge -> inv FFT -> gu row (registers)
__device__ __forceinline__ void inv_fft_to_gu(
    const float2* __restrict__ spec, float* xr, float* xi,
    float (*sre)[132], float (*sim)[132], int t, int n, int h, float* gu)
{
    for (int idx = t; idx < 129*8; idx += 256){
        int w2 = idx >> 3, c = idx & 7;
        float2 v = spec[(((size_t)n*129 + w2)*256 + h)*8 + c];
        sre[c][w2] = v.x; sim[c][w2] = v.y;
    }
    __syncthreads();
#pragma unroll
    for (int c2 = 0; c2 < 4; ++c2){
        int a = 2*c2, b = 2*c2+1;
        if (t <= 128){
            xr[c2*256+t] = sre[a][t] - sim[b][t];
            xi[c2*256+t] = sim[a][t] + sre[b][t];
        } else {
            int m = 256 - t;
            xr[c2*256+t] =  sre[a][m] + sim[b][m];
            xi[c2*256+t] = -sim[a][m] + sre[b][m];
        }
    }
    __syncthreads();
    fft256c<4>(xr, xi, t, +1.f);
    const float s = 1.0f/65536.0f;   // irfftn normalization
#pragma unroll
    for (int c2 = 0; c2 < 4; ++c2){
        gu[2*c2]   = xr[c2*256+t]*s;
        gu[2*c2+1] = xi[c2*256+t]*s;
    }
}

// ---- initial: du = u*Delta, forward rfft along W -----------------------
__global__ __launch_bounds__(256) void fft_fwd_kernel(
    const float* __restrict__ u, const unsigned* __restrict__ dmat,
    float2* __restrict__ spec)
{
    __shared__ float xr[4][256], xi[4][256];
    int t = threadIdx.x, bid = blockIdx.x;
    int n = bid >> 8, h = bid & 255;
    const float* up = u + (size_t)bid*2048 + (size_t)t*8;
    float4 ua = ((const float4*)up)[0], ub = ((const float4*)up)[1];
    float uv[8] = {ua.x,ua.y,ua.z,ua.w, ub.x,ub.y,ub.z,ub.w};
    const unsigned* dp = dmat + ((size_t)bid*4 + (t>>6))*2048 + (t&63);
    float dv[8];
#pragma unroll
    for (int k = 0; k < 8; ++k) dv[k] = 0.f;
#pragma unroll
    for (int j = 0; j < 8; ++j){
        float uj = uv[j];
#pragma unroll
        for (int k2 = 0; k2 < 4; ++k2){
            float2 f = unpack_bf16x2(dp[(j*4+k2)*64]);
            dv[2*k2]   += uj * f.x;
            dv[2*k2+1] += uj * f.y;
        }
    }
    fwd_pack_fft_store(&xr[0][0], &xi[0][0], dv, t, n, h, spec);
}

// ---- fused: cfft along H -> per-frequency 8x8 complex mat -> icfft -----
__global__ __launch_bounds__(512) void ffth_mult_kernel(
    float2* __restrict__ spec, const unsigned* __restrict__ fpack)
{
    __shared__ float xr[8][256], xi[8][256];
    int tid = threadIdx.x;
    int t = tid & 255, g = tid >> 8;
    int c0 = g*4;
    int n = blockIdx.x / 129, w2 = blockIdx.x % 129;
    float2* base = spec + ((size_t)(n*129 + w2))*2048;
    const float4* rp = (const float4*)(base + (size_t)t*8);
    float4 ra = rp[g*2], rb = rp[g*2+1];
    xr[c0+0][t]=ra.x; xi[c0+0][t]=ra.y; xr[c0+1][t]=ra.z; xi[c0+1][t]=ra.w;
    xr[c0+2][t]=rb.x; xi[c0+2][t]=rb.y; xr[c0+3][t]=rb.z; xi[c0+3][t]=rb.w;
    __syncthreads();
    fft256c<4>(&xr[c0][0], &xi[c0][0], t, -1.f);

    float sr[8], si[8];
#pragma unroll
    for (int j = 0; j < 8; ++j){ sr[j] = xr[j][t]; si[j] = xi[j][t]; }
    float orr[4], oii[4];
#pragma unroll
    for (int kq = 0; kq < 4; ++kq){ orr[kq]=0.f; oii[kq]=0.f; }
    const unsigned* fp = fpack + (size_t)w2*16384 + t;
#pragma unroll
    for (int j = 0; j < 8; ++j){
        float sjr = sr[j], sji = si[j];
#pragma unroll
        for (int kq = 0; kq < 4; ++kq){
            float2 f = unpack_bf16x2(fp[(j*8 + c0 + kq)*256]);
            orr[kq] += sjr*f.x - sji*f.y;
            oii[kq] += sjr*f.y + sji*f.x;
        }
    }
    __syncthreads();
#pragma unroll
    for (int kq = 0; kq < 4; ++kq){ xr[c0+kq][t] = orr[kq]; xi[c0+kq][t] = oii[kq]; }
    __syncthreads();
    fft256c<4>(&xr[c0][0], &xi[c0][0], t, +1.f);
    float4* wp = (float4*)(base + (size_t)t*8);
    wp[g*2]   = make_float4(xr[c0+0][t], xi[c0+0][t], xr[c0+1][t], xi[c0+1][t]);
    wp[g*2+1] = make_float4(xr[c0+2][t], xi[c0+2][t], xr[c0+3][t], xi[c0+3][t]);
}

// ---- fused step: inv-W-FFT -> u' = 2u+(gu-u)G -> du = u'D -> fwd-W-FFT -
__global__ __launch_bounds__(256) void born_step_kernel(
    float2* __restrict__ spec, const float* __restrict__ u_in,
    float* __restrict__ u_out, const unsigned* __restrict__ gmat,
    const unsigned* __restrict__ dmat)
{
    __shared__ float sre[8][132], sim[8][132];
    __shared__ float xr[4][256], xi[4][256];
    int t = threadIdx.x, bid = blockIdx.x;
    int n = bid >> 8, h = bid & 255;
    float gu[8];
    inv_fft_to_gu(spec, &xr[0][0], &xi[0][0], sre, sim, t, n, h, gu);

    const float* up = u_in + (size_t)bid*2048 + (size_t)t*8;
    float4 ua = ((const float4*)up)[0], ub = ((const float4*)up)[1];
    float uv[8] = {ua.x,ua.y,ua.z,ua.w, ub.x,ub.y,ub.z,ub.w};
    float e[8], acc[8];
#pragma unroll
    for (int c = 0; c < 8; ++c){ e[c] = gu[c] - uv[c]; acc[c] = 2.0f*uv[c]; }
    const unsigned* gp = gmat + ((size_t)bid*4 + (t>>6))*2048 + (t&63);
#pragma unroll
    for (int j = 0; j < 8; ++j){
        float ej = e[j];
#pragma unroll
        for (int k2 = 0; k2 < 4; ++k2){
            float2 f = unpack_bf16x2(gp[(j*4+k2)*64]);
            acc[2*k2]   += ej * f.x;
            acc[2*k2+1] += ej * f.y;
        }
    }
    float* op = u_out + (size_t)bid*2048 + (size_t)t*8;
    ((float4*)op)[0] = make_float4(acc[0],acc[1],acc[2],acc[3]);
    ((float4*)op)[1] = make_float4(acc[4],acc[5],acc[6],acc[7]);

    // du for next iteration from u'
    const unsigned* dp = dmat + ((size_t)bid*4 + (t>>6))*2048 + (t&63);
    float dv[8];
#pragma unroll
    for (int k = 0; k < 8; ++k) dv[k] = 0.f;
#pragma unroll
    for (int j = 0; j < 8; ++j){
        float uj = acc[j];
#pragma unroll
        for (int k2 = 0; k2 < 4; ++k2){
            float2 f = unpack_bf16x2(dp[(j*4+k2)*64]);
            dv[2*k2]   += uj * f.x;
            dv[2*k2+1] += uj * f.y;
        }
    }
    fwd_pack_fft_store(&xr[0][0], &xi[0][0], dv, t, n, h, spec);
}

// ---- final: inv-W-FFT -> u' -> gelu(u'+bias) -> out --------------------
__global__ __launch_bounds__(256) void final_kernel(
    const float2* __restrict__ spec, const float* __restrict__ u_in,
    const unsigned* __restrict__ gmat, const float* __restrict__ bias,
    float* __restrict__ out)
{
    __shared__ float sre[8][132], sim[8][132];
    __shared__ float xr[4][256], xi[4][256];
    int t = threadIdx.x, bid = blockIdx.x;
    int n = bid >> 8, h = bid & 255;
    float gu[8];
    inv_fft_to_gu(spec, &xr[0][0], &xi[0][0], sre, sim, t, n, h, gu);

    const float* up = u_in + (size_t)bid*2048 + (size_t)t*8;
    float4 ua = ((const float4*)up)[0], ub = ((const float4*)up)[1];
    float uv[8] = {ua.x,ua.y,ua.z,ua.w, ub.x,ub.y,ub.z,ub.w};
    float e[8], acc[8];
#pragma unroll
    for (int c = 0; c < 8; ++c){ e[c] = gu[c] - uv[c]; acc[c] = 2.0f*uv[c]; }
    const unsigned* gp = gmat + ((size_t)bid*4 + (t>>6))*2048 + (t&63);
#pragma unroll
    for (int j = 0; j < 8; ++j){
        float ej = e[j];
#pragma unroll
        for (int k2 = 0; k2 < 4; ++k2){
            float2 f = unpack_bf16x2(gp[(j*4+k2)*64]);
            acc[2*k2]   += ej * f.x;
            acc[2*k2+1] += ej * f.y;
        }
    }
#pragma unroll
    for (int k = 0; k < 8; ++k) acc[k] = gelu_f(acc[k] + bias[k]);
    float* op = out + (size_t)bid*2048 + (size_t)t*8;
    ((float4*)op)[0] = make_float4(acc[0],acc[1],acc[2],acc[3]);
    ((float4*)op)[1] = make_float4(acc[4],acc[5],acc[6],acc[7]);
}

extern "C" void kernel_launch(void* const* d_in, const int* in_sizes, int n_in,
                              void* d_out, int out_size, void* d_ws, size_t ws_size,
                              hipStream_t stream) {
    const float* u_in = (const float*)d_in[0];
    const float* k_in = (const float*)d_in[1];
    const float* Wp[24];
    for (int i = 0; i < 24; ++i) Wp[i] = (const float*)d_in[2+i];
    const float* bias = (const float*)d_in[26];

    char* base = (char*)d_ws;
    unsigned* gmat  = (unsigned*)(base);                  // 32 MiB (bf16 pairs)
    unsigned* dmat  = (unsigned*)(base + 33554432ull);    // 32 MiB
    unsigned* fpack = (unsigned*)(base + 67108864ull);    // 8.45 MB (bf16 pairs)
    float*    u_ws  = (float*)   (base + 75563008ull);    // 8 MiB
    float2*   spec  = (float2*)  (base + 83951616ull);    // 8.45 MB -> ~92 MB

    prep_kernel<<<1153, 256, 0, stream>>>(k_in,
        Wp[0],Wp[1],Wp[2],Wp[3],Wp[4],Wp[5],
        Wp[6],Wp[7],Wp[8],Wp[9],Wp[10],Wp[11],
        Wp[12],Wp[13],Wp[14],Wp[15],Wp[16],Wp[17],
        Wp[18],Wp[19],Wp[20],Wp[21],Wp[22],Wp[23],
        gmat, dmat, fpack);

    fft_fwd_kernel<<<1024, 256, 0, stream>>>(u_in, dmat, spec);
    for (int it = 0; it < 4; ++it){
        ffth_mult_kernel<<<516, 512, 0, stream>>>(spec, fpack);
        if (it < 3){
            born_step_kernel<<<1024, 256, 0, stream>>>(
                spec, (it == 0) ? u_in : u_ws, u_ws, gmat, dmat);
        } else {
            final_kernel<<<1024, 256, 0, stream>>>(spec, u_ws, gmat, bias, (float*)d_out);
        }
    }
}

// Round 7
// 240.553 us; speedup vs baseline: 3.9751x; 1.0228x over previous
//
#include <hip/hip_runtime.h>
#include <math.h>

// Problem constants
#define NB 4
#define HB 256
#define WB 256
#define CB 8
#define NPIX (NB*HB*WB)   // 262144
#define W2B 129           // rfft bins along W
#define TWO_PI_F 6.283185307179586f

__device__ __forceinline__ float gelu_f(float x){
    float z = 0.7978845608028654f*(x + 0.044715f*x*x*x);
    return x / (1.0f + __expf(-2.0f*z));
}

__device__ __forceinline__ unsigned pack_bf16x2(float a, float b){
    unsigned ua = __float_as_uint(a), ub = __float_as_uint(b);
    ua = (ua + 0x7FFFu + ((ua >> 16) & 1u)) >> 16;
    ub = (ub + 0x7FFFu + ((ub >> 16) & 1u)) >> 16;
    return ua | (ub << 16);
}
__device__ __forceinline__ float2 unpack_bf16x2(unsigned v){
    return make_float2(__uint_as_float(v << 16), __uint_as_float(v & 0xFFFF0000u));
}

__device__ __forceinline__ void ldcp(float* dst, const float* __restrict__ src, int n, int t){
    for (int i = t; i < n; i += 256) dst[i] = src[i];
}

// ---- prep: blocks 0..511 gamma (2px/thr), 512..1023 delta (2px/thr),
//      1024..1152 spectral filter. Weights staged in LDS (broadcast
//      ds_read, conflict-free); 2px/thread halves LDS-issue per FMA. ----
// LDS weight layout: [0:32) w1, [32:48) b1, [48:304) w2, [304:320) b2,
//                    [320:1344) w3, [1344:1408) b3
// bf16 pair panel layout: mat[(pix>>6)*2048 + (j*4 + (k>>1))*64 + (pix&63)]
// fpack[w2][j*8+k][h] = bf16x2{re,im}
__global__ __launch_bounds__(256) void prep_kernel(
    const float* __restrict__ kin,
    const float* gw1,const float* gb1,const float* gw2,const float* gb2,const float* gw3,const float* gb3,
    const float* dw1,const float* db1,const float* dw2,const float* db2,const float* dw3,const float* db3,
    const float* fw1,const float* fb1,const float* fw2,const float* fb2,const float* fw3,const float* fb3,
    const float* iw1,const float* ib1,const float* iw2,const float* ib2,const float* iw3,const float* ib3,
    unsigned* __restrict__ gmat, unsigned* __restrict__ dmat,
    unsigned* __restrict__ fpack)
{
    __shared__ float sw[2816];
    int t = threadIdx.x;
    int b = blockIdx.x;
    if (b < 1024){
        int gd = (b >= 512);
        const float* w1 = gd ? dw1 : gw1;  const float* b1 = gd ? db1 : gb1;
        const float* w2 = gd ? dw2 : gw2;  const float* b2 = gd ? db2 : gb2;
        const float* w3 = gd ? dw3 : gw3;  const float* b3 = gd ? db3 : gb3;
        ldcp(sw+0,   w1,  32, t); ldcp(sw+32,  b1, 16, t);
        ldcp(sw+48,  w2, 256, t); ldcp(sw+304, b2, 16, t);
        ldcp(sw+320, w3,1024, t); ldcp(sw+1344,b3, 64, t);
        __syncthreads();
        unsigned* mat = gd ? dmat : gmat;
        int bb_ = b & 511;
        float a[2], bv[2]; size_t base[2];
#pragma unroll
        for (int p = 0; p < 2; ++p){
            int pix = bb_*512 + p*256 + t;
            float2 kv = ((const float2*)kin)[pix];
            a[p] = kv.x; bv[p] = kv.y;
            base[p] = (size_t)(pix >> 6)*2048 + (pix & 63);
        }
        float h1[2][16], h2[2][16];
#pragma unroll
        for (int o = 0; o < 16; ++o){
            float wx = sw[o], wy = sw[16+o], bo = sw[32+o];
#pragma unroll
            for (int p = 0; p < 2; ++p) h1[p][o] = gelu_f(a[p]*wx + bv[p]*wy + bo);
        }
#pragma unroll
        for (int o = 0; o < 16; ++o){
            float acc0 = sw[304+o], acc1 = acc0;
#pragma unroll
            for (int i = 0; i < 16; ++i){
                float w = sw[48+i*16+o];
                acc0 += h1[0][i]*w; acc1 += h1[1][i]*w;
            }
            h2[0][o] = gelu_f(acc0); h2[1][o] = gelu_f(acc1);
        }
        const float s = 1.0f/64.0f;
#pragma unroll
        for (int o = 0; o < 64; o += 2){
            float a0[2], a1[2];
#pragma unroll
            for (int p = 0; p < 2; ++p){ a0[p] = sw[1344+o]; a1[p] = sw[1344+o+1]; }
#pragma unroll
            for (int i = 0; i < 16; ++i){
                float w0 = sw[320+i*64+o], w1v = sw[320+i*64+o+1];
#pragma unroll
                for (int p = 0; p < 2; ++p){ a0[p] += h2[p][i]*w0; a1[p] += h2[p][i]*w1v; }
            }
#pragma unroll
            for (int p = 0; p < 2; ++p)
                mat[base[p] + (size_t)(o>>1)*64] = pack_bf16x2(a0[p]*s, a1[p]*s);
        }
    } else {
        ldcp(sw+0,   fw1,  32, t); ldcp(sw+32,  fb1, 16, t);
        ldcp(sw+48,  fw2, 256, t); ldcp(sw+304, fb2, 16, t);
        ldcp(sw+320, fw3,1024, t); ldcp(sw+1344,fb3, 64, t);
        ldcp(sw+1408+0,   iw1,  32, t); ldcp(sw+1408+32,  ib1, 16, t);
        ldcp(sw+1408+48,  iw2, 256, t); ldcp(sw+1408+304, ib2, 16, t);
        ldcp(sw+1408+320, iw3,1024, t); ldcp(sw+1408+1344,ib3, 64, t);
        __syncthreads();
        int w2 = b - 1024;                          // 0..128 (kx)
        float x = (float)w2;
        float y = (float)(t < 128 ? t : t - 256);   // ky signed, t = h-freq
        float h1r[16], h1i[16], h2r[16], h2i[16];
#pragma unroll
        for (int o = 0; o < 16; ++o){
            h1r[o] = gelu_f(x*sw[o] + y*sw[16+o] + sw[32+o]);
            h1i[o] = gelu_f(x*sw[1408+o] + y*sw[1408+16+o] + sw[1408+32+o]);
        }
#pragma unroll
        for (int o = 0; o < 16; ++o){
            float ar = sw[304+o], ai = sw[1408+304+o];
#pragma unroll
            for (int i = 0; i < 16; ++i){
                ar += h1r[i]*sw[48+i*16+o];
                ai += h1i[i]*sw[1408+48+i*16+o];
            }
            h2r[o] = gelu_f(ar); h2i[o] = gelu_f(ai);
        }
        unsigned* dst = fpack + (size_t)w2*16384 + t;
        const float s = 1.0f/64.0f;
#pragma unroll
        for (int o = 0; o < 64; ++o){
            float ar = sw[1344+o], ai = sw[1408+1344+o];
#pragma unroll
            for (int i = 0; i < 16; ++i){
                ar += h2r[i]*sw[320+i*64+o];
                ai += h2i[i]*sw[1408+320+i*64+o];
            }
            dst[o*256] = pack_bf16x2(ar*s, ai*s);
        }
    }
}

// ---- 256-pt complex FFT, 16x16 Cooley-Tukey, CH channels batched -------
// xr,xi: CH contiguous [256] LDS arrays. Register twiddles; 4 barriers.
template<int CH>
__device__ __forceinline__ void fft256c(float* xr, float* xi, int t, float sgn)
{
    int n2 = t >> 4, k1 = t & 15;
    float csA, snA; __sincosf(sgn*TWO_PI_F*(float)k1*(1.0f/16.0f), &snA, &csA);
    float ar[CH], ai[CH];
#pragma unroll
    for (int c = 0; c < CH; ++c){ ar[c]=0.f; ai[c]=0.f; }
    float cw = 1.f, sw = 0.f;
#pragma unroll
    for (int n1 = 0; n1 < 16; ++n1){
#pragma unroll
        for (int c = 0; c < CH; ++c){
            float xrv = xr[c*256 + 16*n1 + n2];
            float xiv = xi[c*256 + 16*n1 + n2];
            ar[c] += xrv*cw - xiv*sw;
            ai[c] += xrv*sw + xiv*cw;
        }
        float cn = cw*csA - sw*snA;
        sw = cw*snA + sw*csA; cw = cn;
    }
    float cs2, sn2; __sincosf(sgn*TWO_PI_F*(float)(n2*k1)*(1.0f/256.0f), &sn2, &cs2);
#pragma unroll
    for (int c = 0; c < CH; ++c){
        float br = ar[c]*cs2 - ai[c]*sn2;
        float bi = ar[c]*sn2 + ai[c]*cs2;
        ar[c] = br; ai[c] = bi;
    }
    __syncthreads();
#pragma unroll
    for (int c = 0; c < CH; ++c){ xr[c*256+t] = ar[c]; xi[c*256+t] = ai[c]; }
    __syncthreads();
    int k1b = t & 15, k2 = t >> 4;
    float csB, snB; __sincosf(sgn*TWO_PI_F*(float)k2*(1.0f/16.0f), &snB, &csB);
    float yr[CH], yi[CH];
#pragma unroll
    for (int c = 0; c < CH; ++c){ yr[c]=0.f; yi[c]=0.f; }
    cw = 1.f; sw = 0.f;
#pragma unroll
    for (int n2b = 0; n2b < 16; ++n2b){
#pragma unroll
        for (int c = 0; c < CH; ++c){
            float br = xr[c*256 + n2b*16 + k1b];
            float bi = xi[c*256 + n2b*16 + k1b];
            yr[c] += br*cw - bi*sw;
            yi[c] += br*sw + bi*cw;
        }
        float cn = cw*csB - sw*snB;
        sw = cw*snB + sw*csB; cw = cn;
    }
    __syncthreads();
#pragma unroll
    for (int c = 0; c < CH; ++c){ xr[c*256+t] = yr[c]; xi[c*256+t] = yi[c]; }
    __syncthreads();
}

// du row -> pack pairs -> fwd FFT -> Hermitian split -> spec write (t<=128)
__device__ __forceinline__ void fwd_pack_fft_store(
    float* xr, float* xi, const float* dv, int t, int n, int h,
    float2* __restrict__ spec)
{
#pragma unroll
    for (int c2 = 0; c2 < 4; ++c2){ xr[c2*256+t] = dv[2*c2]; xi[c2*256+t] = dv[2*c2+1]; }
    __syncthreads();
    fft256c<4>(xr, xi, t, -1.f);
    if (t <= 128){
        int m = (256 - t) & 255;
        float4* dst = (float4*)(spec + (((size_t)n*129 + t)*256 + h)*8);
#pragma unroll
        for (int c2 = 0; c2 < 4; ++c2){
            float Zr = xr[c2*256+t], Zi = xi[c2*256+t];
            float Yr = xr[c2*256+m], Yi = xi[c2*256+m];
            // A = (Z + conj(Y))/2 ; B = (Z - conj(Y))/(2i)
            dst[c2] = make_float4(0.5f*(Zr+Yr), 0.5f*(Zi-Yi),
                                  0.5f*(Zi+Yi), 0.5f*(Yr-Zr));
        }
    }
}

// spec row -> Hermitian pair-merge -> inv FFT -> gu row (registers)
__device__ __forceinline__ void inv_fft_to_gu(
    const float2* __restrict__ spec, float* xr, float* xi,
    float (*sre)[132], float (*sim)[132], int t, int n, int h, float* gu)
{
    for (int idx = t; idx < 129*8; idx += 256){
        int w2 = idx >> 3, c = idx & 7;
        float2 v = spec[(((size_t)n*129 + w2)*256 + h)*8 + c];
        sre[c][w2] = v.x; sim[c][w2] = v.y;
    }
    __syncthreads();
#pragma unroll
    for (int c2 = 0; c2 < 4; ++c2){
        int a = 2*c2, b = 2*c2+1;
        if (t <= 128){
            xr[c2*256+t] = sre[a][t] - sim[b][t];
            xi[c2*256+t] = sim[a][t] + sre[b][t];
        } else {
            int m = 256 - t;
            xr[c2*256+t] =  sre[a][m] + sim[b][m];
            xi[c2*256+t] = -sim[a][m] + sre[b][m];
        }
    }
    __syncthreads();
    fft256c<4>(xr, xi, t, +1.f);
    const float s = 1.0f/65536.0f;   // irfftn normalization
#pragma unroll
    for (int c2 = 0; c2 < 4; ++c2){
        gu[2*c2]   = xr[c2*256+t]*s;
        gu[2*c2+1] = xi[c2*256+t]*s;
    }
}

// ---- initial: du = u*Delta, forward rfft along W -----------------------
__global__ __launch_bounds__(256) void fft_fwd_kernel(
    const float* __restrict__ u, const unsigned* __restrict__ dmat,
    float2* __restrict__ spec)
{
    __shared__ float xr[4][256], xi[4][256];
    int t = threadIdx.x, bid = blockIdx.x;
    int n = bid >> 8, h = bid & 255;
    const float* up = u + (size_t)bid*2048 + (size_t)t*8;
    float4 ua = ((const float4*)up)[0], ub = ((const float4*)up)[1];
    float uv[8] = {ua.x,ua.y,ua.z,ua.w, ub.x,ub.y,ub.z,ub.w};
    const unsigned* dp = dmat + ((size_t)bid*4 + (t>>6))*2048 + (t&63);
    float dv[8];
#pragma unroll
    for (int k = 0; k < 8; ++k) dv[k] = 0.f;
#pragma unroll
    for (int j = 0; j < 8; ++j){
        float uj = uv[j];
#pragma unroll
        for (int k2 = 0; k2 < 4; ++k2){
            float2 f = unpack_bf16x2(dp[(j*4+k2)*64]);
            dv[2*k2]   += uj * f.x;
            dv[2*k2+1] += uj * f.y;
        }
    }
    fwd_pack_fft_store(&xr[0][0], &xi[0][0], dv, t, n, h, spec);
}

// ---- fused: cfft along H -> per-frequency 8x8 complex mat -> icfft -----
__global__ __launch_bounds__(512) void ffth_mult_kernel(
    float2* __restrict__ spec, const unsigned* __restrict__ fpack)
{
    __shared__ float xr[8][256], xi[8][256];
    int tid = threadIdx.x;
    int t = tid & 255, g = tid >> 8;
    int c0 = g*4;
    int n = blockIdx.x / 129, w2 = blockIdx.x % 129;
    float2* base = spec + ((size_t)(n*129 + w2))*2048;
    const float4* rp = (const float4*)(base + (size_t)t*8);
    float4 ra = rp[g*2], rb = rp[g*2+1];
    xr[c0+0][t]=ra.x; xi[c0+0][t]=ra.y; xr[c0+1][t]=ra.z; xi[c0+1][t]=ra.w;
    xr[c0+2][t]=rb.x; xi[c0+2][t]=rb.y; xr[c0+3][t]=rb.z; xi[c0+3][t]=rb.w;
    __syncthreads();
    fft256c<4>(&xr[c0][0], &xi[c0][0], t, -1.f);

    float sr[8], si[8];
#pragma unroll
    for (int j = 0; j < 8; ++j){ sr[j] = xr[j][t]; si[j] = xi[j][t]; }
    float orr[4], oii[4];
#pragma unroll
    for (int kq = 0; kq < 4; ++kq){ orr[kq]=0.f; oii[kq]=0.f; }
    const unsigned* fp = fpack + (size_t)w2*16384 + t;
#pragma unroll
    for (int j = 0; j < 8; ++j){
        float sjr = sr[j], sji = si[j];
#pragma unroll
        for (int kq = 0; kq < 4; ++kq){
            float2 f = unpack_bf16x2(fp[(j*8 + c0 + kq)*256]);
            orr[kq] += sjr*f.x - sji*f.y;
            oii[kq] += sjr*f.y + sji*f.x;
        }
    }
    __syncthreads();
#pragma unroll
    for (int kq = 0; kq < 4; ++kq){ xr[c0+kq][t] = orr[kq]; xi[c0+kq][t] = oii[kq]; }
    __syncthreads();
    fft256c<4>(&xr[c0][0], &xi[c0][0], t, +1.f);
    float4* wp = (float4*)(base + (size_t)t*8);
    wp[g*2]   = make_float4(xr[c0+0][t], xi[c0+0][t], xr[c0+1][t], xi[c0+1][t]);
    wp[g*2+1] = make_float4(xr[c0+2][t], xi[c0+2][t], xr[c0+3][t], xi[c0+3][t]);
}

// ---- fused step: inv-W-FFT -> u' = 2u+(gu-u)G -> du = u'D -> fwd-W-FFT -
__global__ __launch_bounds__(256) void born_step_kernel(
    float2* __restrict__ spec, const float* __restrict__ u_in,
    float* __restrict__ u_out, const unsigned* __restrict__ gmat,
    const unsigned* __restrict__ dmat)
{
    __shared__ float sre[8][132], sim[8][132];
    __shared__ float xr[4][256], xi[4][256];
    int t = threadIdx.x, bid = blockIdx.x;
    int n = bid >> 8, h = bid & 255;
    float gu[8];
    inv_fft_to_gu(spec, &xr[0][0], &xi[0][0], sre, sim, t, n, h, gu);

    const float* up = u_in + (size_t)bid*2048 + (size_t)t*8;
    float4 ua = ((const float4*)up)[0], ub = ((const float4*)up)[1];
    float uv[8] = {ua.x,ua.y,ua.z,ua.w, ub.x,ub.y,ub.z,ub.w};
    float e[8], acc[8];
#pragma unroll
    for (int c = 0; c < 8; ++c){ e[c] = gu[c] - uv[c]; acc[c] = 2.0f*uv[c]; }
    const unsigned* gp = gmat + ((size_t)bid*4 + (t>>6))*2048 + (t&63);
#pragma unroll
    for (int j = 0; j < 8; ++j){
        float ej = e[j];
#pragma unroll
        for (int k2 = 0; k2 < 4; ++k2){
            float2 f = unpack_bf16x2(gp[(j*4+k2)*64]);
            acc[2*k2]   += ej * f.x;
            acc[2*k2+1] += ej * f.y;
        }
    }
    float* op = u_out + (size_t)bid*2048 + (size_t)t*8;
    ((float4*)op)[0] = make_float4(acc[0],acc[1],acc[2],acc[3]);
    ((float4*)op)[1] = make_float4(acc[4],acc[5],acc[6],acc[7]);

    // du for next iteration from u'
    const unsigned* dp = dmat + ((size_t)bid*4 + (t>>6))*2048 + (t&63);
    float dv[8];
#pragma unroll
    for (int k = 0; k < 8; ++k) dv[k] = 0.f;
#pragma unroll
    for (int j = 0; j < 8; ++j){
        float uj = acc[j];
#pragma unroll
        for (int k2 = 0; k2 < 4; ++k2){
            float2 f = unpack_bf16x2(dp[(j*4+k2)*64]);
            dv[2*k2]   += uj * f.x;
            dv[2*k2+1] += uj * f.y;
        }
    }
    fwd_pack_fft_store(&xr[0][0], &xi[0][0], dv, t, n, h, spec);
}

// ---- final: inv-W-FFT -> u' -> gelu(u'+bias) -> out --------------------
__global__ __launch_bounds__(256) void final_kernel(
    const float2* __restrict__ spec, const float* __restrict__ u_in,
    const unsigned* __restrict__ gmat, const float* __restrict__ bias,
    float* __restrict__ out)
{
    __shared__ float sre[8][132], sim[8][132];
    __shared__ float xr[4][256], xi[4][256];
    int t = threadIdx.x, bid = blockIdx.x;
    int n = bid >> 8, h = bid & 255;
    float gu[8];
    inv_fft_to_gu(spec, &xr[0][0], &xi[0][0], sre, sim, t, n, h, gu);

    const float* up = u_in + (size_t)bid*2048 + (size_t)t*8;
    float4 ua = ((const float4*)up)[0], ub = ((const float4*)up)[1];
    float uv[8] = {ua.x,ua.y,ua.z,ua.w, ub.x,ub.y,ub.z,ub.w};
    float e[8], acc[8];
#pragma unroll
    for (int c = 0; c < 8; ++c){ e[c] = gu[c] - uv[c]; acc[c] = 2.0f*uv[c]; }
    const unsigned* gp = gmat + ((size_t)bid*4 + (t>>6))*2048 + (t&63);
#pragma unroll
    for (int j = 0; j < 8; ++j){
        float ej = e[j];
#pragma unroll
        for (int k2 = 0; k2 < 4; ++k2){
            float2 f = unpack_bf16x2(gp[(j*4+k2)*64]);
            acc[2*k2]   += ej * f.x;
            acc[2*k2+1] += ej * f.y;
        }
    }
#pragma unroll
    for (int k = 0; k < 8; ++k) acc[k] = gelu_f(acc[k] + bias[k]);
    float* op = out + (size_t)bid*2048 + (size_t)t*8;
    ((float4*)op)[0] = make_float4(acc[0],acc[1],acc[2],acc[3]);
    ((float4*)op)[1] = make_float4(acc[4],acc[5],acc[6],acc[7]);
}

extern "C" void kernel_launch(void* const* d_in, const int* in_sizes, int n_in,
                              void* d_out, int out_size, void* d_ws, size_t ws_size,
                              hipStream_t stream) {
    const float* u_in = (const float*)d_in[0];
    const float* k_in = (const float*)d_in[1];
    const float* Wp[24];
    for (int i = 0; i < 24; ++i) Wp[i] = (const float*)d_in[2+i];
    const float* bias = (const float*)d_in[26];

    char* base = (char*)d_ws;
    unsigned* gmat  = (unsigned*)(base);                  // 32 MiB (bf16 pairs)
    unsigned* dmat  = (unsigned*)(base + 33554432ull);    // 32 MiB
    unsigned* fpack = (unsigned*)(base + 67108864ull);    // 8.45 MB (bf16 pairs)
    float*    u_ws  = (float*)   (base + 75563008ull);    // 8 MiB
    float2*   spec  = (float2*)  (base + 83951616ull);    // 8.45 MB -> ~92 MB

    prep_kernel<<<1153, 256, 0, stream>>>(k_in,
        Wp[0],Wp[1],Wp[2],Wp[3],Wp[4],Wp[5],
        Wp[6],Wp[7],Wp[8],Wp[9],Wp[10],Wp[11],
        Wp[12],Wp[13],Wp[14],Wp[15],Wp[16],Wp[17],
        Wp[18],Wp[19],Wp[20],Wp[21],Wp[22],Wp[23],
        gmat, dmat, fpack);

    fft_fwd_kernel<<<1024, 256, 0, stream>>>(u_in, dmat, spec);
    for (int it = 0; it < 4; ++it){
        ffth_mult_kernel<<<516, 512, 0, stream>>>(spec, fpack);
        if (it < 3){
            born_step_kernel<<<1024, 256, 0, stream>>>(
                spec, (it == 0) ? u_in : u_ws, u_ws, gmat, dmat);
        } else {
            final_kernel<<<1024, 256, 0, stream>>>(spec, u_ws, gmat, bias, (float*)d_out);
        }
    }
}

// Round 8
// 231.701 us; speedup vs baseline: 4.1270x; 1.0382x over previous
//
#include <hip/hip_runtime.h>
#include <math.h>

// Problem constants
#define NB 4
#define HB 256
#define WB 256
#define CB 8
#define NPIX (NB*HB*WB)   // 262144
#define W2B 129           // rfft bins along W
#define TWO_PI_F 6.283185307179586f

typedef float f32x4 __attribute__((ext_vector_type(4)));

__device__ __forceinline__ float gelu_f(float x){
    float z = 0.7978845608028654f*(x + 0.044715f*x*x*x);
    return x / (1.0f + __expf(-2.0f*z));
}

__device__ __forceinline__ unsigned pack_bf16x2(float a, float b){
    unsigned ua = __float_as_uint(a), ub = __float_as_uint(b);
    ua = (ua + 0x7FFFu + ((ua >> 16) & 1u)) >> 16;
    ub = (ub + 0x7FFFu + ((ub >> 16) & 1u)) >> 16;
    return ua | (ub << 16);
}
__device__ __forceinline__ float2 unpack_bf16x2(unsigned v){
    return make_float2(__uint_as_float(v << 16), __uint_as_float(v & 0xFFFF0000u));
}

__device__ __forceinline__ void ldcp(float* dst, const float* __restrict__ src, int n, int t){
    for (int i = t; i < n; i += 256) dst[i] = src[i];
}

// ---- prep (unchanged from round 7): gamma/delta 2px/thr + filter -------
__global__ __launch_bounds__(256) void prep_kernel(
    const float* __restrict__ kin,
    const float* gw1,const float* gb1,const float* gw2,const float* gb2,const float* gw3,const float* gb3,
    const float* dw1,const float* db1,const float* dw2,const float* db2,const float* dw3,const float* db3,
    const float* fw1,const float* fb1,const float* fw2,const float* fb2,const float* fw3,const float* fb3,
    const float* iw1,const float* ib1,const float* iw2,const float* ib2,const float* iw3,const float* ib3,
    unsigned* __restrict__ gmat, unsigned* __restrict__ dmat,
    unsigned* __restrict__ fpack)
{
    __shared__ float sw[2816];
    int t = threadIdx.x;
    int b = blockIdx.x;
    if (b < 1024){
        int gd = (b >= 512);
        const float* w1 = gd ? dw1 : gw1;  const float* b1 = gd ? db1 : gb1;
        const float* w2 = gd ? dw2 : gw2;  const float* b2 = gd ? db2 : gb2;
        const float* w3 = gd ? dw3 : gw3;  const float* b3 = gd ? db3 : gb3;
        ldcp(sw+0,   w1,  32, t); ldcp(sw+32,  b1, 16, t);
        ldcp(sw+48,  w2, 256, t); ldcp(sw+304, b2, 16, t);
        ldcp(sw+320, w3,1024, t); ldcp(sw+1344,b3, 64, t);
        __syncthreads();
        unsigned* mat = gd ? dmat : gmat;
        int bb_ = b & 511;
        float a[2], bv[2]; size_t base[2];
#pragma unroll
        for (int p = 0; p < 2; ++p){
            int pix = bb_*512 + p*256 + t;
            float2 kv = ((const float2*)kin)[pix];
            a[p] = kv.x; bv[p] = kv.y;
            base[p] = (size_t)(pix >> 6)*2048 + (pix & 63);
        }
        float h1[2][16], h2[2][16];
#pragma unroll
        for (int o = 0; o < 16; ++o){
            float wx = sw[o], wy = sw[16+o], bo = sw[32+o];
#pragma unroll
            for (int p = 0; p < 2; ++p) h1[p][o] = gelu_f(a[p]*wx + bv[p]*wy + bo);
        }
#pragma unroll
        for (int o = 0; o < 16; ++o){
            float acc0 = sw[304+o], acc1 = acc0;
#pragma unroll
            for (int i = 0; i < 16; ++i){
                float w = sw[48+i*16+o];
                acc0 += h1[0][i]*w; acc1 += h1[1][i]*w;
            }
            h2[0][o] = gelu_f(acc0); h2[1][o] = gelu_f(acc1);
        }
        const float s = 1.0f/64.0f;
#pragma unroll
        for (int o = 0; o < 64; o += 2){
            float a0[2], a1[2];
#pragma unroll
            for (int p = 0; p < 2; ++p){ a0[p] = sw[1344+o]; a1[p] = sw[1344+o+1]; }
#pragma unroll
            for (int i = 0; i < 16; ++i){
                float w0 = sw[320+i*64+o], w1v = sw[320+i*64+o+1];
#pragma unroll
                for (int p = 0; p < 2; ++p){ a0[p] += h2[p][i]*w0; a1[p] += h2[p][i]*w1v; }
            }
#pragma unroll
            for (int p = 0; p < 2; ++p)
                mat[base[p] + (size_t)(o>>1)*64] = pack_bf16x2(a0[p]*s, a1[p]*s);
        }
    } else {
        ldcp(sw+0,   fw1,  32, t); ldcp(sw+32,  fb1, 16, t);
        ldcp(sw+48,  fw2, 256, t); ldcp(sw+304, fb2, 16, t);
        ldcp(sw+320, fw3,1024, t); ldcp(sw+1344,fb3, 64, t);
        ldcp(sw+1408+0,   iw1,  32, t); ldcp(sw+1408+32,  ib1, 16, t);
        ldcp(sw+1408+48,  iw2, 256, t); ldcp(sw+1408+304, ib2, 16, t);
        ldcp(sw+1408+320, iw3,1024, t); ldcp(sw+1408+1344,ib3, 64, t);
        __syncthreads();
        int w2 = b - 1024;                          // 0..128 (kx)
        float x = (float)w2;
        float y = (float)(t < 128 ? t : t - 256);   // ky signed, t = h-freq
        float h1r[16], h1i[16], h2r[16], h2i[16];
#pragma unroll
        for (int o = 0; o < 16; ++o){
            h1r[o] = gelu_f(x*sw[o] + y*sw[16+o] + sw[32+o]);
            h1i[o] = gelu_f(x*sw[1408+o] + y*sw[1408+16+o] + sw[1408+32+o]);
        }
#pragma unroll
        for (int o = 0; o < 16; ++o){
            float ar = sw[304+o], ai = sw[1408+304+o];
#pragma unroll
            for (int i = 0; i < 16; ++i){
                ar += h1r[i]*sw[48+i*16+o];
                ai += h1i[i]*sw[1408+48+i*16+o];
            }
            h2r[o] = gelu_f(ar); h2i[o] = gelu_f(ai);
        }
        unsigned* dst = fpack + (size_t)w2*16384 + t;
        const float s = 1.0f/64.0f;
#pragma unroll
        for (int o = 0; o < 64; ++o){
            float ar = sw[1344+o], ai = sw[1408+1344+o];
#pragma unroll
            for (int i = 0; i < 16; ++i){
                ar += h2r[i]*sw[320+i*64+o];
                ai += h2i[i]*sw[1408+320+i*64+o];
            }
            dst[o*256] = pack_bf16x2(ar*s, ai*s);
        }
    }
}

// ---- 256-pt complex FFT on 4 interleaved channels (f32x4 LDS) ----------
// One ds_read_b128 per butterfly tap serves all 4 channels. 4 barriers.
__device__ __forceinline__ void fft256v(f32x4* xr, f32x4* xi, int t, float sgn)
{
    int n2 = t >> 4, k1 = t & 15;
    float csA, snA; __sincosf(sgn*TWO_PI_F*(float)k1*(1.0f/16.0f), &snA, &csA);
    f32x4 ar = {0.f,0.f,0.f,0.f}, ai = {0.f,0.f,0.f,0.f};
    float cw = 1.f, sw = 0.f;
#pragma unroll
    for (int n1 = 0; n1 < 16; ++n1){
        f32x4 vr = xr[16*n1 + n2], vi = xi[16*n1 + n2];
        ar += vr*cw - vi*sw;
        ai += vr*sw + vi*cw;
        float cn = cw*csA - sw*snA;
        sw = cw*snA + sw*csA; cw = cn;
    }
    float cs2, sn2; __sincosf(sgn*TWO_PI_F*(float)(n2*k1)*(1.0f/256.0f), &sn2, &cs2);
    f32x4 br = ar*cs2 - ai*sn2;
    f32x4 bi = ar*sn2 + ai*cs2;
    __syncthreads();
    xr[t] = br; xi[t] = bi;
    __syncthreads();
    int k1b = t & 15, k2 = t >> 4;
    float csB, snB; __sincosf(sgn*TWO_PI_F*(float)k2*(1.0f/16.0f), &snB, &csB);
    f32x4 yr = {0.f,0.f,0.f,0.f}, yi = {0.f,0.f,0.f,0.f};
    cw = 1.f; sw = 0.f;
#pragma unroll
    for (int n2b = 0; n2b < 16; ++n2b){
        f32x4 br2 = xr[n2b*16 + k1b], bi2 = xi[n2b*16 + k1b];
        yr += br2*cw - bi2*sw;
        yi += br2*sw + bi2*cw;
        float cn = cw*csB - sw*snB;
        sw = cw*snB + sw*csB; cw = cn;
    }
    __syncthreads();
    xr[t] = yr; xi[t] = yi;
    __syncthreads();
}

// du row (8 reals) -> 4 packed complex ch -> fwd FFT -> Hermitian split ->
// spec write (t<=128). spec layout: [n][w2][h][c] float2, channel c = real ch c.
__device__ __forceinline__ void fwd_store(
    f32x4* XR, f32x4* XI, const float* dv, int t, int n, int h,
    float2* __restrict__ spec)
{
    XR[t] = (f32x4){dv[0],dv[2],dv[4],dv[6]};
    XI[t] = (f32x4){dv[1],dv[3],dv[5],dv[7]};
    __syncthreads();
    fft256v(XR, XI, t, -1.f);
    if (t <= 128){
        int m = (256 - t) & 255;
        f32x4 zr = XR[t], zi = XI[t], yr = XR[m], yi = XI[m];
        float4* dst = (float4*)(spec + (((size_t)n*129 + t)*256 + h)*8);
        dst[0] = make_float4(0.5f*(zr.x+yr.x), 0.5f*(zi.x-yi.x), 0.5f*(zi.x+yi.x), 0.5f*(yr.x-zr.x));
        dst[1] = make_float4(0.5f*(zr.y+yr.y), 0.5f*(zi.y-yi.y), 0.5f*(zi.y+yi.y), 0.5f*(yr.y-zr.y));
        dst[2] = make_float4(0.5f*(zr.z+yr.z), 0.5f*(zi.z-yi.z), 0.5f*(zi.z+yi.z), 0.5f*(yr.z-zr.z));
        dst[3] = make_float4(0.5f*(zr.w+yr.w), 0.5f*(zi.w-yi.w), 0.5f*(zi.w+yi.w), 0.5f*(yr.w-zr.w));
    }
}

// direct Hermitian read (own 64B row, full-cacheline) -> inv FFT -> gu[8]
__device__ __forceinline__ void inv_fft_to_gu(
    const float2* __restrict__ spec, f32x4* XR, f32x4* XI,
    int t, int n, int h, float* gu)
{
    int w2 = (t <= 128) ? t : 256 - t;
    const float4* rp = (const float4*)(spec + (((size_t)n*129 + w2)*256 + h)*8);
    float4 q0 = rp[0], q1 = rp[1], q2 = rp[2], q3 = rp[3];
    f32x4 xr, xi;
    if (t <= 128){
        xr = (f32x4){q0.x - q0.w, q1.x - q1.w, q2.x - q2.w, q3.x - q3.w};
        xi = (f32x4){q0.y + q0.z, q1.y + q1.z, q2.y + q2.z, q3.y + q3.z};
    } else {
        xr = (f32x4){ q0.x + q0.w,  q1.x + q1.w,  q2.x + q2.w,  q3.x + q3.w};
        xi = (f32x4){-q0.y + q0.z, -q1.y + q1.z, -q2.y + q2.z, -q3.y + q3.z};
    }
    XR[t] = xr; XI[t] = xi;
    __syncthreads();
    fft256v(XR, XI, t, +1.f);
    const float s = 1.0f/65536.0f;   // irfftn normalization
    f32x4 gr = XR[t], gi = XI[t];
    gu[0]=gr.x*s; gu[1]=gi.x*s; gu[2]=gr.y*s; gu[3]=gi.y*s;
    gu[4]=gr.z*s; gu[5]=gi.z*s; gu[6]=gr.w*s; gu[7]=gi.w*s;
}

// ---- initial: du = u*Delta, forward rfft along W -----------------------
__global__ __launch_bounds__(256) void fft_fwd_kernel(
    const float* __restrict__ u, const unsigned* __restrict__ dmat,
    float2* __restrict__ spec)
{
    __shared__ f32x4 XR[256], XI[256];
    int t = threadIdx.x, bid = blockIdx.x;
    int n = bid >> 8, h = bid & 255;
    const float* up = u + (size_t)bid*2048 + (size_t)t*8;
    float4 ua = ((const float4*)up)[0], ub = ((const float4*)up)[1];
    float uv[8] = {ua.x,ua.y,ua.z,ua.w, ub.x,ub.y,ub.z,ub.w};
    const unsigned* dp = dmat + ((size_t)bid*4 + (t>>6))*2048 + (t&63);
    float dv[8];
#pragma unroll
    for (int k = 0; k < 8; ++k) dv[k] = 0.f;
#pragma unroll
    for (int j = 0; j < 8; ++j){
        float uj = uv[j];
#pragma unroll
        for (int k2 = 0; k2 < 4; ++k2){
            float2 f = unpack_bf16x2(dp[(j*4+k2)*64]);
            dv[2*k2]   += uj * f.x;
            dv[2*k2+1] += uj * f.y;
        }
    }
    fwd_store(XR, XI, dv, t, n, h, spec);
}

// ---- fused: cfft along H -> per-frequency 8x8 complex mat -> icfft -----
__global__ __launch_bounds__(512) void ffth_mult_kernel(
    float2* __restrict__ spec, const unsigned* __restrict__ fpack)
{
    __shared__ f32x4 XR[2][256], XI[2][256];
    int tid = threadIdx.x;
    int t = tid & 255, g = tid >> 8;
    int c0 = g*4;
    int n = blockIdx.x / 129, w2 = blockIdx.x % 129;
    float2* base = spec + ((size_t)(n*129 + w2))*2048;
    const float4* rp = (const float4*)(base + (size_t)t*8);
    float4 ra = rp[g*2], rb = rp[g*2+1];
    XR[g][t] = (f32x4){ra.x, ra.z, rb.x, rb.z};
    XI[g][t] = (f32x4){ra.y, ra.w, rb.y, rb.w};
    __syncthreads();
    fft256v(XR[g], XI[g], t, -1.f);

    f32x4 s0r = XR[0][t], s1r = XR[1][t], s0i = XI[0][t], s1i = XI[1][t];
    float sr[8] = {s0r.x,s0r.y,s0r.z,s0r.w, s1r.x,s1r.y,s1r.z,s1r.w};
    float si[8] = {s0i.x,s0i.y,s0i.z,s0i.w, s1i.x,s1i.y,s1i.z,s1i.w};
    f32x4 orr = {0.f,0.f,0.f,0.f}, oii = {0.f,0.f,0.f,0.f};
    const unsigned* fp = fpack + (size_t)w2*16384 + t;
#pragma unroll
    for (int j = 0; j < 8; ++j){
        float sjr = sr[j], sji = si[j];
        float2 f0 = unpack_bf16x2(fp[(j*8 + c0 + 0)*256]);
        float2 f1 = unpack_bf16x2(fp[(j*8 + c0 + 1)*256]);
        float2 f2 = unpack_bf16x2(fp[(j*8 + c0 + 2)*256]);
        float2 f3 = unpack_bf16x2(fp[(j*8 + c0 + 3)*256]);
        orr.x += sjr*f0.x - sji*f0.y;  oii.x += sjr*f0.y + sji*f0.x;
        orr.y += sjr*f1.x - sji*f1.y;  oii.y += sjr*f1.y + sji*f1.x;
        orr.z += sjr*f2.x - sji*f2.y;  oii.z += sjr*f2.y + sji*f2.x;
        orr.w += sjr*f3.x - sji*f3.y;  oii.w += sjr*f3.y + sji*f3.x;
    }
    __syncthreads();
    XR[g][t] = orr; XI[g][t] = oii;
    __syncthreads();
    fft256v(XR[g], XI[g], t, +1.f);
    f32x4 vr = XR[g][t], vi = XI[g][t];
    float4* wp = (float4*)(base + (size_t)t*8);
    wp[g*2]   = make_float4(vr.x, vi.x, vr.y, vi.y);
    wp[g*2+1] = make_float4(vr.z, vi.z, vr.w, vi.w);
}

// ---- fused step: inv-W-FFT -> u' = 2u+(gu-u)G -> du = u'D -> fwd-W-FFT -
__global__ __launch_bounds__(256) void born_step_kernel(
    float2* __restrict__ spec, const float* __restrict__ u_in,
    float* __restrict__ u_out, const unsigned* __restrict__ gmat,
    const unsigned* __restrict__ dmat)
{
    __shared__ f32x4 XR[256], XI[256];
    int t = threadIdx.x, bid = blockIdx.x;
    int n = bid >> 8, h = bid & 255;
    float gu[8];
    inv_fft_to_gu(spec, XR, XI, t, n, h, gu);

    const float* up = u_in + (size_t)bid*2048 + (size_t)t*8;
    float4 ua = ((const float4*)up)[0], ub = ((const float4*)up)[1];
    float uv[8] = {ua.x,ua.y,ua.z,ua.w, ub.x,ub.y,ub.z,ub.w};
    float e[8], acc[8];
#pragma unroll
    for (int c = 0; c < 8; ++c){ e[c] = gu[c] - uv[c]; acc[c] = 2.0f*uv[c]; }
    const unsigned* gp = gmat + ((size_t)bid*4 + (t>>6))*2048 + (t&63);
#pragma unroll
    for (int j = 0; j < 8; ++j){
        float ej = e[j];
#pragma unroll
        for (int k2 = 0; k2 < 4; ++k2){
            float2 f = unpack_bf16x2(gp[(j*4+k2)*64]);
            acc[2*k2]   += ej * f.x;
            acc[2*k2+1] += ej * f.y;
        }
    }
    float* op = u_out + (size_t)bid*2048 + (size_t)t*8;
    ((float4*)op)[0] = make_float4(acc[0],acc[1],acc[2],acc[3]);
    ((float4*)op)[1] = make_float4(acc[4],acc[5],acc[6],acc[7]);

    // du for next iteration from u'
    const unsigned* dp = dmat + ((size_t)bid*4 + (t>>6))*2048 + (t&63);
    float dv[8];
#pragma unroll
    for (int k = 0; k < 8; ++k) dv[k] = 0.f;
#pragma unroll
    for (int j = 0; j < 8; ++j){
        float uj = acc[j];
#pragma unroll
        for (int k2 = 0; k2 < 4; ++k2){
            float2 f = unpack_bf16x2(dp[(j*4+k2)*64]);
            dv[2*k2]   += uj * f.x;
            dv[2*k2+1] += uj * f.y;
        }
    }
    fwd_store(XR, XI, dv, t, n, h, spec);
}

// ---- final: inv-W-FFT -> u' -> gelu(u'+bias) -> out --------------------
__global__ __launch_bounds__(256) void final_kernel(
    const float2* __restrict__ spec, const float* __restrict__ u_in,
    const unsigned* __restrict__ gmat, const float* __restrict__ bias,
    float* __restrict__ out)
{
    __shared__ f32x4 XR[256], XI[256];
    int t = threadIdx.x, bid = blockIdx.x;
    int n = bid >> 8, h = bid & 255;
    float gu[8];
    inv_fft_to_gu(spec, XR, XI, t, n, h, gu);

    const float* up = u_in + (size_t)bid*2048 + (size_t)t*8;
    float4 ua = ((const float4*)up)[0], ub = ((const float4*)up)[1];
    float uv[8] = {ua.x,ua.y,ua.z,ua.w, ub.x,ub.y,ub.z,ub.w};
    float e[8], acc[8];
#pragma unroll
    for (int c = 0; c < 8; ++c){ e[c] = gu[c] - uv[c]; acc[c] = 2.0f*uv[c]; }
    const unsigned* gp = gmat + ((size_t)bid*4 + (t>>6))*2048 + (t&63);
#pragma unroll
    for (int j = 0; j < 8; ++j){
        float ej = e[j];
#pragma unroll
        for (int k2 = 0; k2 < 4; ++k2){
            float2 f = unpack_bf16x2(gp[(j*4+k2)*64]);
            acc[2*k2]   += ej * f.x;
            acc[2*k2+1] += ej * f.y;
        }
    }
#pragma unroll
    for (int k = 0; k < 8; ++k) acc[k] = gelu_f(acc[k] + bias[k]);
    float* op = out + (size_t)bid*2048 + (size_t)t*8;
    ((float4*)op)[0] = make_float4(acc[0],acc[1],acc[2],acc[3]);
    ((float4*)op)[1] = make_float4(acc[4],acc[5],acc[6],acc[7]);
}

extern "C" void kernel_launch(void* const* d_in, const int* in_sizes, int n_in,
                              void* d_out, int out_size, void* d_ws, size_t ws_size,
                              hipStream_t stream) {
    const float* u_in = (const float*)d_in[0];
    const float* k_in = (const float*)d_in[1];
    const float* Wp[24];
    for (int i = 0; i < 24; ++i) Wp[i] = (const float*)d_in[2+i];
    const float* bias = (const float*)d_in[26];

    char* base = (char*)d_ws;
    unsigned* gmat  = (unsigned*)(base);                  // 32 MiB (bf16 pairs)
    unsigned* dmat  = (unsigned*)(base + 33554432ull);    // 32 MiB
    unsigned* fpack = (unsigned*)(base + 67108864ull);    // 8.45 MB (bf16 pairs)
    float*    u_ws  = (float*)   (base + 75563008ull);    // 8 MiB
    float2*   spec  = (float2*)  (base + 83951616ull);    // 8.45 MB -> ~92 MB

    prep_kernel<<<1153, 256, 0, stream>>>(k_in,
        Wp[0],Wp[1],Wp[2],Wp[3],Wp[4],Wp[5],
        Wp[6],Wp[7],Wp[8],Wp[9],Wp[10],Wp[11],
        Wp[12],Wp[13],Wp[14],Wp[15],Wp[16],Wp[17],
        Wp[18],Wp[19],Wp[20],Wp[21],Wp[22],Wp[23],
        gmat, dmat, fpack);

    fft_fwd_kernel<<<1024, 256, 0, stream>>>(u_in, dmat, spec);
    for (int it = 0; it < 4; ++it){
        ffth_mult_kernel<<<516, 512, 0, stream>>>(spec, fpack);
        if (it < 3){
            born_step_kernel<<<1024, 256, 0, stream>>>(
                spec, (it == 0) ? u_in : u_ws, u_ws, gmat, dmat);
        } else {
            final_kernel<<<1024, 256, 0, stream>>>(spec, u_ws, gmat, bias, (float*)d_out);
        }
    }
}

// Round 9
// 220.700 us; speedup vs baseline: 4.3327x; 1.0498x over previous
//
#include <hip/hip_runtime.h>
#include <math.h>

// Problem constants
#define NB 4
#define HB 256
#define WB 256
#define CB 8
#define NPIX (NB*HB*WB)   // 262144
#define W2B 129           // rfft bins along W
#define TWO_PI_F 6.283185307179586f

typedef float f32x4 __attribute__((ext_vector_type(4)));

__device__ __forceinline__ float gelu_f(float x){
    // x * sigmoid(2z); division via v_rcp_f32 (1-ulp approx, fine vs 1.58 budget)
    float z = 0.7978845608028654f*(x + 0.044715f*x*x*x);
    return x * __builtin_amdgcn_rcpf(1.0f + __expf(-2.0f*z));
}

__device__ __forceinline__ unsigned pack_bf16x2(float a, float b){
    unsigned ua = __float_as_uint(a), ub = __float_as_uint(b);
    ua = (ua + 0x7FFFu + ((ua >> 16) & 1u)) >> 16;
    ub = (ub + 0x7FFFu + ((ub >> 16) & 1u)) >> 16;
    return ua | (ub << 16);
}
__device__ __forceinline__ float2 unpack_bf16x2(unsigned v){
    return make_float2(__uint_as_float(v << 16), __uint_as_float(v & 0xFFFF0000u));
}

__device__ __forceinline__ void ldcp(float* dst, const float* __restrict__ src, int n, int t){
    for (int i = t; i < n; i += 256) dst[i] = src[i];
}

// ---- prep ---------------------------------------------------------------
// Grid order: [0..128] spectral filter (runs first, overlaps gamma/delta);
//             [129..1152] gamma 1px/thr; [1153..2176] delta 1px/thr.
// LDS weight layout: [0:32) w1, [32:48) b1, [48:304) w2, [304:320) b2,
//                    [320:1344) w3, [1344:1408) b3   (16B-aligned offsets)
// bf16 pair panel layout: mat[(pix>>6)*2048 + (j*4 + (k>>1))*64 + (pix&63)]
// fpack[w2][j*8+k][h] = bf16x2{re,im}
__global__ __launch_bounds__(256) void prep_kernel(
    const float* __restrict__ kin,
    const float* gw1,const float* gb1,const float* gw2,const float* gb2,const float* gw3,const float* gb3,
    const float* dw1,const float* db1,const float* dw2,const float* db2,const float* dw3,const float* db3,
    const float* fw1,const float* fb1,const float* fw2,const float* fb2,const float* fw3,const float* fb3,
    const float* iw1,const float* ib1,const float* iw2,const float* ib2,const float* iw3,const float* ib3,
    unsigned* __restrict__ gmat, unsigned* __restrict__ dmat,
    unsigned* __restrict__ fpack)
{
    __shared__ __align__(16) float sw[2816];
    int t = threadIdx.x;
    int b = blockIdx.x;
    if (b >= 129){
        int gd = (b >= 1153);
        const float* w1 = gd ? dw1 : gw1;  const float* b1 = gd ? db1 : gb1;
        const float* w2 = gd ? dw2 : gw2;  const float* b2 = gd ? db2 : gb2;
        const float* w3 = gd ? dw3 : gw3;  const float* b3 = gd ? db3 : gb3;
        ldcp(sw+0,   w1,  32, t); ldcp(sw+32,  b1, 16, t);
        ldcp(sw+48,  w2, 256, t); ldcp(sw+304, b2, 16, t);
        ldcp(sw+320, w3,1024, t); ldcp(sw+1344,b3, 64, t);
        __syncthreads();
        unsigned* mat = gd ? dmat : gmat;
        int pix = (b - (gd ? 1153 : 129))*256 + t;
        float2 kv = ((const float2*)kin)[pix];
        size_t base = (size_t)(pix >> 6)*2048 + (pix & 63);
        float h1[16], h2[16];
#pragma unroll
        for (int o = 0; o < 16; ++o)
            h1[o] = gelu_f(kv.x*sw[o] + kv.y*sw[16+o] + sw[32+o]);
        // layer 2: float4 weight reads (1 b128 / 4 FMA)
#pragma unroll
        for (int oc = 0; oc < 4; ++oc){
            f32x4 acc = *(const f32x4*)(sw + 304 + oc*4);
#pragma unroll
            for (int i = 0; i < 16; ++i){
                f32x4 w = *(const f32x4*)(sw + 48 + i*16 + oc*4);
                acc += h1[i]*w;
            }
            h2[oc*4+0] = gelu_f(acc.x); h2[oc*4+1] = gelu_f(acc.y);
            h2[oc*4+2] = gelu_f(acc.z); h2[oc*4+3] = gelu_f(acc.w);
        }
        const float s = 1.0f/64.0f;
        // layer 3: float4 weight reads, pack bf16 pairs
#pragma unroll
        for (int oc = 0; oc < 16; ++oc){
            f32x4 acc = *(const f32x4*)(sw + 1344 + oc*4);
#pragma unroll
            for (int i = 0; i < 16; ++i){
                f32x4 w = *(const f32x4*)(sw + 320 + i*64 + oc*4);
                acc += h2[i]*w;
            }
            mat[base + (size_t)(oc*2+0)*64] = pack_bf16x2(acc.x*s, acc.y*s);
            mat[base + (size_t)(oc*2+1)*64] = pack_bf16x2(acc.z*s, acc.w*s);
        }
    } else {
        ldcp(sw+0,   fw1,  32, t); ldcp(sw+32,  fb1, 16, t);
        ldcp(sw+48,  fw2, 256, t); ldcp(sw+304, fb2, 16, t);
        ldcp(sw+320, fw3,1024, t); ldcp(sw+1344,fb3, 64, t);
        ldcp(sw+1408+0,   iw1,  32, t); ldcp(sw+1408+32,  ib1, 16, t);
        ldcp(sw+1408+48,  iw2, 256, t); ldcp(sw+1408+304, ib2, 16, t);
        ldcp(sw+1408+320, iw3,1024, t); ldcp(sw+1408+1344,ib3, 64, t);
        __syncthreads();
        int w2 = b;                                 // 0..128 (kx)
        float x = (float)w2;
        float y = (float)(t < 128 ? t : t - 256);   // ky signed, t = h-freq
        float h1r[16], h1i[16], h2r[16], h2i[16];
#pragma unroll
        for (int o = 0; o < 16; ++o){
            h1r[o] = gelu_f(x*sw[o] + y*sw[16+o] + sw[32+o]);
            h1i[o] = gelu_f(x*sw[1408+o] + y*sw[1408+16+o] + sw[1408+32+o]);
        }
#pragma unroll
        for (int o = 0; o < 16; ++o){
            float ar = sw[304+o], ai = sw[1408+304+o];
#pragma unroll
            for (int i = 0; i < 16; ++i){
                ar += h1r[i]*sw[48+i*16+o];
                ai += h1i[i]*sw[1408+48+i*16+o];
            }
            h2r[o] = gelu_f(ar); h2i[o] = gelu_f(ai);
        }
        unsigned* dst = fpack + (size_t)w2*16384 + t;
        const float s = 1.0f/64.0f;
#pragma unroll
        for (int o = 0; o < 64; ++o){
            float ar = sw[1344+o], ai = sw[1408+1344+o];
#pragma unroll
            for (int i = 0; i < 16; ++i){
                ar += h2r[i]*sw[320+i*64+o];
                ai += h2i[i]*sw[1408+320+i*64+o];
            }
            dst[o*256] = pack_bf16x2(ar*s, ai*s);
        }
    }
}

// ---- 256-pt complex FFT, 4 interleaved channels (f32x4 LDS) ------------
// Full version: result stored back to LDS (needed when mirror access follows).
__device__ __forceinline__ void fft256v(f32x4* xr, f32x4* xi, int t, float sgn)
{
    int n2 = t >> 4, k1 = t & 15;
    float csA, snA; __sincosf(sgn*TWO_PI_F*(float)k1*(1.0f/16.0f), &snA, &csA);
    f32x4 ar = {0.f,0.f,0.f,0.f}, ai = {0.f,0.f,0.f,0.f};
    float cw = 1.f, sw = 0.f;
#pragma unroll
    for (int n1 = 0; n1 < 16; ++n1){
        f32x4 vr = xr[16*n1 + n2], vi = xi[16*n1 + n2];
        ar += vr*cw - vi*sw;
        ai += vr*sw + vi*cw;
        float cn = cw*csA - sw*snA;
        sw = cw*snA + sw*csA; cw = cn;
    }
    float cs2, sn2; __sincosf(sgn*TWO_PI_F*(float)(n2*k1)*(1.0f/256.0f), &sn2, &cs2);
    f32x4 br = ar*cs2 - ai*sn2;
    f32x4 bi = ar*sn2 + ai*cs2;
    __syncthreads();
    xr[t] = br; xi[t] = bi;
    __syncthreads();
    int k1b = t & 15, k2 = t >> 4;
    float csB, snB; __sincosf(sgn*TWO_PI_F*(float)k2*(1.0f/16.0f), &snB, &csB);
    f32x4 yr = {0.f,0.f,0.f,0.f}, yi = {0.f,0.f,0.f,0.f};
    cw = 1.f; sw = 0.f;
#pragma unroll
    for (int n2b = 0; n2b < 16; ++n2b){
        f32x4 br2 = xr[n2b*16 + k1b], bi2 = xi[n2b*16 + k1b];
        yr += br2*cw - bi2*sw;
        yi += br2*sw + bi2*cw;
        float cn = cw*csB - sw*snB;
        sw = cw*snB + sw*csB; cw = cn;
    }
    __syncthreads();
    xr[t] = yr; xi[t] = yi;
    __syncthreads();
}

// Core version: caller placed input in LDS and synced. Result X[t] returned
// in registers; NO final store/sync (LDS left with stage-1 data — caller must
// sync before reusing the buffer).
__device__ __forceinline__ void fft256v_core(f32x4* xr, f32x4* xi, int t, float sgn,
                                             f32x4& outR, f32x4& outI)
{
    int n2 = t >> 4, k1 = t & 15;
    float csA, snA; __sincosf(sgn*TWO_PI_F*(float)k1*(1.0f/16.0f), &snA, &csA);
    f32x4 ar = {0.f,0.f,0.f,0.f}, ai = {0.f,0.f,0.f,0.f};
    float cw = 1.f, sw = 0.f;
#pragma unroll
    for (int n1 = 0; n1 < 16; ++n1){
        f32x4 vr = xr[16*n1 + n2], vi = xi[16*n1 + n2];
        ar += vr*cw - vi*sw;
        ai += vr*sw + vi*cw;
        float cn = cw*csA - sw*snA;
        sw = cw*snA + sw*csA; cw = cn;
    }
    float cs2, sn2; __sincosf(sgn*TWO_PI_F*(float)(n2*k1)*(1.0f/256.0f), &sn2, &cs2);
    f32x4 br = ar*cs2 - ai*sn2;
    f32x4 bi = ar*sn2 + ai*cs2;
    __syncthreads();
    xr[t] = br; xi[t] = bi;
    __syncthreads();
    int k1b = t & 15, k2 = t >> 4;
    float csB, snB; __sincosf(sgn*TWO_PI_F*(float)k2*(1.0f/16.0f), &snB, &csB);
    f32x4 yr = {0.f,0.f,0.f,0.f}, yi = {0.f,0.f,0.f,0.f};
    cw = 1.f; sw = 0.f;
#pragma unroll
    for (int n2b = 0; n2b < 16; ++n2b){
        f32x4 br2 = xr[n2b*16 + k1b], bi2 = xi[n2b*16 + k1b];
        yr += br2*cw - bi2*sw;
        yi += br2*sw + bi2*cw;
        float cn = cw*csB - sw*snB;
        sw = cw*snB + sw*csB; cw = cn;
    }
    outR = yr; outI = yi;
}

// du row (8 reals) -> 4 packed complex ch -> fwd FFT -> Hermitian split ->
// spec write (t<=128). Mirror access requires the stored version.
__device__ __forceinline__ void fwd_store(
    f32x4* XR, f32x4* XI, const float* dv, int t, int n, int h,
    float2* __restrict__ spec)
{
    XR[t] = (f32x4){dv[0],dv[2],dv[4],dv[6]};
    XI[t] = (f32x4){dv[1],dv[3],dv[5],dv[7]};
    __syncthreads();
    fft256v(XR, XI, t, -1.f);
    if (t <= 128){
        int m = (256 - t) & 255;
        f32x4 zr = XR[t], zi = XI[t], yr = XR[m], yi = XI[m];
        float4* dst = (float4*)(spec + (((size_t)n*129 + t)*256 + h)*8);
        dst[0] = make_float4(0.5f*(zr.x+yr.x), 0.5f*(zi.x-yi.x), 0.5f*(zi.x+yi.x), 0.5f*(yr.x-zr.x));
        dst[1] = make_float4(0.5f*(zr.y+yr.y), 0.5f*(zi.y-yi.y), 0.5f*(zi.y+yi.y), 0.5f*(yr.y-zr.y));
        dst[2] = make_float4(0.5f*(zr.z+yr.z), 0.5f*(zi.z-yi.z), 0.5f*(zi.z+yi.z), 0.5f*(yr.z-zr.z));
        dst[3] = make_float4(0.5f*(zr.w+yr.w), 0.5f*(zi.w-yi.w), 0.5f*(zi.w+yi.w), 0.5f*(yr.w-zr.w));
    }
}

// direct Hermitian read -> inv FFT (core) -> gu[8] in registers.
// NOTE: leaves LDS mid-FFT; caller must __syncthreads() before reusing XR/XI.
__device__ __forceinline__ void inv_fft_to_gu(
    const float2* __restrict__ spec, f32x4* XR, f32x4* XI,
    int t, int n, int h, float* gu)
{
    int w2 = (t <= 128) ? t : 256 - t;
    const float4* rp = (const float4*)(spec + (((size_t)n*129 + w2)*256 + h)*8);
    float4 q0 = rp[0], q1 = rp[1], q2 = rp[2], q3 = rp[3];
    f32x4 xr, xi;
    if (t <= 128){
        xr = (f32x4){q0.x - q0.w, q1.x - q1.w, q2.x - q2.w, q3.x - q3.w};
        xi = (f32x4){q0.y + q0.z, q1.y + q1.z, q2.y + q2.z, q3.y + q3.z};
    } else {
        xr = (f32x4){ q0.x + q0.w,  q1.x + q1.w,  q2.x + q2.w,  q3.x + q3.w};
        xi = (f32x4){-q0.y + q0.z, -q1.y + q1.z, -q2.y + q2.z, -q3.y + q3.z};
    }
    XR[t] = xr; XI[t] = xi;
    __syncthreads();
    f32x4 gr, gi;
    fft256v_core(XR, XI, t, +1.f, gr, gi);
    const float s = 1.0f/65536.0f;   // irfftn normalization
    gu[0]=gr.x*s; gu[1]=gi.x*s; gu[2]=gr.y*s; gu[3]=gi.y*s;
    gu[4]=gr.z*s; gu[5]=gi.z*s; gu[6]=gr.w*s; gu[7]=gi.w*s;
}

// ---- initial: du = u*Delta, forward rfft along W -----------------------
__global__ __launch_bounds__(256) void fft_fwd_kernel(
    const float* __restrict__ u, const unsigned* __restrict__ dmat,
    float2* __restrict__ spec)
{
    __shared__ f32x4 XR[256], XI[256];
    int t = threadIdx.x, bid = blockIdx.x;
    int n = bid >> 8, h = bid & 255;
    const float* up = u + (size_t)bid*2048 + (size_t)t*8;
    float4 ua = ((const float4*)up)[0], ub = ((const float4*)up)[1];
    float uv[8] = {ua.x,ua.y,ua.z,ua.w, ub.x,ub.y,ub.z,ub.w};
    const unsigned* dp = dmat + ((size_t)bid*4 + (t>>6))*2048 + (t&63);
    float dv[8];
#pragma unroll
    for (int k = 0; k < 8; ++k) dv[k] = 0.f;
#pragma unroll
    for (int j = 0; j < 8; ++j){
        float uj = uv[j];
#pragma unroll
        for (int k2 = 0; k2 < 4; ++k2){
            float2 f = unpack_bf16x2(dp[(j*4+k2)*64]);
            dv[2*k2]   += uj * f.x;
            dv[2*k2+1] += uj * f.y;
        }
    }
    fwd_store(XR, XI, dv, t, n, h, spec);
}

// ---- fused: cfft along H -> per-frequency 8x8 complex mat -> icfft -----
__global__ __launch_bounds__(512) void ffth_mult_kernel(
    float2* __restrict__ spec, const unsigned* __restrict__ fpack)
{
    __shared__ f32x4 XR[2][256], XI[2][256];
    int tid = threadIdx.x;
    int t = tid & 255, g = tid >> 8;
    int c0 = g*4;
    int n = blockIdx.x / 129, w2 = blockIdx.x % 129;
    float2* base = spec + ((size_t)(n*129 + w2))*2048;
    const float4* rp = (const float4*)(base + (size_t)t*8);
    float4 ra = rp[g*2], rb = rp[g*2+1];
    XR[g][t] = (f32x4){ra.x, ra.z, rb.x, rb.z};
    XI[g][t] = (f32x4){ra.y, ra.w, rb.y, rb.w};
    __syncthreads();
    f32x4 sR, sI;
    fft256v_core(XR[g], XI[g], t, -1.f, sR, sI);   // own 4 channels, pos t
    __syncthreads();                                // all stage-2 reads done
    XR[g][t] = sR; XI[g][t] = sI;
    __syncthreads();
    f32x4 oR = XR[1-g][t], oI = XI[1-g][t];         // other group's 4 channels
    f32x4 aR = g ? oR : sR, aI = g ? oI : sI;       // ch 0-3
    f32x4 bR = g ? sR : oR, bI = g ? sI : oI;       // ch 4-7
    float sr[8] = {aR.x,aR.y,aR.z,aR.w, bR.x,bR.y,bR.z,bR.w};
    float si[8] = {aI.x,aI.y,aI.z,aI.w, bI.x,bI.y,bI.z,bI.w};
    f32x4 orr = {0.f,0.f,0.f,0.f}, oii = {0.f,0.f,0.f,0.f};
    const unsigned* fp = fpack + (size_t)w2*16384 + t;
#pragma unroll
    for (int j = 0; j < 8; ++j){
        float sjr = sr[j], sji = si[j];
        float2 f0 = unpack_bf16x2(fp[(j*8 + c0 + 0)*256]);
        float2 f1 = unpack_bf16x2(fp[(j*8 + c0 + 1)*256]);
        float2 f2 = unpack_bf16x2(fp[(j*8 + c0 + 2)*256]);
        float2 f3 = unpack_bf16x2(fp[(j*8 + c0 + 3)*256]);
        orr.x += sjr*f0.x - sji*f0.y;  oii.x += sjr*f0.y + sji*f0.x;
        orr.y += sjr*f1.x - sji*f1.y;  oii.y += sjr*f1.y + sji*f1.x;
        orr.z += sjr*f2.x - sji*f2.y;  oii.z += sjr*f2.y + sji*f2.x;
        orr.w += sjr*f3.x - sji*f3.y;  oii.w += sjr*f3.y + sji*f3.x;
    }
    __syncthreads();                                // matmul reads done
    XR[g][t] = orr; XI[g][t] = oii;
    __syncthreads();
    f32x4 vR, vI;
    fft256v_core(XR[g], XI[g], t, +1.f, vR, vI);
    float4* wp = (float4*)(base + (size_t)t*8);
    wp[g*2]   = make_float4(vR.x, vI.x, vR.y, vI.y);
    wp[g*2+1] = make_float4(vR.z, vI.z, vR.w, vI.w);
}

// ---- fused step: inv-W-FFT -> u' = 2u+(gu-u)G -> du = u'D -> fwd-W-FFT -
__global__ __launch_bounds__(256) void born_step_kernel(
    float2* __restrict__ spec, const float* __restrict__ u_in,
    float* __restrict__ u_out, const unsigned* __restrict__ gmat,
    const unsigned* __restrict__ dmat)
{
    __shared__ f32x4 XR[256], XI[256];
    int t = threadIdx.x, bid = blockIdx.x;
    int n = bid >> 8, h = bid & 255;
    float gu[8];
    inv_fft_to_gu(spec, XR, XI, t, n, h, gu);

    const float* up = u_in + (size_t)bid*2048 + (size_t)t*8;
    float4 ua = ((const float4*)up)[0], ub = ((const float4*)up)[1];
    float uv[8] = {ua.x,ua.y,ua.z,ua.w, ub.x,ub.y,ub.z,ub.w};
    float e[8], acc[8];
#pragma unroll
    for (int c = 0; c < 8; ++c){ e[c] = gu[c] - uv[c]; acc[c] = 2.0f*uv[c]; }
    const unsigned* gp = gmat + ((size_t)bid*4 + (t>>6))*2048 + (t&63);
#pragma unroll
    for (int j = 0; j < 8; ++j){
        float ej = e[j];
#pragma unroll
        for (int k2 = 0; k2 < 4; ++k2){
            float2 f = unpack_bf16x2(gp[(j*4+k2)*64]);
            acc[2*k2]   += ej * f.x;
            acc[2*k2+1] += ej * f.y;
        }
    }
    float* op = u_out + (size_t)bid*2048 + (size_t)t*8;
    ((float4*)op)[0] = make_float4(acc[0],acc[1],acc[2],acc[3]);
    ((float4*)op)[1] = make_float4(acc[4],acc[5],acc[6],acc[7]);

    // du for next iteration from u'
    const unsigned* dp = dmat + ((size_t)bid*4 + (t>>6))*2048 + (t&63);
    float dv[8];
#pragma unroll
    for (int k = 0; k < 8; ++k) dv[k] = 0.f;
#pragma unroll
    for (int j = 0; j < 8; ++j){
        float uj = acc[j];
#pragma unroll
        for (int k2 = 0; k2 < 4; ++k2){
            float2 f = unpack_bf16x2(dp[(j*4+k2)*64]);
            dv[2*k2]   += uj * f.x;
            dv[2*k2+1] += uj * f.y;
        }
    }
    __syncthreads();   // guard: laggards may still read XR/XI from inv stage-2
    fwd_store(XR, XI, dv, t, n, h, spec);
}

// ---- final: inv-W-FFT -> u' -> gelu(u'+bias) -> out --------------------
__global__ __launch_bounds__(256) void final_kernel(
    const float2* __restrict__ spec, const float* __restrict__ u_in,
    const unsigned* __restrict__ gmat, const float* __restrict__ bias,
    float* __restrict__ out)
{
    __shared__ f32x4 XR[256], XI[256];
    int t = threadIdx.x, bid = blockIdx.x;
    int n = bid >> 8, h = bid & 255;
    float gu[8];
    inv_fft_to_gu(spec, XR, XI, t, n, h, gu);

    const float* up = u_in + (size_t)bid*2048 + (size_t)t*8;
    float4 ua = ((const float4*)up)[0], ub = ((const float4*)up)[1];
    float uv[8] = {ua.x,ua.y,ua.z,ua.w, ub.x,ub.y,ub.z,ub.w};
    float e[8], acc[8];
#pragma unroll
    for (int c = 0; c < 8; ++c){ e[c] = gu[c] - uv[c]; acc[c] = 2.0f*uv[c]; }
    const unsigned* gp = gmat + ((size_t)bid*4 + (t>>6))*2048 + (t&63);
#pragma unroll
    for (int j = 0; j < 8; ++j){
        float ej = e[j];
#pragma unroll
        for (int k2 = 0; k2 < 4; ++k2){
            float2 f = unpack_bf16x2(gp[(j*4+k2)*64]);
            acc[2*k2]   += ej * f.x;
            acc[2*k2+1] += ej * f.y;
        }
    }
#pragma unroll
    for (int k = 0; k < 8; ++k) acc[k] = gelu_f(acc[k] + bias[k]);
    float* op = out + (size_t)bid*2048 + (size_t)t*8;
    ((float4*)op)[0] = make_float4(acc[0],acc[1],acc[2],acc[3]);
    ((float4*)op)[1] = make_float4(acc[4],acc[5],acc[6],acc[7]);
}

extern "C" void kernel_launch(void* const* d_in, const int* in_sizes, int n_in,
                              void* d_out, int out_size, void* d_ws, size_t ws_size,
                              hipStream_t stream) {
    const float* u_in = (const float*)d_in[0];
    const float* k_in = (const float*)d_in[1];
    const float* Wp[24];
    for (int i = 0; i < 24; ++i) Wp[i] = (const float*)d_in[2+i];
    const float* bias = (const float*)d_in[26];

    char* base = (char*)d_ws;
    unsigned* gmat  = (unsigned*)(base);                  // 32 MiB (bf16 pairs)
    unsigned* dmat  = (unsigned*)(base + 33554432ull);    // 32 MiB
    unsigned* fpack = (unsigned*)(base + 67108864ull);    // 8.45 MB (bf16 pairs)
    float*    u_ws  = (float*)   (base + 75563008ull);    // 8 MiB
    float2*   spec  = (float2*)  (base + 83951616ull);    // 8.45 MB -> ~92 MB

    prep_kernel<<<2177, 256, 0, stream>>>(k_in,
        Wp[0],Wp[1],Wp[2],Wp[3],Wp[4],Wp[5],
        Wp[6],Wp[7],Wp[8],Wp[9],Wp[10],Wp[11],
        Wp[12],Wp[13],Wp[14],Wp[15],Wp[16],Wp[17],
        Wp[18],Wp[19],Wp[20],Wp[21],Wp[22],Wp[23],
        gmat, dmat, fpack);

    fft_fwd_kernel<<<1024, 256, 0, stream>>>(u_in, dmat, spec);
    for (int it = 0; it < 4; ++it){
        ffth_mult_kernel<<<516, 512, 0, stream>>>(spec, fpack);
        if (it < 3){
            born_step_kernel<<<1024, 256, 0, stream>>>(
                spec, (it == 0) ? u_in : u_ws, u_ws, gmat, dmat);
        } else {
            final_kernel<<<1024, 256, 0, stream>>>(spec, u_ws, gmat, bias, (float*)d_out);
        }
    }
}

// Round 10
// 220.096 us; speedup vs baseline: 4.3446x; 1.0027x over previous
//
#include <hip/hip_runtime.h>
#include <math.h>

// Problem constants
#define NB 4
#define HB 256
#define WB 256
#define CB 8
#define NPIX (NB*HB*WB)   // 262144
#define W2B 129           // rfft bins along W
#define TWO_PI_F 6.283185307179586f

typedef float f32x4 __attribute__((ext_vector_type(4)));

__device__ __forceinline__ float gelu_f(float x){
    float z = 0.7978845608028654f*(x + 0.044715f*x*x*x);
    return x * __builtin_amdgcn_rcpf(1.0f + __expf(-2.0f*z));
}

__device__ __forceinline__ unsigned pack_bf16x2(float a, float b){
    unsigned ua = __float_as_uint(a), ub = __float_as_uint(b);
    ua = (ua + 0x7FFFu + ((ua >> 16) & 1u)) >> 16;
    ub = (ub + 0x7FFFu + ((ub >> 16) & 1u)) >> 16;
    return ua | (ub << 16);
}
__device__ __forceinline__ float2 unpack_bf16x2(unsigned v){
    return make_float2(__uint_as_float(v << 16), __uint_as_float(v & 0xFFFF0000u));
}

__device__ __forceinline__ void ldcp(float* dst, const float* __restrict__ src, int n, int t){
    for (int i = t; i < n; i += 256) dst[i] = src[i];
}

// ---- prep ---------------------------------------------------------------
// Grid: [0..128] spectral filter (first); [129..640] gamma 2px/thr;
//       [641..1152] delta 2px/thr.
// mat layout (uint4 rows): mat[(pix>>6)*2048 + j*256 + (pix&63)*4 + c],
//   c=0..3, each uint = bf16x2{k=2c, k=2c+1} of row j  (8 KB/64-px panel)
// fpack layout: fpack[w2*16384 + q*1024 + h*4 + c], q=(j*8+k)>>2, c=k&3,
//   each uint = bf16x2{re,im}
__global__ __launch_bounds__(256) void prep_kernel(
    const float* __restrict__ kin,
    const float* gw1,const float* gb1,const float* gw2,const float* gb2,const float* gw3,const float* gb3,
    const float* dw1,const float* db1,const float* dw2,const float* db2,const float* dw3,const float* db3,
    const float* fw1,const float* fb1,const float* fw2,const float* fb2,const float* fw3,const float* fb3,
    const float* iw1,const float* ib1,const float* iw2,const float* ib2,const float* iw3,const float* ib3,
    unsigned* __restrict__ gmat, unsigned* __restrict__ dmat,
    unsigned* __restrict__ fpack)
{
    __shared__ __align__(16) float sw[2816];
    int t = threadIdx.x;
    int b = blockIdx.x;
    if (b >= 129){
        int gd = (b >= 641);
        const float* w1 = gd ? dw1 : gw1;  const float* b1 = gd ? db1 : gb1;
        const float* w2 = gd ? dw2 : gw2;  const float* b2 = gd ? db2 : gb2;
        const float* w3 = gd ? dw3 : gw3;  const float* b3 = gd ? db3 : gb3;
        ldcp(sw+0,   w1,  32, t); ldcp(sw+32,  b1, 16, t);
        ldcp(sw+48,  w2, 256, t); ldcp(sw+304, b2, 16, t);
        ldcp(sw+320, w3,1024, t); ldcp(sw+1344,b3, 64, t);
        __syncthreads();
        unsigned* mat = gd ? dmat : gmat;
        int p0 = (b - (gd ? 641 : 129))*512 + t;
        int p1 = p0 + 256;
        float2 kv0 = ((const float2*)kin)[p0];
        float2 kv1 = ((const float2*)kin)[p1];
        size_t base0 = (size_t)(p0 >> 6)*2048 + (size_t)(p0 & 63)*4;
        size_t base1 = (size_t)(p1 >> 6)*2048 + (size_t)(p1 & 63)*4;
        float h1[2][16], h2[2][16];
#pragma unroll
        for (int o = 0; o < 16; ++o){
            float wx = sw[o], wy = sw[16+o], bo = sw[32+o];
            h1[0][o] = gelu_f(kv0.x*wx + kv0.y*wy + bo);
            h1[1][o] = gelu_f(kv1.x*wx + kv1.y*wy + bo);
        }
#pragma unroll
        for (int oc = 0; oc < 4; ++oc){
            f32x4 bb = *(const f32x4*)(sw + 304 + oc*4);
            f32x4 a0 = bb, a1 = bb;
#pragma unroll
            for (int i = 0; i < 16; ++i){
                f32x4 w = *(const f32x4*)(sw + 48 + i*16 + oc*4);
                a0 += h1[0][i]*w; a1 += h1[1][i]*w;
            }
            h2[0][oc*4+0]=gelu_f(a0.x); h2[0][oc*4+1]=gelu_f(a0.y);
            h2[0][oc*4+2]=gelu_f(a0.z); h2[0][oc*4+3]=gelu_f(a0.w);
            h2[1][oc*4+0]=gelu_f(a1.x); h2[1][oc*4+1]=gelu_f(a1.y);
            h2[1][oc*4+2]=gelu_f(a1.z); h2[1][oc*4+3]=gelu_f(a1.w);
        }
        const float s = 1.0f/64.0f;
        // layer 3: per j, outputs k=0..7 (two f32x4 quads), shared weight reads
#pragma unroll
        for (int j = 0; j < 8; ++j){
            f32x4 bA = *(const f32x4*)(sw + 1344 + j*8);
            f32x4 bB = *(const f32x4*)(sw + 1344 + j*8 + 4);
            f32x4 A0 = bA, A1 = bB, B0 = bA, B1 = bB;
#pragma unroll
            for (int i = 0; i < 16; ++i){
                f32x4 wA = *(const f32x4*)(sw + 320 + i*64 + j*8);
                f32x4 wB = *(const f32x4*)(sw + 320 + i*64 + j*8 + 4);
                float h0 = h2[0][i], h1v = h2[1][i];
                A0 += h0*wA; A1 += h0*wB;
                B0 += h1v*wA; B1 += h1v*wB;
            }
            uint4 o0 = { pack_bf16x2(A0.x*s,A0.y*s), pack_bf16x2(A0.z*s,A0.w*s),
                         pack_bf16x2(A1.x*s,A1.y*s), pack_bf16x2(A1.z*s,A1.w*s) };
            uint4 o1 = { pack_bf16x2(B0.x*s,B0.y*s), pack_bf16x2(B0.z*s,B0.w*s),
                         pack_bf16x2(B1.x*s,B1.y*s), pack_bf16x2(B1.z*s,B1.w*s) };
            *(uint4*)(mat + base0 + (size_t)j*256) = o0;
            *(uint4*)(mat + base1 + (size_t)j*256) = o1;
        }
    } else {
        ldcp(sw+0,   fw1,  32, t); ldcp(sw+32,  fb1, 16, t);
        ldcp(sw+48,  fw2, 256, t); ldcp(sw+304, fb2, 16, t);
        ldcp(sw+320, fw3,1024, t); ldcp(sw+1344,fb3, 64, t);
        ldcp(sw+1408+0,   iw1,  32, t); ldcp(sw+1408+32,  ib1, 16, t);
        ldcp(sw+1408+48,  iw2, 256, t); ldcp(sw+1408+304, ib2, 16, t);
        ldcp(sw+1408+320, iw3,1024, t); ldcp(sw+1408+1344,ib3, 64, t);
        __syncthreads();
        int w2 = b;                                 // 0..128 (kx)
        float x = (float)w2;
        float y = (float)(t < 128 ? t : t - 256);   // ky signed, t = h-freq
        float h1r[16], h1i[16], h2r[16], h2i[16];
#pragma unroll
        for (int o = 0; o < 16; ++o){
            h1r[o] = gelu_f(x*sw[o] + y*sw[16+o] + sw[32+o]);
            h1i[o] = gelu_f(x*sw[1408+o] + y*sw[1408+16+o] + sw[1408+32+o]);
        }
#pragma unroll
        for (int o = 0; o < 16; ++o){
            float ar = sw[304+o], ai = sw[1408+304+o];
#pragma unroll
            for (int i = 0; i < 16; ++i){
                ar += h1r[i]*sw[48+i*16+o];
                ai += h1i[i]*sw[1408+48+i*16+o];
            }
            h2r[o] = gelu_f(ar); h2i[o] = gelu_f(ai);
        }
        const float s = 1.0f/64.0f;
#pragma unroll
        for (int q = 0; q < 16; ++q){
            f32x4 aR = *(const f32x4*)(sw + 1344 + q*4);
            f32x4 aI = *(const f32x4*)(sw + 1408 + 1344 + q*4);
#pragma unroll
            for (int i = 0; i < 16; ++i){
                aR += h2r[i] * *(const f32x4*)(sw + 320 + i*64 + q*4);
                aI += h2i[i] * *(const f32x4*)(sw + 1408 + 320 + i*64 + q*4);
            }
            uint4 out = { pack_bf16x2(aR.x*s, aI.x*s), pack_bf16x2(aR.y*s, aI.y*s),
                          pack_bf16x2(aR.z*s, aI.z*s), pack_bf16x2(aR.w*s, aI.w*s) };
            *(uint4*)(fpack + (size_t)w2*16384 + (size_t)q*1024 + (size_t)t*4) = out;
        }
    }
}

// ---- 256-pt complex FFT, 4 interleaved channels (f32x4 LDS) ------------
__device__ __forceinline__ void fft256v(f32x4* xr, f32x4* xi, int t, float sgn)
{
    int n2 = t >> 4, k1 = t & 15;
    float csA, snA; __sincosf(sgn*TWO_PI_F*(float)k1*(1.0f/16.0f), &snA, &csA);
    f32x4 ar = {0.f,0.f,0.f,0.f}, ai = {0.f,0.f,0.f,0.f};
    float cw = 1.f, sw = 0.f;
#pragma unroll
    for (int n1 = 0; n1 < 16; ++n1){
        f32x4 vr = xr[16*n1 + n2], vi = xi[16*n1 + n2];
        ar += vr*cw - vi*sw;
        ai += vr*sw + vi*cw;
        float cn = cw*csA - sw*snA;
        sw = cw*snA + sw*csA; cw = cn;
    }
    float cs2, sn2; __sincosf(sgn*TWO_PI_F*(float)(n2*k1)*(1.0f/256.0f), &sn2, &cs2);
    f32x4 br = ar*cs2 - ai*sn2;
    f32x4 bi = ar*sn2 + ai*cs2;
    __syncthreads();
    xr[t] = br; xi[t] = bi;
    __syncthreads();
    int k1b = t & 15, k2 = t >> 4;
    float csB, snB; __sincosf(sgn*TWO_PI_F*(float)k2*(1.0f/16.0f), &snB, &csB);
    f32x4 yr = {0.f,0.f,0.f,0.f}, yi = {0.f,0.f,0.f,0.f};
    cw = 1.f; sw = 0.f;
#pragma unroll
    for (int n2b = 0; n2b < 16; ++n2b){
        f32x4 br2 = xr[n2b*16 + k1b], bi2 = xi[n2b*16 + k1b];
        yr += br2*cw - bi2*sw;
        yi += br2*sw + bi2*cw;
        float cn = cw*csB - sw*snB;
        sw = cw*snB + sw*csB; cw = cn;
    }
    __syncthreads();
    xr[t] = yr; xi[t] = yi;
    __syncthreads();
}

// Core version: result returned in registers; no final store/sync.
__device__ __forceinline__ void fft256v_core(f32x4* xr, f32x4* xi, int t, float sgn,
                                             f32x4& outR, f32x4& outI)
{
    int n2 = t >> 4, k1 = t & 15;
    float csA, snA; __sincosf(sgn*TWO_PI_F*(float)k1*(1.0f/16.0f), &snA, &csA);
    f32x4 ar = {0.f,0.f,0.f,0.f}, ai = {0.f,0.f,0.f,0.f};
    float cw = 1.f, sw = 0.f;
#pragma unroll
    for (int n1 = 0; n1 < 16; ++n1){
        f32x4 vr = xr[16*n1 + n2], vi = xi[16*n1 + n2];
        ar += vr*cw - vi*sw;
        ai += vr*sw + vi*cw;
        float cn = cw*csA - sw*snA;
        sw = cw*snA + sw*csA; cw = cn;
    }
    float cs2, sn2; __sincosf(sgn*TWO_PI_F*(float)(n2*k1)*(1.0f/256.0f), &sn2, &cs2);
    f32x4 br = ar*cs2 - ai*sn2;
    f32x4 bi = ar*sn2 + ai*cs2;
    __syncthreads();
    xr[t] = br; xi[t] = bi;
    __syncthreads();
    int k1b = t & 15, k2 = t >> 4;
    float csB, snB; __sincosf(sgn*TWO_PI_F*(float)k2*(1.0f/16.0f), &snB, &csB);
    f32x4 yr = {0.f,0.f,0.f,0.f}, yi = {0.f,0.f,0.f,0.f};
    cw = 1.f; sw = 0.f;
#pragma unroll
    for (int n2b = 0; n2b < 16; ++n2b){
        f32x4 br2 = xr[n2b*16 + k1b], bi2 = xi[n2b*16 + k1b];
        yr += br2*cw - bi2*sw;
        yi += br2*sw + bi2*cw;
        float cn = cw*csB - sw*snB;
        sw = cw*snB + sw*csB; cw = cn;
    }
    outR = yr; outI = yi;
}

// du row -> fwd FFT -> Hermitian split -> spec write (t<=128)
__device__ __forceinline__ void fwd_store(
    f32x4* XR, f32x4* XI, const float* dv, int t, int n, int h,
    float2* __restrict__ spec)
{
    XR[t] = (f32x4){dv[0],dv[2],dv[4],dv[6]};
    XI[t] = (f32x4){dv[1],dv[3],dv[5],dv[7]};
    __syncthreads();
    fft256v(XR, XI, t, -1.f);
    if (t <= 128){
        int m = (256 - t) & 255;
        f32x4 zr = XR[t], zi = XI[t], yr = XR[m], yi = XI[m];
        float4* dst = (float4*)(spec + (((size_t)n*129 + t)*256 + h)*8);
        dst[0] = make_float4(0.5f*(zr.x+yr.x), 0.5f*(zi.x-yi.x), 0.5f*(zi.x+yi.x), 0.5f*(yr.x-zr.x));
        dst[1] = make_float4(0.5f*(zr.y+yr.y), 0.5f*(zi.y-yi.y), 0.5f*(zi.y+yi.y), 0.5f*(yr.y-zr.y));
        dst[2] = make_float4(0.5f*(zr.z+yr.z), 0.5f*(zi.z-yi.z), 0.5f*(zi.z+yi.z), 0.5f*(yr.z-zr.z));
        dst[3] = make_float4(0.5f*(zr.w+yr.w), 0.5f*(zi.w-yi.w), 0.5f*(zi.w+yi.w), 0.5f*(yr.w-zr.w));
    }
}

// direct Hermitian read -> inv FFT (core) -> gu[8] in registers.
__device__ __forceinline__ void inv_fft_to_gu(
    const float2* __restrict__ spec, f32x4* XR, f32x4* XI,
    int t, int n, int h, float* gu)
{
    int w2 = (t <= 128) ? t : 256 - t;
    const float4* rp = (const float4*)(spec + (((size_t)n*129 + w2)*256 + h)*8);
    float4 q0 = rp[0], q1 = rp[1], q2 = rp[2], q3 = rp[3];
    f32x4 xr, xi;
    if (t <= 128){
        xr = (f32x4){q0.x - q0.w, q1.x - q1.w, q2.x - q2.w, q3.x - q3.w};
        xi = (f32x4){q0.y + q0.z, q1.y + q1.z, q2.y + q2.z, q3.y + q3.z};
    } else {
        xr = (f32x4){ q0.x + q0.w,  q1.x + q1.w,  q2.x + q2.w,  q3.x + q3.w};
        xi = (f32x4){-q0.y + q0.z, -q1.y + q1.z, -q2.y + q2.z, -q3.y + q3.z};
    }
    XR[t] = xr; XI[t] = xi;
    __syncthreads();
    f32x4 gr, gi;
    fft256v_core(XR, XI, t, +1.f, gr, gi);
    const float s = 1.0f/65536.0f;
    gu[0]=gr.x*s; gu[1]=gi.x*s; gu[2]=gr.y*s; gu[3]=gi.y*s;
    gu[4]=gr.z*s; gu[5]=gi.z*s; gu[6]=gr.w*s; gu[7]=gi.w*s;
}

// matvec accumulate: acc[k] += v[j] * M[j][k], M in uint4-row layout
__device__ __forceinline__ void matvec_acc(const unsigned* __restrict__ mat,
                                           size_t base, const float* v, float* acc)
{
    const uint4* mp = (const uint4*)(mat + base);
#pragma unroll
    for (int j = 0; j < 8; ++j){
        uint4 q = mp[j*64];
        float vj = v[j];
        float2 f0 = unpack_bf16x2(q.x), f1 = unpack_bf16x2(q.y);
        float2 f2 = unpack_bf16x2(q.z), f3 = unpack_bf16x2(q.w);
        acc[0] += vj*f0.x; acc[1] += vj*f0.y;
        acc[2] += vj*f1.x; acc[3] += vj*f1.y;
        acc[4] += vj*f2.x; acc[5] += vj*f2.y;
        acc[6] += vj*f3.x; acc[7] += vj*f3.y;
    }
}

// ---- initial: du = u*Delta, forward rfft along W -----------------------
__global__ __launch_bounds__(256) void fft_fwd_kernel(
    const float* __restrict__ u, const unsigned* __restrict__ dmat,
    float2* __restrict__ spec)
{
    __shared__ f32x4 XR[256], XI[256];
    int t = threadIdx.x, bid = blockIdx.x;
    int n = bid >> 8, h = bid & 255;
    const float* up = u + (size_t)bid*2048 + (size_t)t*8;
    float4 ua = ((const float4*)up)[0], ub = ((const float4*)up)[1];
    float uv[8] = {ua.x,ua.y,ua.z,ua.w, ub.x,ub.y,ub.z,ub.w};
    size_t base = (size_t)(bid*4 + (t>>6))*2048 + (size_t)(t&63)*4;
    float dv[8] = {0,0,0,0,0,0,0,0};
    matvec_acc(dmat, base, uv, dv);
    fwd_store(XR, XI, dv, t, n, h, spec);
}

// ---- fused: cfft along H -> per-frequency 8x8 complex mat -> icfft -----
__global__ __launch_bounds__(512) void ffth_mult_kernel(
    float2* __restrict__ spec, const unsigned* __restrict__ fpack)
{
    __shared__ f32x4 XR[2][256], XI[2][256];
    int tid = threadIdx.x;
    int t = tid & 255, g = tid >> 8;
    int n = blockIdx.x / 129, w2 = blockIdx.x % 129;
    float2* base = spec + ((size_t)(n*129 + w2))*2048;
    const float4* rp = (const float4*)(base + (size_t)t*8);
    float4 ra = rp[g*2], rb = rp[g*2+1];
    XR[g][t] = (f32x4){ra.x, ra.z, rb.x, rb.z};
    XI[g][t] = (f32x4){ra.y, ra.w, rb.y, rb.w};
    __syncthreads();
    f32x4 sR, sI;
    fft256v_core(XR[g], XI[g], t, -1.f, sR, sI);
    __syncthreads();
    XR[g][t] = sR; XI[g][t] = sI;
    __syncthreads();
    f32x4 oR = XR[1-g][t], oI = XI[1-g][t];
    f32x4 aR = g ? oR : sR, aI = g ? oI : sI;       // ch 0-3
    f32x4 bR = g ? sR : oR, bI = g ? sI : oI;       // ch 4-7
    float sr[8] = {aR.x,aR.y,aR.z,aR.w, bR.x,bR.y,bR.z,bR.w};
    float si[8] = {aI.x,aI.y,aI.z,aI.w, bI.x,bI.y,bI.z,bI.w};
    f32x4 orr = {0.f,0.f,0.f,0.f}, oii = {0.f,0.f,0.f,0.f};
    const uint4* fp = (const uint4*)(fpack + (size_t)w2*16384 + (size_t)t*4);
#pragma unroll
    for (int j = 0; j < 8; ++j){
        float sjr = sr[j], sji = si[j];
        uint4 fq = fp[(j*2 + g)*256];
        float2 f0 = unpack_bf16x2(fq.x), f1 = unpack_bf16x2(fq.y);
        float2 f2 = unpack_bf16x2(fq.z), f3 = unpack_bf16x2(fq.w);
        orr.x += sjr*f0.x - sji*f0.y;  oii.x += sjr*f0.y + sji*f0.x;
        orr.y += sjr*f1.x - sji*f1.y;  oii.y += sjr*f1.y + sji*f1.x;
        orr.z += sjr*f2.x - sji*f2.y;  oii.z += sjr*f2.y + sji*f2.x;
        orr.w += sjr*f3.x - sji*f3.y;  oii.w += sjr*f3.y + sji*f3.x;
    }
    __syncthreads();
    XR[g][t] = orr; XI[g][t] = oii;
    __syncthreads();
    f32x4 vR, vI;
    fft256v_core(XR[g], XI[g], t, +1.f, vR, vI);
    float4* wp = (float4*)(base + (size_t)t*8);
    wp[g*2]   = make_float4(vR.x, vI.x, vR.y, vI.y);
    wp[g*2+1] = make_float4(vR.z, vI.z, vR.w, vI.w);
}

// ---- fused step: inv-W-FFT -> u' = 2u+(gu-u)G -> du = u'D -> fwd-W-FFT -
__global__ __launch_bounds__(256) void born_step_kernel(
    float2* __restrict__ spec, const float* __restrict__ u_in,
    float* __restrict__ u_out, const unsigned* __restrict__ gmat,
    const unsigned* __restrict__ dmat)
{
    __shared__ f32x4 XR[256], XI[256];
    int t = threadIdx.x, bid = blockIdx.x;
    int n = bid >> 8, h = bid & 255;
    float gu[8];
    inv_fft_to_gu(spec, XR, XI, t, n, h, gu);

    const float* up = u_in + (size_t)bid*2048 + (size_t)t*8;
    float4 ua = ((const float4*)up)[0], ub = ((const float4*)up)[1];
    float uv[8] = {ua.x,ua.y,ua.z,ua.w, ub.x,ub.y,ub.z,ub.w};
    float e[8], acc[8];
#pragma unroll
    for (int c = 0; c < 8; ++c){ e[c] = gu[c] - uv[c]; acc[c] = 2.0f*uv[c]; }
    size_t base = (size_t)(bid*4 + (t>>6))*2048 + (size_t)(t&63)*4;
    matvec_acc(gmat, base, e, acc);
    float* op = u_out + (size_t)bid*2048 + (size_t)t*8;
    ((float4*)op)[0] = make_float4(acc[0],acc[1],acc[2],acc[3]);
    ((float4*)op)[1] = make_float4(acc[4],acc[5],acc[6],acc[7]);

    float dv[8] = {0,0,0,0,0,0,0,0};
    matvec_acc(dmat, base, acc, dv);
    __syncthreads();   // guard: laggards may still read XR/XI from inv stage-2
    fwd_store(XR, XI, dv, t, n, h, spec);
}

// ---- final: inv-W-FFT -> u' -> gelu(u'+bias) -> out --------------------
__global__ __launch_bounds__(256) void final_kernel(
    const float2* __restrict__ spec, const float* __restrict__ u_in,
    const unsigned* __restrict__ gmat, const float* __restrict__ bias,
    float* __restrict__ out)
{
    __shared__ f32x4 XR[256], XI[256];
    int t = threadIdx.x, bid = blockIdx.x;
    int n = bid >> 8, h = bid & 255;
    float gu[8];
    inv_fft_to_gu(spec, XR, XI, t, n, h, gu);

    const float* up = u_in + (size_t)bid*2048 + (size_t)t*8;
    float4 ua = ((const float4*)up)[0], ub = ((const float4*)up)[1];
    float uv[8] = {ua.x,ua.y,ua.z,ua.w, ub.x,ub.y,ub.z,ub.w};
    float e[8], acc[8];
#pragma unroll
    for (int c = 0; c < 8; ++c){ e[c] = gu[c] - uv[c]; acc[c] = 2.0f*uv[c]; }
    size_t base = (size_t)(bid*4 + (t>>6))*2048 + (size_t)(t&63)*4;
    matvec_acc(gmat, base, e, acc);
#pragma unroll
    for (int k = 0; k < 8; ++k) acc[k] = gelu_f(acc[k] + bias[k]);
    float* op = out + (size_t)bid*2048 + (size_t)t*8;
    ((float4*)op)[0] = make_float4(acc[0],acc[1],acc[2],acc[3]);
    ((float4*)op)[1] = make_float4(acc[4],acc[5],acc[6],acc[7]);
}

extern "C" void kernel_launch(void* const* d_in, const int* in_sizes, int n_in,
                              void* d_out, int out_size, void* d_ws, size_t ws_size,
                              hipStream_t stream) {
    const float* u_in = (const float*)d_in[0];
    const float* k_in = (const float*)d_in[1];
    const float* Wp[24];
    for (int i = 0; i < 24; ++i) Wp[i] = (const float*)d_in[2+i];
    const float* bias = (const float*)d_in[26];

    char* base = (char*)d_ws;
    unsigned* gmat  = (unsigned*)(base);                  // 32 MiB (bf16 pairs)
    unsigned* dmat  = (unsigned*)(base + 33554432ull);    // 32 MiB
    unsigned* fpack = (unsigned*)(base + 67108864ull);    // 8.45 MB (bf16 pairs)
    float*    u_ws  = (float*)   (base + 75563008ull);    // 8 MiB
    float2*   spec  = (float2*)  (base + 83951616ull);    // 8.45 MB -> ~92 MB

    prep_kernel<<<1153, 256, 0, stream>>>(k_in,
        Wp[0],Wp[1],Wp[2],Wp[3],Wp[4],Wp[5],
        Wp[6],Wp[7],Wp[8],Wp[9],Wp[10],Wp[11],
        Wp[12],Wp[13],Wp[14],Wp[15],Wp[16],Wp[17],
        Wp[18],Wp[19],Wp[20],Wp[21],Wp[22],Wp[23],
        gmat, dmat, fpack);

    fft_fwd_kernel<<<1024, 256, 0, stream>>>(u_in, dmat, spec);
    for (int it = 0; it < 4; ++it){
        ffth_mult_kernel<<<516, 512, 0, stream>>>(spec, fpack);
        if (it < 3){
            born_step_kernel<<<1024, 256, 0, stream>>>(
                spec, (it == 0) ? u_in : u_ws, u_ws, gmat, dmat);
        } else {
            final_kernel<<<1024, 256, 0, stream>>>(spec, u_ws, gmat, bias, (float*)d_out);
        }
    }
}